// Round 4
// baseline (1301.139 us; speedup 1.0000x reference)
//
#include <hip/hip_runtime.h>
#include <math.h>

// ---------------------------------------------------------------- constants
constexpr int N  = 40000;   // nodes
constexpr int D  = 128;     // latent dim
constexpr int E  = 640000;  // spatial edges
constexpr int Bg = 8;       // graphs
constexpr int Sg = 5000;    // nodes per graph
constexpr int KN = 6;       // knn
constexpr int FF = 256;     // ffn hidden
constexpr int LGCAP = 320;  // max in-degree supported in spatial GAT (actual ~45)
constexpr int QLEN = 1280;  // candidate quarter length (64-aligned); last quarter 1160
constexpr int NCAND = 48;   // 4 quarters x top-12

typedef short short8 __attribute__((ext_vector_type(8)));
typedef float f32x4  __attribute__((ext_vector_type(4)));

// ---------------------------------------------------------------- GEMM: out = A@W + bias (+res) (+relu6)
__global__ __launch_bounds__(256) void gemm_k(
    const float* __restrict__ A, int lda,
    const float* __restrict__ Wm, int ldw,
    const float* __restrict__ bias,
    const float* __restrict__ res,
    float* __restrict__ out, int ldo,
    int Kdim, int act)
{
    __shared__ float as[64][36];
    __shared__ float ws[32][128];
    int tid = threadIdx.x;
    int tr = tid >> 4, tc = tid & 15;
    int r0 = blockIdx.x * 64;
    int cb = blockIdx.y * 128;

    float acc[4][8];
#pragma unroll
    for (int j = 0; j < 4; ++j)
#pragma unroll
        for (int m = 0; m < 8; ++m) acc[j][m] = 0.f;

    for (int kt = 0; kt < Kdim; kt += 32) {
#pragma unroll
        for (int i = 0; i < 2; ++i) {
            int c2 = i * 256 + tid;
            int row = c2 >> 3, k4 = (c2 & 7) * 4;
            *(float4*)&as[row][k4] = *(const float4*)&A[(size_t)(r0 + row) * lda + kt + k4];
        }
#pragma unroll
        for (int i = 0; i < 4; ++i) {
            int c2 = i * 256 + tid;
            int row = c2 >> 5, c4 = (c2 & 31) * 4;
            *(float4*)&ws[row][c4] = *(const float4*)&Wm[(size_t)(kt + row) * ldw + cb + c4];
        }
        __syncthreads();
#pragma unroll 8
        for (int k = 0; k < 32; ++k) {
            float a[4], b[8];
#pragma unroll
            for (int j = 0; j < 4; ++j) a[j] = as[tr + 16 * j][k];
#pragma unroll
            for (int m = 0; m < 8; ++m) b[m] = ws[k][tc + 16 * m];
#pragma unroll
            for (int j = 0; j < 4; ++j)
#pragma unroll
                for (int m = 0; m < 8; ++m) acc[j][m] = fmaf(a[j], b[m], acc[j][m]);
        }
        __syncthreads();
    }
#pragma unroll
    for (int j = 0; j < 4; ++j) {
        int r = r0 + tr + 16 * j;
#pragma unroll
        for (int m = 0; m < 8; ++m) {
            int c = tc + 16 * m;
            float v = acc[j][m] + bias[cb + c];
            if (res) v += res[(size_t)r * 128 + c];
            if (act) v = fminf(fmaxf(v, 0.f), 6.f);
            out[(size_t)r * ldo + cb + c] = v;
        }
    }
}

// ---------------------------------------------------------------- per-row squared norm (wave per row)
__global__ __launch_bounds__(256) void sqnorm_k(const float* __restrict__ x, float* __restrict__ sqn)
{
    int w = threadIdx.x >> 6, lane = threadIdx.x & 63;
    int row = blockIdx.x * 4 + w;
    float v0 = x[(size_t)row * 128 + lane];
    float v1 = x[(size_t)row * 128 + 64 + lane];
    float s = v0 * v0 + v1 * v1;
#pragma unroll
    for (int off = 32; off; off >>= 1) s += __shfl_xor(s, off);
    if (lane == 0) sqn[row] = s;
}

// ---------------------------------------------------------------- x -> bf16 hi/lo split
__device__ __forceinline__ unsigned short f2bf(float f)
{
    unsigned int u = __float_as_uint(f);
    return (unsigned short)((u + 0x7fffu + ((u >> 16) & 1u)) >> 16);
}

__global__ __launch_bounds__(256) void cast_k(const float* __restrict__ x,
                                              unsigned short* __restrict__ xh,
                                              unsigned short* __restrict__ xl)
{
    size_t i = ((size_t)blockIdx.x * 256 + threadIdx.x) * 8;
    float4 v0 = *(const float4*)&x[i];
    float4 v1 = *(const float4*)&x[i + 4];
    float f[8] = {v0.x, v0.y, v0.z, v0.w, v1.x, v1.y, v1.z, v1.w};
    short8 hv, lv;
#pragma unroll
    for (int j = 0; j < 8; ++j) {
        unsigned short h = f2bf(f[j]);
        float hf = __uint_as_float(((unsigned int)h) << 16);
        hv[j] = (short)h;
        lv[j] = (short)f2bf(f[j] - hf);
    }
    *(short8*)&xh[i] = hv;
    *(short8*)&xl[i] = lv;
}

// ---------------------------------------------------------------- kNN prefilter via MFMA
// grid: 8 graphs x 40 query-blocks(128q) x 4 candidate-quarters (64-aligned,
// quarters tile the FULL Sg=5000: 1280/1280/1280/1160).
// block: 4 waves; wave w owns 32 queries (2 sets of 16 = mfma N dim).
// candidate tiles of 64 staged in LDS (hi only, XOR-swizzled rows).
// terms kept: cand_hi*(q_hi + q_lo); cand_lo dropped (err ~0.05 << margin).
// per-lane top-8 over its candidate stream -> shfl-merge -> top-12/quarter.
__global__ __launch_bounds__(256) void knn_mfma_k(const unsigned short* __restrict__ xh,
                                                  const unsigned short* __restrict__ xl,
                                                  const float* __restrict__ sqn,
                                                  int* __restrict__ cand)
{
    __shared__ char lds[16640];               // 16KB hi tile + 256B csq
    char* ldsH = lds;
    float* cs_s = (float*)(lds + 16384);

    int b = blockIdx.x;
    int g = b & 7, r = b >> 3;                // g == XCD id -> per-graph L2 locality
    int qtr = r & 3, qblk = r >> 2;
    int gbase = g * Sg;
    int cbase = qtr * QLEN;
    int qlen = (qtr < 3) ? QLEN : (Sg - 3 * QLEN);   // 1160 for last quarter
    int ntiles = (qlen + 63) >> 6;                    // 20/20/20/19
    int tid = threadIdx.x;
    int w = tid >> 6, lane = tid & 63;
    int lg = lane >> 4, ln = lane & 15;
    int q0 = qblk * 128 + w * 32;

    // resident query B-frags: [qset][kstep], hi+lo
    short8 bh[2][4], bl[2][4];
#pragma unroll
    for (int s = 0; s < 2; ++s) {
        int q = q0 + s * 16 + ln;
        int qrow = gbase + (q < Sg ? q : Sg - 1);
#pragma unroll
        for (int ks = 0; ks < 4; ++ks) {
            bh[s][ks] = *(const short8*)&xh[(size_t)qrow * 128 + ks * 32 + lg * 8];
            bl[s][ks] = *(const short8*)&xl[(size_t)qrow * 128 + ks * 32 + lg * 8];
        }
    }

    float d8[2][8]; int i8[2][8]; float mx[2]; int sl[2];
#pragma unroll
    for (int s = 0; s < 2; ++s) {
        mx[s] = __builtin_inff(); sl[s] = 0;
#pragma unroll
        for (int t = 0; t < 8; ++t) { d8[s][t] = __builtin_inff(); i8[s][t] = -1; }
    }

    for (int t64 = 0; t64 < ntiles; ++t64) {
        int c0 = cbase + t64 * 64;            // graph-relative
        __syncthreads();
        // stage 64 cand hi rows (row clamp keeps tail reads in-bounds),
        // swizzled: byte ^= (row&7)<<4
#pragma unroll
        for (int i = 0; i < 4; ++i) {
            int c = i * 256 + tid;            // 1024 chunks of 16B
            int row = c >> 4, slot = c & 15;
            int cr = c0 + row;
            if (cr >= Sg) cr = Sg - 1;
            short8 vh = *(const short8*)&xh[(size_t)(gbase + cr) * 128 + slot * 8];
            *(short8*)(ldsH + row * 256 + ((slot * 16) ^ ((row & 7) << 4))) = vh;
        }
        if (tid < 64) {
            int cl = c0 + tid;
            cs_s[tid] = (cl < cbase + qlen) ? sqn[gbase + cl] : __builtin_inff();
        }
        __syncthreads();

#pragma unroll
        for (int g16 = 0; g16 < 4; ++g16) {
            f32x4 acc0 = {0.f, 0.f, 0.f, 0.f};
            f32x4 acc1 = {0.f, 0.f, 0.f, 0.f};
            int rr = g16 * 16 + ln;
            int rsw = (rr & 7) << 4;
#pragma unroll
            for (int ks = 0; ks < 4; ++ks) {
                short8 ah = *(const short8*)(ldsH + rr * 256 + ((lg * 16 + ks * 64) ^ rsw));
                acc0 = __builtin_amdgcn_mfma_f32_16x16x32_bf16(ah, bh[0][ks], acc0, 0, 0, 0);
                acc0 = __builtin_amdgcn_mfma_f32_16x16x32_bf16(ah, bl[0][ks], acc0, 0, 0, 0);
                acc1 = __builtin_amdgcn_mfma_f32_16x16x32_bf16(ah, bh[1][ks], acc1, 0, 0, 0);
                acc1 = __builtin_amdgcn_mfma_f32_16x16x32_bf16(ah, bl[1][ks], acc1, 0, 0, 0);
            }
            f32x4 cv = *(const f32x4*)&cs_s[g16 * 16 + lg * 4];
#pragma unroll
            for (int s = 0; s < 2; ++s) {
                const f32x4& ac = s ? acc1 : acc0;
                bool ov = (c0 + g16 * 16) == (q0 + s * 16);  // 16-aligned ranges
#pragma unroll
                for (int rg = 0; rg < 4; ++rg) {
                    float dv = fmaf(-2.f, ac[rg], cv[rg]);
                    bool skip = ov && (lg * 4 + rg == ln);   // self-pair
                    if (!skip && dv < mx[s]) {
#pragma unroll
                        for (int t = 0; t < 8; ++t)
                            if (t == sl[s]) { d8[s][t] = dv; i8[s][t] = gbase + c0 + g16 * 16 + lg * 4 + rg; }
                        float m2 = d8[s][0]; int s2 = 0;
#pragma unroll
                        for (int t = 1; t < 8; ++t)
                            if (d8[s][t] > m2) { m2 = d8[s][t]; s2 = t; }
                        mx[s] = m2; sl[s] = s2;
                    }
                }
            }
        }
    }

    // in-wave merge: partials for query (s, ln) live in lanes ln + 16*lg.
#pragma unroll
    for (int s = 0; s < 2; ++s) {
        float d12[12]; int i12[12];
#pragma unroll
        for (int t = 0; t < 8; ++t) { d12[t] = d8[s][t]; i12[t] = i8[s][t]; }
#pragma unroll
        for (int t = 8; t < 12; ++t) { d12[t] = __builtin_inff(); i12[t] = -1; }
        float m12 = __builtin_inff(); int s12 = 8;
#pragma unroll
        for (int sg = 1; sg < 4; ++sg) {
#pragma unroll
            for (int t = 0; t < 8; ++t) {
                float dv = __shfl(d8[s][t], ln + sg * 16);
                int ci = __shfl(i8[s][t], ln + sg * 16);
                if (dv < m12) {
#pragma unroll
                    for (int u = 0; u < 12; ++u)
                        if (u == s12) { d12[u] = dv; i12[u] = ci; }
                    float m2 = d12[0]; int s2 = 0;
#pragma unroll
                    for (int u = 1; u < 12; ++u)
                        if (d12[u] > m2) { m2 = d12[u]; s2 = u; }
                    m12 = m2; s12 = s2;
                }
            }
        }
        int q = q0 + s * 16 + ln;
        if (lg == 0 && q < Sg) {
            int* cp = &cand[(size_t)(gbase + q) * NCAND + qtr * 12];
#pragma unroll
            for (int t = 0; t < 12; ++t) cp[t] = i12[t];
        }
    }
}

// ---------------------------------------------------------------- exact fp32 re-rank of <=48 candidates
// serial ascending-k fmaf chain == round-1 knn_k accumulation order (bitwise).
__global__ __launch_bounds__(256) void knn_rerank_k(const float* __restrict__ x,
                                                    const float* __restrict__ sqn,
                                                    const int* __restrict__ cand,
                                                    int* __restrict__ knn_idx)
{
    int q = blockIdx.x * 256 + threadIdx.x;
    if (q >= N) return;
    const float* xq = x + (size_t)q * 128;
    float d6[6]; int i6[6]; float mx = __builtin_inff(); int sl = 0;
#pragma unroll
    for (int t = 0; t < 6; ++t) { d6[t] = __builtin_inff(); i6[t] = -1; }
    for (int j = 0; j < NCAND; ++j) {
        int c = cand[(size_t)q * NCAND + j];
        if (c < 0) continue;
        const float* xc = x + (size_t)c * 128;
        float acc = 0.f;
        for (int k = 0; k < 128; ++k) acc = fmaf(xq[k], xc[k], acc);
        float dv = fmaf(-2.f, acc, sqn[c]);
        if (dv < mx) {
#pragma unroll
            for (int t = 0; t < 6; ++t)
                if (t == sl) { d6[t] = dv; i6[t] = c; }
            float m2 = d6[0]; int s2 = 0;
#pragma unroll
            for (int t = 1; t < 6; ++t)
                if (d6[t] > m2) { m2 = d6[t]; s2 = t; }
            mx = m2; sl = s2;
        }
    }
#pragma unroll
    for (int t = 0; t < 6; ++t) knn_idx[(size_t)q * 6 + t] = i6[t];
}

// ---------------------------------------------------------------- CSR build
__global__ __launch_bounds__(256) void hist_k(const int* __restrict__ dstA, int* __restrict__ deg)
{
    int e = blockIdx.x * 256 + threadIdx.x;
    atomicAdd(&deg[dstA[e]], 1);
}

__global__ __launch_bounds__(1024) void scan_k(const int* __restrict__ deg, int* __restrict__ rowptr)
{
    __shared__ int ps[1024];
    int t = threadIdx.x;
    const int chunk = 40;
    int base = t * chunk;
    int s = 0;
    for (int k = 0; k < chunk; ++k) { int i = base + k; if (i < N) s += deg[i]; }
    ps[t] = s;
    __syncthreads();
    for (int off = 1; off < 1024; off <<= 1) {
        int v = (t >= off) ? ps[t - off] : 0;
        __syncthreads();
        ps[t] += v;
        __syncthreads();
    }
    int run = ps[t] - s;
    for (int k = 0; k < chunk; ++k) {
        int i = base + k;
        if (i < N) { rowptr[i] = run; run += deg[i]; }
    }
    if (t == 0) rowptr[N] = E;
}

__global__ __launch_bounds__(256) void scatter_k(const int* __restrict__ srcA, const int* __restrict__ dstA,
                                                 const float* __restrict__ ea,
                                                 const int* __restrict__ rowptr, int* __restrict__ cnt,
                                                 int* __restrict__ csr_src, float* __restrict__ csr_ea)
{
    int e = blockIdx.x * 256 + threadIdx.x;
    int d = dstA[e];
    int pos = rowptr[d] + atomicAdd(&cnt[d], 1);
    csr_src[pos] = srcA[e];
    csr_ea[pos] = ea[e];
}

// ---------------------------------------------------------------- spatial GATv2 (wave per dst node)
__global__ __launch_bounds__(256) void spatial_gat_k(
    const float* __restrict__ xl, const float* __restrict__ xr,
    const int* __restrict__ rowptr, const int* __restrict__ csr_src, const float* __restrict__ csr_ea,
    const float* __restrict__ att, const float* __restrict__ wse, const float* __restrict__ bias,
    float* __restrict__ ch2)
{
    __shared__ float lg[4][LGCAP];
    int w = threadIdx.x >> 6, lane = threadIdx.x & 63;
    int dst = blockIdx.x * 4 + w;
    int base = rowptr[dst];
    int deg = rowptr[dst + 1] - base;
    if (deg > LGCAP) deg = LGCAP;
    float xr0 = xr[(size_t)dst * 128 + lane], xr1 = xr[(size_t)dst * 128 + 64 + lane];
    float at0 = att[lane], at1 = att[64 + lane];
    float we0 = wse[lane], we1 = wse[64 + lane];
    float m = -1e30f;
    for (int i = 0; i < deg; ++i) {
        int s = csr_src[base + i];
        float ea = csr_ea[base + i];
        float h0 = xl[(size_t)s * 128 + lane] + xr0 + ea * we0;
        float h1 = xl[(size_t)s * 128 + 64 + lane] + xr1 + ea * we1;
        h0 = h0 > 0.f ? h0 : 0.2f * h0;
        h1 = h1 > 0.f ? h1 : 0.2f * h1;
        float p = h0 * at0 + h1 * at1;
#pragma unroll
        for (int off = 32; off; off >>= 1) p += __shfl_xor(p, off);
        if (lane == 0) lg[w][i] = p;
        m = fmaxf(m, p);
    }
    __syncthreads();
    float sum = 0.f;
    for (int i = lane; i < deg; i += 64) {
        float ev = __expf(lg[w][i] - m);
        lg[w][i] = ev;
        sum += ev;
    }
#pragma unroll
    for (int off = 32; off; off >>= 1) sum += __shfl_xor(sum, off);
    float inv = 1.f / sum;
    __syncthreads();
    float o0 = 0.f, o1 = 0.f;
    for (int i = 0; i < deg; ++i) {
        float a = lg[w][i] * inv;
        int s = csr_src[base + i];
        o0 = fmaf(a, xl[(size_t)s * 128 + lane], o0);
        o1 = fmaf(a, xl[(size_t)s * 128 + 64 + lane], o1);
    }
    ch2[(size_t)dst * 256 + lane] = o0 + bias[lane];
    ch2[(size_t)dst * 256 + 64 + lane] = o1 + bias[64 + lane];
}

// ---------------------------------------------------------------- latent GATv2 (wave per dst; 6 knn + self)
__global__ __launch_bounds__(256) void latent_gat_k(
    const float* __restrict__ xl, const float* __restrict__ xr,
    const int* __restrict__ knn, const float* __restrict__ att,
    const float* __restrict__ bias, float* __restrict__ ch2)
{
    int w = threadIdx.x >> 6, lane = threadIdx.x & 63;
    int dst = blockIdx.x * 4 + w;
    float xr0 = xr[(size_t)dst * 128 + lane], xr1 = xr[(size_t)dst * 128 + 64 + lane];
    float at0 = att[lane], at1 = att[64 + lane];
    int s[7];
#pragma unroll
    for (int j = 0; j < 6; ++j) s[j] = knn[(size_t)dst * 6 + j];
    s[6] = dst;
    float l[7];
#pragma unroll
    for (int j = 0; j < 7; ++j) {
        float h0 = xl[(size_t)s[j] * 128 + lane] + xr0;
        float h1 = xl[(size_t)s[j] * 128 + 64 + lane] + xr1;
        h0 = h0 > 0.f ? h0 : 0.2f * h0;
        h1 = h1 > 0.f ? h1 : 0.2f * h1;
        float p = h0 * at0 + h1 * at1;
#pragma unroll
        for (int off = 32; off; off >>= 1) p += __shfl_xor(p, off);
        l[j] = p;
    }
    float m = l[0];
#pragma unroll
    for (int j = 1; j < 7; ++j) m = fmaxf(m, l[j]);
    float sum = 0.f;
#pragma unroll
    for (int j = 0; j < 7; ++j) { l[j] = __expf(l[j] - m); sum += l[j]; }
    float inv = 1.f / sum;
    float o0 = 0.f, o1 = 0.f;
#pragma unroll
    for (int j = 0; j < 7; ++j) {
        float a = l[j] * inv;
        o0 = fmaf(a, xl[(size_t)s[j] * 128 + lane], o0);
        o1 = fmaf(a, xl[(size_t)s[j] * 128 + 64 + lane], o1);
    }
    ch2[(size_t)dst * 256 + 128 + lane] = o0 + bias[lane];
    ch2[(size_t)dst * 256 + 192 + lane] = o1 + bias[64 + lane];
}

// ---------------------------------------------------------------- launch
extern "C" void kernel_launch(void* const* d_in, const int* in_sizes, int n_in,
                              void* d_out, int out_size, void* d_ws, size_t ws_size,
                              hipStream_t stream)
{
    const float* x      = (const float*)d_in[0];
    const int*   ei     = (const int*)  d_in[1];
    const float* eattr  = (const float*)d_in[2];
    const float* W_sl   = (const float*)d_in[4];
    const float* b_sl   = (const float*)d_in[5];
    const float* W_sr   = (const float*)d_in[6];
    const float* b_sr   = (const float*)d_in[7];
    const float* att_s  = (const float*)d_in[8];
    const float* W_se   = (const float*)d_in[9];
    const float* bias_s = (const float*)d_in[10];
    const float* W_ll   = (const float*)d_in[11];
    const float* b_ll   = (const float*)d_in[12];
    const float* W_lr   = (const float*)d_in[13];
    const float* b_lr   = (const float*)d_in[14];
    const float* att_l  = (const float*)d_in[15];
    const float* bias_l = (const float*)d_in[16];
    const float* W_c    = (const float*)d_in[17];
    const float* b_c    = (const float*)d_in[18];
    const float* W_f1   = (const float*)d_in[19];
    const float* b_f1   = (const float*)d_in[20];
    const float* W_f2   = (const float*)d_in[21];
    const float* b_f2   = (const float*)d_in[22];
    float* out = (float*)d_out;

    char* wp = (char*)d_ws;
    auto take = [&](size_t bytes) { char* p = wp; wp += (bytes + 255) & ~(size_t)255; return p; };
    float* xl_s    = (float*)take((size_t)N * D * 4);
    float* xr_s    = (float*)take((size_t)N * D * 4);
    float* xl_l    = (float*)take((size_t)N * D * 4);
    float* xr_l    = (float*)take((size_t)N * D * 4);
    float* ch2     = (float*)take((size_t)N * 2 * D * 4);
    float* sqn     = (float*)take((size_t)N * 4);
    int*   knn_idx = (int*)  take((size_t)N * KN * 4);
    int*   deg     = (int*)  take((size_t)N * 4);
    int*   rowptr  = (int*)  take((size_t)(N + 1) * 4);
    int*   csr_src = (int*)  take((size_t)E * 4);
    float* csr_ea  = (float*)take((size_t)E * 4);
    unsigned short* x_hi = (unsigned short*)take((size_t)N * D * 2);
    unsigned short* x_lo = (unsigned short*)take((size_t)N * D * 2);
    int*   knn_cand = (int*)take((size_t)N * NCAND * 4);
    float* fused   = xl_s;
    float* hbuf    = ch2;
    if ((size_t)(wp - (char*)d_ws) > ws_size) return;

    dim3 blk(256);

    // node transforms
    gemm_k<<<dim3(N / 64, 1), blk, 0, stream>>>(x, D, W_sl, D, b_sl, nullptr, xl_s, D, D, 0);
    gemm_k<<<dim3(N / 64, 1), blk, 0, stream>>>(x, D, W_sr, D, b_sr, nullptr, xr_s, D, D, 0);
    gemm_k<<<dim3(N / 64, 1), blk, 0, stream>>>(x, D, W_ll, D, b_ll, nullptr, xl_l, D, D, 0);
    gemm_k<<<dim3(N / 64, 1), blk, 0, stream>>>(x, D, W_lr, D, b_lr, nullptr, xr_l, D, D, 0);

    // kNN graph: bf16 MFMA prefilter (4 quarters tiling Sg) -> exact fp32 re-rank
    sqnorm_k<<<dim3(N / 4), blk, 0, stream>>>(x, sqn);
    cast_k<<<dim3((N * D) / (256 * 8)), blk, 0, stream>>>(x, x_hi, x_lo);
    knn_mfma_k<<<dim3(Bg * 40 * 4), blk, 0, stream>>>(x_hi, x_lo, sqn, knn_cand);
    knn_rerank_k<<<dim3((N + 255) / 256), blk, 0, stream>>>(x, sqn, knn_cand, knn_idx);

    // CSR of spatial edges by dst
    hipMemsetAsync(deg, 0, (size_t)N * 4, stream);
    hist_k<<<dim3(E / 256), blk, 0, stream>>>(ei + E, deg);
    scan_k<<<dim3(1), dim3(1024), 0, stream>>>(deg, rowptr);
    hipMemsetAsync(deg, 0, (size_t)N * 4, stream);
    scatter_k<<<dim3(E / 256), blk, 0, stream>>>(ei, ei + E, eattr, rowptr, deg, csr_src, csr_ea);

    // two GAT channels -> ch2 = [ch_sp | ch_lat]
    spatial_gat_k<<<dim3(N / 4), blk, 0, stream>>>(xl_s, xr_s, rowptr, csr_src, csr_ea,
                                                   att_s, W_se, bias_s, ch2);
    latent_gat_k<<<dim3(N / 4), blk, 0, stream>>>(xl_l, xr_l, knn_idx, att_l, bias_l, ch2);

    // fusion + FFN
    gemm_k<<<dim3(N / 64, 1), blk, 0, stream>>>(ch2, 2 * D, W_c, D, b_c, x, fused, D, 2 * D, 0);
    gemm_k<<<dim3(N / 64, 2), blk, 0, stream>>>(fused, D, W_f1, FF, b_f1, nullptr, hbuf, FF, D, 1);
    gemm_k<<<dim3(N / 64, 1), blk, 0, stream>>>(hbuf, FF, W_f2, D, b_f2, fused, out, D, FF, 1);
}

// Round 5
// 1041.082 us; speedup vs baseline: 1.2498x; 1.2498x over previous
//
#include <hip/hip_runtime.h>
#include <math.h>

// ---------------------------------------------------------------- constants
constexpr int N  = 40000;   // nodes
constexpr int D  = 128;     // latent dim
constexpr int E  = 640000;  // spatial edges
constexpr int Bg = 8;       // graphs
constexpr int Sg = 5000;    // nodes per graph
constexpr int KN = 6;       // knn
constexpr int FF = 256;     // ffn hidden
constexpr int LGCAP = 320;  // max in-degree supported in spatial GAT (actual ~45)
constexpr int QLEN = 1280;  // candidate quarter length (64-aligned); last quarter 1160
constexpr int NCAND = 48;   // 4 quarters x top-12

typedef short short8 __attribute__((ext_vector_type(8)));
typedef float f32x4  __attribute__((ext_vector_type(4)));

// ---------------------------------------------------------------- GEMM: out = A@W + bias (+res) (+relu6)
__global__ __launch_bounds__(256) void gemm_k(
    const float* __restrict__ A, int lda,
    const float* __restrict__ Wm, int ldw,
    const float* __restrict__ bias,
    const float* __restrict__ res,
    float* __restrict__ out, int ldo,
    int Kdim, int act)
{
    __shared__ float as[64][36];
    __shared__ float ws[32][128];
    int tid = threadIdx.x;
    int tr = tid >> 4, tc = tid & 15;
    int r0 = blockIdx.x * 64;
    int cb = blockIdx.y * 128;

    float acc[4][8];
#pragma unroll
    for (int j = 0; j < 4; ++j)
#pragma unroll
        for (int m = 0; m < 8; ++m) acc[j][m] = 0.f;

    for (int kt = 0; kt < Kdim; kt += 32) {
#pragma unroll
        for (int i = 0; i < 2; ++i) {
            int c2 = i * 256 + tid;
            int row = c2 >> 3, k4 = (c2 & 7) * 4;
            *(float4*)&as[row][k4] = *(const float4*)&A[(size_t)(r0 + row) * lda + kt + k4];
        }
#pragma unroll
        for (int i = 0; i < 4; ++i) {
            int c2 = i * 256 + tid;
            int row = c2 >> 5, c4 = (c2 & 31) * 4;
            *(float4*)&ws[row][c4] = *(const float4*)&Wm[(size_t)(kt + row) * ldw + cb + c4];
        }
        __syncthreads();
#pragma unroll 8
        for (int k = 0; k < 32; ++k) {
            float a[4], b[8];
#pragma unroll
            for (int j = 0; j < 4; ++j) a[j] = as[tr + 16 * j][k];
#pragma unroll
            for (int m = 0; m < 8; ++m) b[m] = ws[k][tc + 16 * m];
#pragma unroll
            for (int j = 0; j < 4; ++j)
#pragma unroll
                for (int m = 0; m < 8; ++m) acc[j][m] = fmaf(a[j], b[m], acc[j][m]);
        }
        __syncthreads();
    }
#pragma unroll
    for (int j = 0; j < 4; ++j) {
        int r = r0 + tr + 16 * j;
#pragma unroll
        for (int m = 0; m < 8; ++m) {
            int c = tc + 16 * m;
            float v = acc[j][m] + bias[cb + c];
            if (res) v += res[(size_t)r * 128 + c];
            if (act) v = fminf(fmaxf(v, 0.f), 6.f);
            out[(size_t)r * ldo + cb + c] = v;
        }
    }
}

// ---------------------------------------------------------------- per-row squared norm (wave per row)
__global__ __launch_bounds__(256) void sqnorm_k(const float* __restrict__ x, float* __restrict__ sqn)
{
    int w = threadIdx.x >> 6, lane = threadIdx.x & 63;
    int row = blockIdx.x * 4 + w;
    float v0 = x[(size_t)row * 128 + lane];
    float v1 = x[(size_t)row * 128 + 64 + lane];
    float s = v0 * v0 + v1 * v1;
#pragma unroll
    for (int off = 32; off; off >>= 1) s += __shfl_xor(s, off);
    if (lane == 0) sqn[row] = s;
}

// ---------------------------------------------------------------- x -> bf16 hi/lo split
__device__ __forceinline__ unsigned short f2bf(float f)
{
    unsigned int u = __float_as_uint(f);
    return (unsigned short)((u + 0x7fffu + ((u >> 16) & 1u)) >> 16);
}

__global__ __launch_bounds__(256) void cast_k(const float* __restrict__ x,
                                              unsigned short* __restrict__ xh,
                                              unsigned short* __restrict__ xl)
{
    size_t i = ((size_t)blockIdx.x * 256 + threadIdx.x) * 8;
    float4 v0 = *(const float4*)&x[i];
    float4 v1 = *(const float4*)&x[i + 4];
    float f[8] = {v0.x, v0.y, v0.z, v0.w, v1.x, v1.y, v1.z, v1.w};
    short8 hv, lv;
#pragma unroll
    for (int j = 0; j < 8; ++j) {
        unsigned short h = f2bf(f[j]);
        float hf = __uint_as_float(((unsigned int)h) << 16);
        hv[j] = (short)h;
        lv[j] = (short)f2bf(f[j] - hf);
    }
    *(short8*)&xh[i] = hv;
    *(short8*)&xl[i] = lv;
}

// ---------------------------------------------------------------- kNN prefilter via MFMA
// grid: 8 graphs x 40 query-blocks(128q) x 4 candidate-quarters (64-aligned,
// quarters tile the FULL Sg=5000: 1280/1280/1280/1160).
// block: 4 waves; wave w owns 32 queries (2 sets of 16 = mfma N dim).
// candidate tiles of 64 staged in LDS (hi only, XOR-swizzled rows).
// terms kept: cand_hi*(q_hi + q_lo); cand_lo dropped (err ~0.05 << margin).
// per-lane top-8 over its candidate stream -> shfl-merge -> top-12/quarter.
__global__ __launch_bounds__(256) void knn_mfma_k(const unsigned short* __restrict__ xh,
                                                  const unsigned short* __restrict__ xl,
                                                  const float* __restrict__ sqn,
                                                  int* __restrict__ cand)
{
    __shared__ char lds[16640];               // 16KB hi tile + 256B csq
    char* ldsH = lds;
    float* cs_s = (float*)(lds + 16384);

    int b = blockIdx.x;
    int g = b & 7, r = b >> 3;                // g == XCD id -> per-graph L2 locality
    int qtr = r & 3, qblk = r >> 2;
    int gbase = g * Sg;
    int cbase = qtr * QLEN;
    int qlen = (qtr < 3) ? QLEN : (Sg - 3 * QLEN);   // 1160 for last quarter
    int ntiles = (qlen + 63) >> 6;                    // 20/20/20/19
    int tid = threadIdx.x;
    int w = tid >> 6, lane = tid & 63;
    int lg = lane >> 4, ln = lane & 15;
    int q0 = qblk * 128 + w * 32;

    // resident query B-frags: [qset][kstep], hi+lo
    short8 bh[2][4], bl[2][4];
#pragma unroll
    for (int s = 0; s < 2; ++s) {
        int q = q0 + s * 16 + ln;
        int qrow = gbase + (q < Sg ? q : Sg - 1);
#pragma unroll
        for (int ks = 0; ks < 4; ++ks) {
            bh[s][ks] = *(const short8*)&xh[(size_t)qrow * 128 + ks * 32 + lg * 8];
            bl[s][ks] = *(const short8*)&xl[(size_t)qrow * 128 + ks * 32 + lg * 8];
        }
    }

    float d8[2][8]; int i8[2][8]; float mx[2]; int sl[2];
#pragma unroll
    for (int s = 0; s < 2; ++s) {
        mx[s] = __builtin_inff(); sl[s] = 0;
#pragma unroll
        for (int t = 0; t < 8; ++t) { d8[s][t] = __builtin_inff(); i8[s][t] = -1; }
    }

    for (int t64 = 0; t64 < ntiles; ++t64) {
        int c0 = cbase + t64 * 64;            // graph-relative
        __syncthreads();
        // stage 64 cand hi rows (row clamp keeps tail reads in-bounds),
        // swizzled: byte ^= (row&7)<<4
#pragma unroll
        for (int i = 0; i < 4; ++i) {
            int c = i * 256 + tid;            // 1024 chunks of 16B
            int row = c >> 4, slot = c & 15;
            int cr = c0 + row;
            if (cr >= Sg) cr = Sg - 1;
            short8 vh = *(const short8*)&xh[(size_t)(gbase + cr) * 128 + slot * 8];
            *(short8*)(ldsH + row * 256 + ((slot * 16) ^ ((row & 7) << 4))) = vh;
        }
        if (tid < 64) {
            int cl = c0 + tid;
            cs_s[tid] = (cl < cbase + qlen) ? sqn[gbase + cl] : __builtin_inff();
        }
        __syncthreads();

#pragma unroll
        for (int g16 = 0; g16 < 4; ++g16) {
            f32x4 acc0 = {0.f, 0.f, 0.f, 0.f};
            f32x4 acc1 = {0.f, 0.f, 0.f, 0.f};
            int rr = g16 * 16 + ln;
            int rsw = (rr & 7) << 4;
#pragma unroll
            for (int ks = 0; ks < 4; ++ks) {
                short8 ah = *(const short8*)(ldsH + rr * 256 + ((lg * 16 + ks * 64) ^ rsw));
                acc0 = __builtin_amdgcn_mfma_f32_16x16x32_bf16(ah, bh[0][ks], acc0, 0, 0, 0);
                acc0 = __builtin_amdgcn_mfma_f32_16x16x32_bf16(ah, bl[0][ks], acc0, 0, 0, 0);
                acc1 = __builtin_amdgcn_mfma_f32_16x16x32_bf16(ah, bh[1][ks], acc1, 0, 0, 0);
                acc1 = __builtin_amdgcn_mfma_f32_16x16x32_bf16(ah, bl[1][ks], acc1, 0, 0, 0);
            }
            f32x4 cv = *(const f32x4*)&cs_s[g16 * 16 + lg * 4];
#pragma unroll
            for (int s = 0; s < 2; ++s) {
                const f32x4& ac = s ? acc1 : acc0;
                bool ov = (c0 + g16 * 16) == (q0 + s * 16);  // 16-aligned ranges
#pragma unroll
                for (int rg = 0; rg < 4; ++rg) {
                    float dv = fmaf(-2.f, ac[rg], cv[rg]);
                    bool skip = ov && (lg * 4 + rg == ln);   // self-pair
                    if (!skip && dv < mx[s]) {
#pragma unroll
                        for (int t = 0; t < 8; ++t)
                            if (t == sl[s]) { d8[s][t] = dv; i8[s][t] = gbase + c0 + g16 * 16 + lg * 4 + rg; }
                        float m2 = d8[s][0]; int s2 = 0;
#pragma unroll
                        for (int t = 1; t < 8; ++t)
                            if (d8[s][t] > m2) { m2 = d8[s][t]; s2 = t; }
                        mx[s] = m2; sl[s] = s2;
                    }
                }
            }
        }
    }

    // in-wave merge: partials for query (s, ln) live in lanes ln + 16*lg.
#pragma unroll
    for (int s = 0; s < 2; ++s) {
        float d12[12]; int i12[12];
#pragma unroll
        for (int t = 0; t < 8; ++t) { d12[t] = d8[s][t]; i12[t] = i8[s][t]; }
#pragma unroll
        for (int t = 8; t < 12; ++t) { d12[t] = __builtin_inff(); i12[t] = -1; }
        float m12 = __builtin_inff(); int s12 = 8;
#pragma unroll
        for (int sg = 1; sg < 4; ++sg) {
#pragma unroll
            for (int t = 0; t < 8; ++t) {
                float dv = __shfl(d8[s][t], ln + sg * 16);
                int ci = __shfl(i8[s][t], ln + sg * 16);
                if (dv < m12) {
#pragma unroll
                    for (int u = 0; u < 12; ++u)
                        if (u == s12) { d12[u] = dv; i12[u] = ci; }
                    float m2 = d12[0]; int s2 = 0;
#pragma unroll
                    for (int u = 1; u < 12; ++u)
                        if (d12[u] > m2) { m2 = d12[u]; s2 = u; }
                    m12 = m2; s12 = s2;
                }
            }
        }
        int q = q0 + s * 16 + ln;
        if (lg == 0 && q < Sg) {
            int* cp = &cand[(size_t)(gbase + q) * NCAND + qtr * 12];
#pragma unroll
            for (int t = 0; t < 12; ++t) cp[t] = i12[t];
        }
    }
}

// ---------------------------------------------------------------- exact fp32 re-rank, wave per query
// lane l holds xq[2l:2l+2]; per candidate: coalesced row read (float2/lane),
// shfl_xor tree reduce -> wave-uniform dv -> uniform top-6 insert.
__global__ __launch_bounds__(256) void knn_rerank_k(const float* __restrict__ x,
                                                    const float* __restrict__ sqn,
                                                    const int* __restrict__ cand,
                                                    int* __restrict__ knn_idx)
{
    int w = threadIdx.x >> 6, lane = threadIdx.x & 63;
    int q = blockIdx.x * 4 + w;
    float2 qv = *(const float2*)&x[(size_t)q * 128 + lane * 2];
    const int* cp = &cand[(size_t)q * NCAND];

    float d6[6]; int i6[6]; float mx = __builtin_inff(); int sl = 0;
#pragma unroll
    for (int t = 0; t < 6; ++t) { d6[t] = __builtin_inff(); i6[t] = -1; }

    for (int j = 0; j < NCAND; ++j) {
        int c = cp[j];                         // wave-uniform broadcast load
        if (c < 0) continue;
        float2 cv = *(const float2*)&x[(size_t)c * 128 + lane * 2];
        float p = fmaf(qv.y, cv.y, qv.x * cv.x);
#pragma unroll
        for (int off = 32; off; off >>= 1) p += __shfl_xor(p, off);
        float dv = fmaf(-2.f, p, sqn[c]);      // wave-uniform
        if (dv < mx) {                         // uniform across lanes -> no divergence
#pragma unroll
            for (int t = 0; t < 6; ++t)
                if (t == sl) { d6[t] = dv; i6[t] = c; }
            float m2 = d6[0]; int s2 = 0;
#pragma unroll
            for (int t = 1; t < 6; ++t)
                if (d6[t] > m2) { m2 = d6[t]; s2 = t; }
            mx = m2; sl = s2;
        }
    }
    if (lane < 6) {
        int v;
#pragma unroll
        for (int t = 0; t < 6; ++t) if (t == lane) v = i6[t];
        knn_idx[(size_t)q * 6 + lane] = v;
    }
}

// ---------------------------------------------------------------- CSR build
__global__ __launch_bounds__(256) void hist_k(const int* __restrict__ dstA, int* __restrict__ deg)
{
    int e = blockIdx.x * 256 + threadIdx.x;
    atomicAdd(&deg[dstA[e]], 1);
}

__global__ __launch_bounds__(1024) void scan_k(const int* __restrict__ deg, int* __restrict__ rowptr)
{
    __shared__ int ps[1024];
    int t = threadIdx.x;
    const int chunk = 40;
    int base = t * chunk;
    int s = 0;
    for (int k = 0; k < chunk; ++k) { int i = base + k; if (i < N) s += deg[i]; }
    ps[t] = s;
    __syncthreads();
    for (int off = 1; off < 1024; off <<= 1) {
        int v = (t >= off) ? ps[t - off] : 0;
        __syncthreads();
        ps[t] += v;
        __syncthreads();
    }
    int run = ps[t] - s;
    for (int k = 0; k < chunk; ++k) {
        int i = base + k;
        if (i < N) { rowptr[i] = run; run += deg[i]; }
    }
    if (t == 0) rowptr[N] = E;
}

__global__ __launch_bounds__(256) void scatter_k(const int* __restrict__ srcA, const int* __restrict__ dstA,
                                                 const float* __restrict__ ea,
                                                 const int* __restrict__ rowptr, int* __restrict__ cnt,
                                                 int* __restrict__ csr_src, float* __restrict__ csr_ea)
{
    int e = blockIdx.x * 256 + threadIdx.x;
    int d = dstA[e];
    int pos = rowptr[d] + atomicAdd(&cnt[d], 1);
    csr_src[pos] = srcA[e];
    csr_ea[pos] = ea[e];
}

// ---------------------------------------------------------------- spatial GATv2 (wave per dst node)
__global__ __launch_bounds__(256) void spatial_gat_k(
    const float* __restrict__ xl, const float* __restrict__ xr,
    const int* __restrict__ rowptr, const int* __restrict__ csr_src, const float* __restrict__ csr_ea,
    const float* __restrict__ att, const float* __restrict__ wse, const float* __restrict__ bias,
    float* __restrict__ ch2)
{
    __shared__ float lg[4][LGCAP];
    int w = threadIdx.x >> 6, lane = threadIdx.x & 63;
    int dst = blockIdx.x * 4 + w;
    int base = rowptr[dst];
    int deg = rowptr[dst + 1] - base;
    if (deg > LGCAP) deg = LGCAP;
    float xr0 = xr[(size_t)dst * 128 + lane], xr1 = xr[(size_t)dst * 128 + 64 + lane];
    float at0 = att[lane], at1 = att[64 + lane];
    float we0 = wse[lane], we1 = wse[64 + lane];
    float m = -1e30f;
    for (int i = 0; i < deg; ++i) {
        int s = csr_src[base + i];
        float ea = csr_ea[base + i];
        float h0 = xl[(size_t)s * 128 + lane] + xr0 + ea * we0;
        float h1 = xl[(size_t)s * 128 + 64 + lane] + xr1 + ea * we1;
        h0 = h0 > 0.f ? h0 : 0.2f * h0;
        h1 = h1 > 0.f ? h1 : 0.2f * h1;
        float p = h0 * at0 + h1 * at1;
#pragma unroll
        for (int off = 32; off; off >>= 1) p += __shfl_xor(p, off);
        if (lane == 0) lg[w][i] = p;
        m = fmaxf(m, p);
    }
    __syncthreads();
    float sum = 0.f;
    for (int i = lane; i < deg; i += 64) {
        float ev = __expf(lg[w][i] - m);
        lg[w][i] = ev;
        sum += ev;
    }
#pragma unroll
    for (int off = 32; off; off >>= 1) sum += __shfl_xor(sum, off);
    float inv = 1.f / sum;
    __syncthreads();
    float o0 = 0.f, o1 = 0.f;
    for (int i = 0; i < deg; ++i) {
        float a = lg[w][i] * inv;
        int s = csr_src[base + i];
        o0 = fmaf(a, xl[(size_t)s * 128 + lane], o0);
        o1 = fmaf(a, xl[(size_t)s * 128 + 64 + lane], o1);
    }
    ch2[(size_t)dst * 256 + lane] = o0 + bias[lane];
    ch2[(size_t)dst * 256 + 64 + lane] = o1 + bias[64 + lane];
}

// ---------------------------------------------------------------- latent GATv2 (wave per dst; 6 knn + self)
__global__ __launch_bounds__(256) void latent_gat_k(
    const float* __restrict__ xl, const float* __restrict__ xr,
    const int* __restrict__ knn, const float* __restrict__ att,
    const float* __restrict__ bias, float* __restrict__ ch2)
{
    int w = threadIdx.x >> 6, lane = threadIdx.x & 63;
    int dst = blockIdx.x * 4 + w;
    float xr0 = xr[(size_t)dst * 128 + lane], xr1 = xr[(size_t)dst * 128 + 64 + lane];
    float at0 = att[lane], at1 = att[64 + lane];
    int s[7];
#pragma unroll
    for (int j = 0; j < 6; ++j) s[j] = knn[(size_t)dst * 6 + j];
    s[6] = dst;
    float l[7];
#pragma unroll
    for (int j = 0; j < 7; ++j) {
        float h0 = xl[(size_t)s[j] * 128 + lane] + xr0;
        float h1 = xl[(size_t)s[j] * 128 + 64 + lane] + xr1;
        h0 = h0 > 0.f ? h0 : 0.2f * h0;
        h1 = h1 > 0.f ? h1 : 0.2f * h1;
        float p = h0 * at0 + h1 * at1;
#pragma unroll
        for (int off = 32; off; off >>= 1) p += __shfl_xor(p, off);
        l[j] = p;
    }
    float m = l[0];
#pragma unroll
    for (int j = 1; j < 7; ++j) m = fmaxf(m, l[j]);
    float sum = 0.f;
#pragma unroll
    for (int j = 0; j < 7; ++j) { l[j] = __expf(l[j] - m); sum += l[j]; }
    float inv = 1.f / sum;
    float o0 = 0.f, o1 = 0.f;
#pragma unroll
    for (int j = 0; j < 7; ++j) {
        float a = l[j] * inv;
        o0 = fmaf(a, xl[(size_t)s[j] * 128 + lane], o0);
        o1 = fmaf(a, xl[(size_t)s[j] * 128 + 64 + lane], o1);
    }
    ch2[(size_t)dst * 256 + 128 + lane] = o0 + bias[lane];
    ch2[(size_t)dst * 256 + 192 + lane] = o1 + bias[64 + lane];
}

// ---------------------------------------------------------------- launch
extern "C" void kernel_launch(void* const* d_in, const int* in_sizes, int n_in,
                              void* d_out, int out_size, void* d_ws, size_t ws_size,
                              hipStream_t stream)
{
    const float* x      = (const float*)d_in[0];
    const int*   ei     = (const int*)  d_in[1];
    const float* eattr  = (const float*)d_in[2];
    const float* W_sl   = (const float*)d_in[4];
    const float* b_sl   = (const float*)d_in[5];
    const float* W_sr   = (const float*)d_in[6];
    const float* b_sr   = (const float*)d_in[7];
    const float* att_s  = (const float*)d_in[8];
    const float* W_se   = (const float*)d_in[9];
    const float* bias_s = (const float*)d_in[10];
    const float* W_ll   = (const float*)d_in[11];
    const float* b_ll   = (const float*)d_in[12];
    const float* W_lr   = (const float*)d_in[13];
    const float* b_lr   = (const float*)d_in[14];
    const float* att_l  = (const float*)d_in[15];
    const float* bias_l = (const float*)d_in[16];
    const float* W_c    = (const float*)d_in[17];
    const float* b_c    = (const float*)d_in[18];
    const float* W_f1   = (const float*)d_in[19];
    const float* b_f1   = (const float*)d_in[20];
    const float* W_f2   = (const float*)d_in[21];
    const float* b_f2   = (const float*)d_in[22];
    float* out = (float*)d_out;

    char* wp = (char*)d_ws;
    auto take = [&](size_t bytes) { char* p = wp; wp += (bytes + 255) & ~(size_t)255; return p; };
    float* xl_s    = (float*)take((size_t)N * D * 4);
    float* xr_s    = (float*)take((size_t)N * D * 4);
    float* xl_l    = (float*)take((size_t)N * D * 4);
    float* xr_l    = (float*)take((size_t)N * D * 4);
    float* ch2     = (float*)take((size_t)N * 2 * D * 4);
    float* sqn     = (float*)take((size_t)N * 4);
    int*   knn_idx = (int*)  take((size_t)N * KN * 4);
    int*   deg     = (int*)  take((size_t)N * 4);
    int*   rowptr  = (int*)  take((size_t)(N + 1) * 4);
    int*   csr_src = (int*)  take((size_t)E * 4);
    float* csr_ea  = (float*)take((size_t)E * 4);
    unsigned short* x_hi = (unsigned short*)take((size_t)N * D * 2);
    unsigned short* x_lo = (unsigned short*)take((size_t)N * D * 2);
    int*   knn_cand = (int*)take((size_t)N * NCAND * 4);
    float* fused   = xl_s;
    float* hbuf    = ch2;
    if ((size_t)(wp - (char*)d_ws) > ws_size) return;

    dim3 blk(256);

    // node transforms
    gemm_k<<<dim3(N / 64, 1), blk, 0, stream>>>(x, D, W_sl, D, b_sl, nullptr, xl_s, D, D, 0);
    gemm_k<<<dim3(N / 64, 1), blk, 0, stream>>>(x, D, W_sr, D, b_sr, nullptr, xr_s, D, D, 0);
    gemm_k<<<dim3(N / 64, 1), blk, 0, stream>>>(x, D, W_ll, D, b_ll, nullptr, xl_l, D, D, 0);
    gemm_k<<<dim3(N / 64, 1), blk, 0, stream>>>(x, D, W_lr, D, b_lr, nullptr, xr_l, D, D, 0);

    // kNN graph: bf16 MFMA prefilter (4 quarters tiling Sg) -> exact fp32 re-rank
    sqnorm_k<<<dim3(N / 4), blk, 0, stream>>>(x, sqn);
    cast_k<<<dim3((N * D) / (256 * 8)), blk, 0, stream>>>(x, x_hi, x_lo);
    knn_mfma_k<<<dim3(Bg * 40 * 4), blk, 0, stream>>>(x_hi, x_lo, sqn, knn_cand);
    knn_rerank_k<<<dim3(N / 4), blk, 0, stream>>>(x, sqn, knn_cand, knn_idx);

    // CSR of spatial edges by dst
    hipMemsetAsync(deg, 0, (size_t)N * 4, stream);
    hist_k<<<dim3(E / 256), blk, 0, stream>>>(ei + E, deg);
    scan_k<<<dim3(1), dim3(1024), 0, stream>>>(deg, rowptr);
    hipMemsetAsync(deg, 0, (size_t)N * 4, stream);
    scatter_k<<<dim3(E / 256), blk, 0, stream>>>(ei, ei + E, eattr, rowptr, deg, csr_src, csr_ea);

    // two GAT channels -> ch2 = [ch_sp | ch_lat]
    spatial_gat_k<<<dim3(N / 4), blk, 0, stream>>>(xl_s, xr_s, rowptr, csr_src, csr_ea,
                                                   att_s, W_se, bias_s, ch2);
    latent_gat_k<<<dim3(N / 4), blk, 0, stream>>>(xl_l, xr_l, knn_idx, att_l, bias_l, ch2);

    // fusion + FFN
    gemm_k<<<dim3(N / 64, 1), blk, 0, stream>>>(ch2, 2 * D, W_c, D, b_c, x, fused, D, 2 * D, 0);
    gemm_k<<<dim3(N / 64, 2), blk, 0, stream>>>(fused, D, W_f1, FF, b_f1, nullptr, hbuf, FF, D, 1);
    gemm_k<<<dim3(N / 64, 1), blk, 0, stream>>>(hbuf, FF, W_f2, D, b_f2, fused, out, D, FF, 1);
}

// Round 6
// 805.086 us; speedup vs baseline: 1.6161x; 1.2931x over previous
//
#include <hip/hip_runtime.h>
#include <math.h>

// ---------------------------------------------------------------- constants
constexpr int N  = 40000;   // nodes
constexpr int D  = 128;     // latent dim
constexpr int E  = 640000;  // spatial edges
constexpr int Bg = 8;       // graphs
constexpr int Sg = 5000;    // nodes per graph
constexpr int KN = 6;       // knn
constexpr int FF = 256;     // ffn hidden
constexpr int LGCAP = 320;  // max in-degree supported in spatial GAT (actual ~45)
constexpr int QLEN = 1280;  // candidate quarter length (64-aligned); last 1160
constexpr int NCAND = 48;   // 4 quarters x top-12

typedef short short8 __attribute__((ext_vector_type(8)));
typedef float f32x4  __attribute__((ext_vector_type(4)));

// ---------------------------------------------------------------- GEMM: out = A@W + bias (+res) (+relu6)
__global__ __launch_bounds__(256) void gemm_k(
    const float* __restrict__ A, int lda,
    const float* __restrict__ Wm, int ldw,
    const float* __restrict__ bias,
    const float* __restrict__ res,
    float* __restrict__ out, int ldo,
    int Kdim, int act)
{
    __shared__ float as[64][36];
    __shared__ float ws[32][128];
    int tid = threadIdx.x;
    int tr = tid >> 4, tc = tid & 15;
    int r0 = blockIdx.x * 64;
    int cb = blockIdx.y * 128;

    float acc[4][8];
#pragma unroll
    for (int j = 0; j < 4; ++j)
#pragma unroll
        for (int m = 0; m < 8; ++m) acc[j][m] = 0.f;

    for (int kt = 0; kt < Kdim; kt += 32) {
#pragma unroll
        for (int i = 0; i < 2; ++i) {
            int c2 = i * 256 + tid;
            int row = c2 >> 3, k4 = (c2 & 7) * 4;
            *(float4*)&as[row][k4] = *(const float4*)&A[(size_t)(r0 + row) * lda + kt + k4];
        }
#pragma unroll
        for (int i = 0; i < 4; ++i) {
            int c2 = i * 256 + tid;
            int row = c2 >> 5, c4 = (c2 & 31) * 4;
            *(float4*)&ws[row][c4] = *(const float4*)&Wm[(size_t)(kt + row) * ldw + cb + c4];
        }
        __syncthreads();
#pragma unroll 8
        for (int k = 0; k < 32; ++k) {
            float a[4], b[8];
#pragma unroll
            for (int j = 0; j < 4; ++j) a[j] = as[tr + 16 * j][k];
#pragma unroll
            for (int m = 0; m < 8; ++m) b[m] = ws[k][tc + 16 * m];
#pragma unroll
            for (int j = 0; j < 4; ++j)
#pragma unroll
                for (int m = 0; m < 8; ++m) acc[j][m] = fmaf(a[j], b[m], acc[j][m]);
        }
        __syncthreads();
    }
#pragma unroll
    for (int j = 0; j < 4; ++j) {
        int r = r0 + tr + 16 * j;
#pragma unroll
        for (int m = 0; m < 8; ++m) {
            int c = tc + 16 * m;
            float v = acc[j][m] + bias[cb + c];
            if (res) v += res[(size_t)r * 128 + c];
            if (act) v = fminf(fmaxf(v, 0.f), 6.f);
            out[(size_t)r * ldo + cb + c] = v;
        }
    }
}

// ---------------------------------------------------------------- fused 4x node-transform GEMM (x shared A)
__global__ __launch_bounds__(256) void gemm4_k(
    const float* __restrict__ A,
    const float* __restrict__ W0, const float* __restrict__ W1,
    const float* __restrict__ W2, const float* __restrict__ W3,
    const float* __restrict__ b0, const float* __restrict__ b1,
    const float* __restrict__ b2, const float* __restrict__ b3,
    float* __restrict__ o0, float* __restrict__ o1,
    float* __restrict__ o2, float* __restrict__ o3)
{
    const float* Wm; const float* bias; float* out;
    if (blockIdx.y == 0)      { Wm = W0; bias = b0; out = o0; }
    else if (blockIdx.y == 1) { Wm = W1; bias = b1; out = o1; }
    else if (blockIdx.y == 2) { Wm = W2; bias = b2; out = o2; }
    else                      { Wm = W3; bias = b3; out = o3; }

    __shared__ float as[64][36];
    __shared__ float ws[32][128];
    int tid = threadIdx.x;
    int tr = tid >> 4, tc = tid & 15;
    int r0 = blockIdx.x * 64;

    float acc[4][8];
#pragma unroll
    for (int j = 0; j < 4; ++j)
#pragma unroll
        for (int m = 0; m < 8; ++m) acc[j][m] = 0.f;

    for (int kt = 0; kt < 128; kt += 32) {
#pragma unroll
        for (int i = 0; i < 2; ++i) {
            int c2 = i * 256 + tid;
            int row = c2 >> 3, k4 = (c2 & 7) * 4;
            *(float4*)&as[row][k4] = *(const float4*)&A[(size_t)(r0 + row) * 128 + kt + k4];
        }
#pragma unroll
        for (int i = 0; i < 4; ++i) {
            int c2 = i * 256 + tid;
            int row = c2 >> 5, c4 = (c2 & 31) * 4;
            *(float4*)&ws[row][c4] = *(const float4*)&Wm[(size_t)(kt + row) * 128 + c4];
        }
        __syncthreads();
#pragma unroll 8
        for (int k = 0; k < 32; ++k) {
            float a[4], b[8];
#pragma unroll
            for (int j = 0; j < 4; ++j) a[j] = as[tr + 16 * j][k];
#pragma unroll
            for (int m = 0; m < 8; ++m) b[m] = ws[k][tc + 16 * m];
#pragma unroll
            for (int j = 0; j < 4; ++j)
#pragma unroll
                for (int m = 0; m < 8; ++m) acc[j][m] = fmaf(a[j], b[m], acc[j][m]);
        }
        __syncthreads();
    }
#pragma unroll
    for (int j = 0; j < 4; ++j) {
        int r = r0 + tr + 16 * j;
#pragma unroll
        for (int m = 0; m < 8; ++m) {
            int c = tc + 16 * m;
            out[(size_t)r * 128 + c] = acc[j][m] + bias[c];
        }
    }
}

// ---------------------------------------------------------------- prep: sqnorm + bf16-hi cast (one x pass)
__device__ __forceinline__ unsigned short f2bf(float f)
{
    unsigned int u = __float_as_uint(f);
    return (unsigned short)((u + 0x7fffu + ((u >> 16) & 1u)) >> 16);
}

__global__ __launch_bounds__(256) void prep_k(const float* __restrict__ x,
                                              unsigned short* __restrict__ xh,
                                              float* __restrict__ sqn)
{
    int w = threadIdx.x >> 6, lane = threadIdx.x & 63;
    int row = blockIdx.x * 4 + w;
    float2 v = *(const float2*)&x[(size_t)row * 128 + lane * 2];
    ushort2 h = make_ushort2(f2bf(v.x), f2bf(v.y));
    *(ushort2*)&xh[(size_t)row * 128 + lane * 2] = h;
    float s = fmaf(v.y, v.y, v.x * v.x);
#pragma unroll
    for (int off = 32; off; off >>= 1) s += __shfl_xor(s, off);
    if (lane == 0) sqn[row] = s;
}

// ---------------------------------------------------------------- branchless sorted insert (ascending u32)
__device__ __forceinline__ void ins6(unsigned (&d)[6], unsigned k)
{
#pragma unroll
    for (int t = 0; t < 6; ++t) {
        unsigned lo = d[t] < k ? d[t] : k;
        unsigned hi = d[t] < k ? k : d[t];
        d[t] = lo; k = hi;
    }
}

// ---------------------------------------------------------------- kNN prefilter via MFMA, branchless selection
// grid: 8 graphs x 40 query-blocks(128q) x 4 quarters (1280/1280/1280/1160).
// wave owns 32 queries (2 x 16 = mfma N dim); cands tiled 64/LDS (hi, swizzled).
// scores pure-bf16 (hi*hi); err ~0.1 << order-stat gaps; exact fp32 re-rank after.
// per-lane sorted top-6 packed keys -> shfl-merge -> top-12/quarter.
__global__ __launch_bounds__(256) void knn_mfma_k(const unsigned short* __restrict__ xh,
                                                  const float* __restrict__ sqn,
                                                  int* __restrict__ cand)
{
    __shared__ char lds[16640];               // 16KB hi tile + 256B biased csq
    char* ldsH = lds;
    float* cs_s = (float*)(lds + 16384);

    int b = blockIdx.x;
    int g = b & 7, r = b >> 3;                // g == XCD id -> per-graph L2 locality
    int qtr = r & 3, qblk = r >> 2;
    int gbase = g * Sg;
    int cbase = qtr * QLEN;
    int qlen = (qtr < 3) ? QLEN : (Sg - 3 * QLEN);   // 1160 last
    int ntiles = (qlen + 63) >> 6;                    // 20/20/20/19
    int tid = threadIdx.x;
    int w = tid >> 6, lane = tid & 63;
    int lg = lane >> 4, ln = lane & 15;
    int q0 = qblk * 128 + w * 32;

    // resident query B-frags (hi only): [qset][kstep]
    short8 bh[2][4];
#pragma unroll
    for (int s = 0; s < 2; ++s) {
        int q = q0 + s * 16 + ln;
        int qrow = gbase + (q < Sg ? q : Sg - 1);
#pragma unroll
        for (int ks = 0; ks < 4; ++ks)
            bh[s][ks] = *(const short8*)&xh[(size_t)qrow * 128 + ks * 32 + lg * 8];
    }

    unsigned d6a[6], d6b[6];
#pragma unroll
    for (int t = 0; t < 6; ++t) { d6a[t] = 0xFFFFFFFFu; d6b[t] = 0xFFFFFFFFu; }

    for (int t64 = 0; t64 < ntiles; ++t64) {
        int c0 = cbase + t64 * 64;            // graph-relative
        __syncthreads();
        // stage 64 cand hi rows, swizzled: byte ^= (row&7)<<4
#pragma unroll
        for (int i = 0; i < 4; ++i) {
            int c = i * 256 + tid;            // 1024 chunks of 16B
            int row = c >> 4, slot = c & 15;
            int cr = c0 + row;
            if (cr >= Sg) cr = Sg - 1;
            short8 vh = *(const short8*)&xh[(size_t)(gbase + cr) * 128 + slot * 8];
            *(short8*)(ldsH + row * 256 + ((slot * 16) ^ ((row & 7) << 4))) = vh;
        }
        if (tid < 64) {
            int cl = c0 + tid;
            cs_s[tid] = (cl < cbase + qlen) ? (sqn[gbase + cl] + 1024.0f) : __builtin_inff();
        }
        __syncthreads();

#pragma unroll
        for (int g16 = 0; g16 < 4; ++g16) {
            f32x4 acc0 = {0.f, 0.f, 0.f, 0.f};
            f32x4 acc1 = {0.f, 0.f, 0.f, 0.f};
            int rr = g16 * 16 + ln;
            int rsw = (rr & 7) << 4;
#pragma unroll
            for (int ks = 0; ks < 4; ++ks) {
                short8 ah = *(const short8*)(ldsH + rr * 256 + ((lg * 16 + ks * 64) ^ rsw));
                acc0 = __builtin_amdgcn_mfma_f32_16x16x32_bf16(ah, bh[0][ks], acc0, 0, 0, 0);
                acc1 = __builtin_amdgcn_mfma_f32_16x16x32_bf16(ah, bh[1][ks], acc1, 0, 0, 0);
            }
            f32x4 cv = *(const f32x4*)&cs_s[g16 * 16 + lg * 4];   // biased +1024
            int idx0 = (c0 - cbase) + g16 * 16 + lg * 4;          // quarter-local, 11 bits
#pragma unroll
            for (int rg = 0; rg < 4; ++rg) {
                float kf0 = fmaf(-2.f, acc0[rg], cv[rg]);
                float kf1 = fmaf(-2.f, acc1[rg], cv[rg]);
                unsigned ki = (unsigned)(idx0 + rg);
                ins6(d6a, (__float_as_uint(kf0) & 0xFFFFF800u) | ki);
                ins6(d6b, (__float_as_uint(kf1) & 0xFFFFF800u) | ki);
            }
        }
    }

    // in-wave merge: partials for query (s, ln) live in lanes ln + 16*lg.
#pragma unroll
    for (int s = 0; s < 2; ++s) {
        unsigned m12[12];
#pragma unroll
        for (int t = 0; t < 6; ++t) m12[t] = s ? d6b[t] : d6a[t];
#pragma unroll
        for (int t = 6; t < 12; ++t) m12[t] = 0xFFFFFFFFu;
#pragma unroll
        for (int sg = 1; sg < 4; ++sg)
#pragma unroll
            for (int t = 0; t < 6; ++t) {
                unsigned v = __shfl(s ? d6b[t] : d6a[t], ln + sg * 16);
#pragma unroll
                for (int u = 0; u < 12; ++u) {
                    unsigned lo = m12[u] < v ? m12[u] : v;
                    unsigned hi = m12[u] < v ? v : m12[u];
                    m12[u] = lo; v = hi;
                }
            }
        int q = q0 + s * 16 + ln;
        if (lg == 0 && q < Sg) {
            int* cp = &cand[(size_t)(gbase + q) * NCAND + qtr * 12];
#pragma unroll
            for (int t = 0; t < 12; ++t) cp[t] = gbase + cbase + (int)(m12[t] & 2047u);
        }
    }
}

// ---------------------------------------------------------------- exact fp32 re-rank, wave per query
__global__ __launch_bounds__(256) void knn_rerank_k(const float* __restrict__ x,
                                                    const float* __restrict__ sqn,
                                                    const int* __restrict__ cand,
                                                    int* __restrict__ knn_idx)
{
    int w = threadIdx.x >> 6, lane = threadIdx.x & 63;
    int q = blockIdx.x * 4 + w;
    float2 qv = *(const float2*)&x[(size_t)q * 128 + lane * 2];
    const int* cp = &cand[(size_t)q * NCAND];

    float d6[6]; int i6[6]; float mx = __builtin_inff(); int sl = 0;
#pragma unroll
    for (int t = 0; t < 6; ++t) { d6[t] = __builtin_inff(); i6[t] = -1; }

    for (int j = 0; j < NCAND; ++j) {
        int c = cp[j];                         // wave-uniform broadcast load
        if ((unsigned)c >= (unsigned)N || c == q) continue;   // self/garbage skip
        float2 cv = *(const float2*)&x[(size_t)c * 128 + lane * 2];
        float p = fmaf(qv.y, cv.y, qv.x * cv.x);
#pragma unroll
        for (int off = 32; off; off >>= 1) p += __shfl_xor(p, off);
        float dv = fmaf(-2.f, p, sqn[c]);      // wave-uniform
        if (dv < mx) {
#pragma unroll
            for (int t = 0; t < 6; ++t)
                if (t == sl) { d6[t] = dv; i6[t] = c; }
            float m2 = d6[0]; int s2 = 0;
#pragma unroll
            for (int t = 1; t < 6; ++t)
                if (d6[t] > m2) { m2 = d6[t]; s2 = t; }
            mx = m2; sl = s2;
        }
    }
    if (lane < 6) {
        int v;
#pragma unroll
        for (int t = 0; t < 6; ++t) if (t == lane) v = i6[t];
        knn_idx[(size_t)q * 6 + lane] = v;
    }
}

// ---------------------------------------------------------------- CSR build
__global__ __launch_bounds__(256) void hist_k(const int* __restrict__ dstA, int* __restrict__ deg)
{
    int e = blockIdx.x * 256 + threadIdx.x;
    atomicAdd(&deg[dstA[e]], 1);
}

__global__ __launch_bounds__(1024) void scan_k(const int* __restrict__ deg, int* __restrict__ rowptr)
{
    __shared__ int ps[1024];
    int t = threadIdx.x;
    const int chunk = 40;
    int base = t * chunk;
    int s = 0;
    for (int k = 0; k < chunk; ++k) { int i = base + k; if (i < N) s += deg[i]; }
    ps[t] = s;
    __syncthreads();
    for (int off = 1; off < 1024; off <<= 1) {
        int v = (t >= off) ? ps[t - off] : 0;
        __syncthreads();
        ps[t] += v;
        __syncthreads();
    }
    int run = ps[t] - s;
    for (int k = 0; k < chunk; ++k) {
        int i = base + k;
        if (i < N) { rowptr[i] = run; run += deg[i]; }
    }
    if (t == 0) rowptr[N] = E;
}

__global__ __launch_bounds__(256) void scatter_k(const int* __restrict__ srcA, const int* __restrict__ dstA,
                                                 const float* __restrict__ ea,
                                                 const int* __restrict__ rowptr, int* __restrict__ cnt,
                                                 int* __restrict__ csr_src, float* __restrict__ csr_ea)
{
    int e = blockIdx.x * 256 + threadIdx.x;
    int d = dstA[e];
    int pos = rowptr[d] + atomicAdd(&cnt[d], 1);
    csr_src[pos] = srcA[e];
    csr_ea[pos] = ea[e];
}

// ---------------------------------------------------------------- spatial GATv2 (wave per dst node)
__global__ __launch_bounds__(256) void spatial_gat_k(
    const float* __restrict__ xl, const float* __restrict__ xr,
    const int* __restrict__ rowptr, const int* __restrict__ csr_src, const float* __restrict__ csr_ea,
    const float* __restrict__ att, const float* __restrict__ wse, const float* __restrict__ bias,
    float* __restrict__ ch2)
{
    __shared__ float lg[4][LGCAP];
    int w = threadIdx.x >> 6, lane = threadIdx.x & 63;
    int dst = blockIdx.x * 4 + w;
    int base = rowptr[dst];
    int deg = rowptr[dst + 1] - base;
    if (deg > LGCAP) deg = LGCAP;
    float xr0 = xr[(size_t)dst * 128 + lane], xr1 = xr[(size_t)dst * 128 + 64 + lane];
    float at0 = att[lane], at1 = att[64 + lane];
    float we0 = wse[lane], we1 = wse[64 + lane];
    float m = -1e30f;
    for (int i = 0; i < deg; ++i) {
        int s = csr_src[base + i];
        float ea = csr_ea[base + i];
        float h0 = xl[(size_t)s * 128 + lane] + xr0 + ea * we0;
        float h1 = xl[(size_t)s * 128 + 64 + lane] + xr1 + ea * we1;
        h0 = h0 > 0.f ? h0 : 0.2f * h0;
        h1 = h1 > 0.f ? h1 : 0.2f * h1;
        float p = h0 * at0 + h1 * at1;
#pragma unroll
        for (int off = 32; off; off >>= 1) p += __shfl_xor(p, off);
        if (lane == 0) lg[w][i] = p;
        m = fmaxf(m, p);
    }
    __syncthreads();
    float sum = 0.f;
    for (int i = lane; i < deg; i += 64) {
        float ev = __expf(lg[w][i] - m);
        lg[w][i] = ev;
        sum += ev;
    }
#pragma unroll
    for (int off = 32; off; off >>= 1) sum += __shfl_xor(sum, off);
    float inv = 1.f / sum;
    __syncthreads();
    float o0 = 0.f, o1 = 0.f;
    for (int i = 0; i < deg; ++i) {
        float a = lg[w][i] * inv;
        int s = csr_src[base + i];
        o0 = fmaf(a, xl[(size_t)s * 128 + lane], o0);
        o1 = fmaf(a, xl[(size_t)s * 128 + 64 + lane], o1);
    }
    ch2[(size_t)dst * 256 + lane] = o0 + bias[lane];
    ch2[(size_t)dst * 256 + 64 + lane] = o1 + bias[64 + lane];
}

// ---------------------------------------------------------------- latent GATv2 (wave per dst; 6 knn + self)
__global__ __launch_bounds__(256) void latent_gat_k(
    const float* __restrict__ xl, const float* __restrict__ xr,
    const int* __restrict__ knn, const float* __restrict__ att,
    const float* __restrict__ bias, float* __restrict__ ch2)
{
    int w = threadIdx.x >> 6, lane = threadIdx.x & 63;
    int dst = blockIdx.x * 4 + w;
    float xr0 = xr[(size_t)dst * 128 + lane], xr1 = xr[(size_t)dst * 128 + 64 + lane];
    float at0 = att[lane], at1 = att[64 + lane];
    int s[7];
#pragma unroll
    for (int j = 0; j < 6; ++j) s[j] = knn[(size_t)dst * 6 + j];
    s[6] = dst;
    float l[7];
#pragma unroll
    for (int j = 0; j < 7; ++j) {
        float h0 = xl[(size_t)s[j] * 128 + lane] + xr0;
        float h1 = xl[(size_t)s[j] * 128 + 64 + lane] + xr1;
        h0 = h0 > 0.f ? h0 : 0.2f * h0;
        h1 = h1 > 0.f ? h1 : 0.2f * h1;
        float p = h0 * at0 + h1 * at1;
#pragma unroll
        for (int off = 32; off; off >>= 1) p += __shfl_xor(p, off);
        l[j] = p;
    }
    float m = l[0];
#pragma unroll
    for (int j = 1; j < 7; ++j) m = fmaxf(m, l[j]);
    float sum = 0.f;
#pragma unroll
    for (int j = 0; j < 7; ++j) { l[j] = __expf(l[j] - m); sum += l[j]; }
    float inv = 1.f / sum;
    float o0 = 0.f, o1 = 0.f;
#pragma unroll
    for (int j = 0; j < 7; ++j) {
        float a = l[j] * inv;
        o0 = fmaf(a, xl[(size_t)s[j] * 128 + lane], o0);
        o1 = fmaf(a, xl[(size_t)s[j] * 128 + 64 + lane], o1);
    }
    ch2[(size_t)dst * 256 + 128 + lane] = o0 + bias[lane];
    ch2[(size_t)dst * 256 + 192 + lane] = o1 + bias[64 + lane];
}

// ---------------------------------------------------------------- launch
extern "C" void kernel_launch(void* const* d_in, const int* in_sizes, int n_in,
                              void* d_out, int out_size, void* d_ws, size_t ws_size,
                              hipStream_t stream)
{
    const float* x      = (const float*)d_in[0];
    const int*   ei     = (const int*)  d_in[1];
    const float* eattr  = (const float*)d_in[2];
    const float* W_sl   = (const float*)d_in[4];
    const float* b_sl   = (const float*)d_in[5];
    const float* W_sr   = (const float*)d_in[6];
    const float* b_sr   = (const float*)d_in[7];
    const float* att_s  = (const float*)d_in[8];
    const float* W_se   = (const float*)d_in[9];
    const float* bias_s = (const float*)d_in[10];
    const float* W_ll   = (const float*)d_in[11];
    const float* b_ll   = (const float*)d_in[12];
    const float* W_lr   = (const float*)d_in[13];
    const float* b_lr   = (const float*)d_in[14];
    const float* att_l  = (const float*)d_in[15];
    const float* bias_l = (const float*)d_in[16];
    const float* W_c    = (const float*)d_in[17];
    const float* b_c    = (const float*)d_in[18];
    const float* W_f1   = (const float*)d_in[19];
    const float* b_f1   = (const float*)d_in[20];
    const float* W_f2   = (const float*)d_in[21];
    const float* b_f2   = (const float*)d_in[22];
    float* out = (float*)d_out;

    char* wp = (char*)d_ws;
    auto take = [&](size_t bytes) { char* p = wp; wp += (bytes + 255) & ~(size_t)255; return p; };
    float* xl_s    = (float*)take((size_t)N * D * 4);
    float* xr_s    = (float*)take((size_t)N * D * 4);
    float* xl_l    = (float*)take((size_t)N * D * 4);
    float* xr_l    = (float*)take((size_t)N * D * 4);
    float* ch2     = (float*)take((size_t)N * 2 * D * 4);
    float* sqn     = (float*)take((size_t)N * 4);
    int*   knn_idx = (int*)  take((size_t)N * KN * 4);
    int*   deg     = (int*)  take((size_t)N * 4);
    int*   rowptr  = (int*)  take((size_t)(N + 1) * 4);
    int*   csr_src = (int*)  take((size_t)E * 4);
    float* csr_ea  = (float*)take((size_t)E * 4);
    unsigned short* x_hi = (unsigned short*)take((size_t)N * D * 2);
    int*   knn_cand = (int*)take((size_t)N * NCAND * 4);
    float* fused   = xl_s;
    float* hbuf    = ch2;
    if ((size_t)(wp - (char*)d_ws) > ws_size) return;

    dim3 blk(256);

    // fused node transforms: 4 outputs, one launch
    gemm4_k<<<dim3(N / 64, 4), blk, 0, stream>>>(x,
        W_sl, W_sr, W_ll, W_lr, b_sl, b_sr, b_ll, b_lr,
        xl_s, xr_s, xl_l, xr_l);

    // kNN graph: prep -> bf16 MFMA prefilter -> exact fp32 re-rank
    prep_k<<<dim3(N / 4), blk, 0, stream>>>(x, x_hi, sqn);
    knn_mfma_k<<<dim3(Bg * 40 * 4), blk, 0, stream>>>(x_hi, sqn, knn_cand);
    knn_rerank_k<<<dim3(N / 4), blk, 0, stream>>>(x, sqn, knn_cand, knn_idx);

    // CSR of spatial edges by dst
    hipMemsetAsync(deg, 0, (size_t)N * 4, stream);
    hist_k<<<dim3(E / 256), blk, 0, stream>>>(ei + E, deg);
    scan_k<<<dim3(1), dim3(1024), 0, stream>>>(deg, rowptr);
    hipMemsetAsync(deg, 0, (size_t)N * 4, stream);
    scatter_k<<<dim3(E / 256), blk, 0, stream>>>(ei, ei + E, eattr, rowptr, deg, csr_src, csr_ea);

    // two GAT channels -> ch2 = [ch_sp | ch_lat]
    spatial_gat_k<<<dim3(N / 4), blk, 0, stream>>>(xl_s, xr_s, rowptr, csr_src, csr_ea,
                                                   att_s, W_se, bias_s, ch2);
    latent_gat_k<<<dim3(N / 4), blk, 0, stream>>>(xl_l, xr_l, knn_idx, att_l, bias_l, ch2);

    // fusion + FFN
    gemm_k<<<dim3(N / 64, 1), blk, 0, stream>>>(ch2, 2 * D, W_c, D, b_c, x, fused, D, 2 * D, 0);
    gemm_k<<<dim3(N / 64, 2), blk, 0, stream>>>(fused, D, W_f1, FF, b_f1, nullptr, hbuf, FF, D, 1);
    gemm_k<<<dim3(N / 64, 1), blk, 0, stream>>>(hbuf, FF, W_f2, D, b_f2, fused, out, D, FF, 1);
}

// Round 7
// 714.091 us; speedup vs baseline: 1.8221x; 1.1274x over previous
//
#include <hip/hip_runtime.h>
#include <math.h>

// ---------------------------------------------------------------- constants
constexpr int N  = 40000;   // nodes
constexpr int D  = 128;     // latent dim
constexpr int E  = 640000;  // spatial edges
constexpr int Bg = 8;       // graphs
constexpr int Sg = 5000;    // nodes per graph
constexpr int KN = 6;       // knn
constexpr int FF = 256;     // ffn hidden
constexpr int LGCAP = 320;  // max in-degree supported in spatial GAT (actual ~45)
constexpr int QLEN = 1280;  // candidate quarter length (64-aligned); last 1160
constexpr int NCAND = 48;   // 4 quarters x top-12

typedef short short8 __attribute__((ext_vector_type(8)));
typedef float f32x4  __attribute__((ext_vector_type(4)));

// ---------------------------------------------------------------- GEMM: out = A@W + bias (+res) (+relu6)
__global__ __launch_bounds__(256) void gemm_k(
    const float* __restrict__ A, int lda,
    const float* __restrict__ Wm, int ldw,
    const float* __restrict__ bias,
    const float* __restrict__ res,
    float* __restrict__ out, int ldo,
    int Kdim, int act)
{
    __shared__ float as[64][36];
    __shared__ float ws[32][128];
    int tid = threadIdx.x;
    int tr = tid >> 4, tc = tid & 15;
    int r0 = blockIdx.x * 64;
    int cb = blockIdx.y * 128;

    float acc[4][8];
#pragma unroll
    for (int j = 0; j < 4; ++j)
#pragma unroll
        for (int m = 0; m < 8; ++m) acc[j][m] = 0.f;

    for (int kt = 0; kt < Kdim; kt += 32) {
#pragma unroll
        for (int i = 0; i < 2; ++i) {
            int c2 = i * 256 + tid;
            int row = c2 >> 3, k4 = (c2 & 7) * 4;
            *(float4*)&as[row][k4] = *(const float4*)&A[(size_t)(r0 + row) * lda + kt + k4];
        }
#pragma unroll
        for (int i = 0; i < 4; ++i) {
            int c2 = i * 256 + tid;
            int row = c2 >> 5, c4 = (c2 & 31) * 4;
            *(float4*)&ws[row][c4] = *(const float4*)&Wm[(size_t)(kt + row) * ldw + cb + c4];
        }
        __syncthreads();
#pragma unroll 8
        for (int k = 0; k < 32; ++k) {
            float a[4], b[8];
#pragma unroll
            for (int j = 0; j < 4; ++j) a[j] = as[tr + 16 * j][k];
#pragma unroll
            for (int m = 0; m < 8; ++m) b[m] = ws[k][tc + 16 * m];
#pragma unroll
            for (int j = 0; j < 4; ++j)
#pragma unroll
                for (int m = 0; m < 8; ++m) acc[j][m] = fmaf(a[j], b[m], acc[j][m]);
        }
        __syncthreads();
    }
#pragma unroll
    for (int j = 0; j < 4; ++j) {
        int r = r0 + tr + 16 * j;
#pragma unroll
        for (int m = 0; m < 8; ++m) {
            int c = tc + 16 * m;
            float v = acc[j][m] + bias[cb + c];
            if (res) v += res[(size_t)r * 128 + c];
            if (act) v = fminf(fmaxf(v, 0.f), 6.f);
            out[(size_t)r * ldo + cb + c] = v;
        }
    }
}

// ---------------------------------------------------------------- fused 4x node-transform GEMM (x shared A)
__global__ __launch_bounds__(256) void gemm4_k(
    const float* __restrict__ A,
    const float* __restrict__ W0, const float* __restrict__ W1,
    const float* __restrict__ W2, const float* __restrict__ W3,
    const float* __restrict__ b0, const float* __restrict__ b1,
    const float* __restrict__ b2, const float* __restrict__ b3,
    float* __restrict__ o0, float* __restrict__ o1,
    float* __restrict__ o2, float* __restrict__ o3)
{
    const float* Wm; const float* bias; float* out;
    if (blockIdx.y == 0)      { Wm = W0; bias = b0; out = o0; }
    else if (blockIdx.y == 1) { Wm = W1; bias = b1; out = o1; }
    else if (blockIdx.y == 2) { Wm = W2; bias = b2; out = o2; }
    else                      { Wm = W3; bias = b3; out = o3; }

    __shared__ float as[64][36];
    __shared__ float ws[32][128];
    int tid = threadIdx.x;
    int tr = tid >> 4, tc = tid & 15;
    int r0 = blockIdx.x * 64;

    float acc[4][8];
#pragma unroll
    for (int j = 0; j < 4; ++j)
#pragma unroll
        for (int m = 0; m < 8; ++m) acc[j][m] = 0.f;

    for (int kt = 0; kt < 128; kt += 32) {
#pragma unroll
        for (int i = 0; i < 2; ++i) {
            int c2 = i * 256 + tid;
            int row = c2 >> 3, k4 = (c2 & 7) * 4;
            *(float4*)&as[row][k4] = *(const float4*)&A[(size_t)(r0 + row) * 128 + kt + k4];
        }
#pragma unroll
        for (int i = 0; i < 4; ++i) {
            int c2 = i * 256 + tid;
            int row = c2 >> 5, c4 = (c2 & 31) * 4;
            *(float4*)&ws[row][c4] = *(const float4*)&Wm[(size_t)(kt + row) * 128 + c4];
        }
        __syncthreads();
#pragma unroll 8
        for (int k = 0; k < 32; ++k) {
            float a[4], b[8];
#pragma unroll
            for (int j = 0; j < 4; ++j) a[j] = as[tr + 16 * j][k];
#pragma unroll
            for (int m = 0; m < 8; ++m) b[m] = ws[k][tc + 16 * m];
#pragma unroll
            for (int j = 0; j < 4; ++j)
#pragma unroll
                for (int m = 0; m < 8; ++m) acc[j][m] = fmaf(a[j], b[m], acc[j][m]);
        }
        __syncthreads();
    }
#pragma unroll
    for (int j = 0; j < 4; ++j) {
        int r = r0 + tr + 16 * j;
#pragma unroll
        for (int m = 0; m < 8; ++m) {
            int c = tc + 16 * m;
            out[(size_t)r * 128 + c] = acc[j][m] + bias[c];
        }
    }
}

// ---------------------------------------------------------------- prep: sqnorm + bf16-hi cast (one x pass)
__device__ __forceinline__ unsigned short f2bf(float f)
{
    unsigned int u = __float_as_uint(f);
    return (unsigned short)((u + 0x7fffu + ((u >> 16) & 1u)) >> 16);
}

__global__ __launch_bounds__(256) void prep_k(const float* __restrict__ x,
                                              unsigned short* __restrict__ xh,
                                              float* __restrict__ sqn)
{
    int w = threadIdx.x >> 6, lane = threadIdx.x & 63;
    int row = blockIdx.x * 4 + w;
    float2 v = *(const float2*)&x[(size_t)row * 128 + lane * 2];
    ushort2 h = make_ushort2(f2bf(v.x), f2bf(v.y));
    *(ushort2*)&xh[(size_t)row * 128 + lane * 2] = h;
    float s = fmaf(v.y, v.y, v.x * v.x);
#pragma unroll
    for (int off = 32; off; off >>= 1) s += __shfl_xor(s, off);
    if (lane == 0) sqn[row] = s;
}

// ---------------------------------------------------------------- branchless sorted insert (ascending u32)
__device__ __forceinline__ void ins6(unsigned (&d)[6], unsigned k)
{
#pragma unroll
    for (int t = 0; t < 6; ++t) {
        unsigned lo = d[t] < k ? d[t] : k;
        unsigned hi = d[t] < k ? k : d[t];
        d[t] = lo; k = hi;
    }
}

// ---------------------------------------------------------------- kNN prefilter via MFMA, branchless selection
// grid: 8 graphs x 40 query-blocks(128q) x 4 quarters (1280/1280/1280/1160).
// wave owns 32 queries (2 x 16 = mfma N dim); cands tiled 64/LDS (hi, swizzled).
// scores pure-bf16 (hi*hi); err ~0.1 << order-stat gaps; exact fp32 re-rank after.
// per-lane sorted top-6 packed keys (guarded insert) -> shfl-merge -> top-12/quarter.
__global__ __launch_bounds__(256) void knn_mfma_k(const unsigned short* __restrict__ xh,
                                                  const float* __restrict__ sqn,
                                                  int* __restrict__ cand)
{
    __shared__ char lds[16640];               // 16KB hi tile + 256B biased csq
    char* ldsH = lds;
    float* cs_s = (float*)(lds + 16384);

    int b = blockIdx.x;
    int g = b & 7, r = b >> 3;                // g == XCD id -> per-graph L2 locality
    int qtr = r & 3, qblk = r >> 2;
    int gbase = g * Sg;
    int cbase = qtr * QLEN;
    int qlen = (qtr < 3) ? QLEN : (Sg - 3 * QLEN);   // 1160 last
    int ntiles = (qlen + 63) >> 6;                    // 20/20/20/19
    int tid = threadIdx.x;
    int w = tid >> 6, lane = tid & 63;
    int lg = lane >> 4, ln = lane & 15;
    int q0 = qblk * 128 + w * 32;

    // resident query B-frags (hi only): [qset][kstep]
    short8 bh[2][4];
#pragma unroll
    for (int s = 0; s < 2; ++s) {
        int q = q0 + s * 16 + ln;
        int qrow = gbase + (q < Sg ? q : Sg - 1);
#pragma unroll
        for (int ks = 0; ks < 4; ++ks)
            bh[s][ks] = *(const short8*)&xh[(size_t)qrow * 128 + ks * 32 + lg * 8];
    }

    unsigned d6a[6], d6b[6];
#pragma unroll
    for (int t = 0; t < 6; ++t) { d6a[t] = 0xFFFFFFFFu; d6b[t] = 0xFFFFFFFFu; }

    for (int t64 = 0; t64 < ntiles; ++t64) {
        int c0 = cbase + t64 * 64;            // graph-relative
        __syncthreads();
        // stage 64 cand hi rows, swizzled: byte ^= (row&7)<<4
#pragma unroll
        for (int i = 0; i < 4; ++i) {
            int c = i * 256 + tid;            // 1024 chunks of 16B
            int row = c >> 4, slot = c & 15;
            int cr = c0 + row;
            if (cr >= Sg) cr = Sg - 1;
            short8 vh = *(const short8*)&xh[(size_t)(gbase + cr) * 128 + slot * 8];
            *(short8*)(ldsH + row * 256 + ((slot * 16) ^ ((row & 7) << 4))) = vh;
        }
        if (tid < 64) {
            int cl = c0 + tid;
            cs_s[tid] = (cl < cbase + qlen) ? (sqn[gbase + cl] + 1024.0f) : __builtin_inff();
        }
        __syncthreads();

#pragma unroll
        for (int g16 = 0; g16 < 4; ++g16) {
            f32x4 acc0 = {0.f, 0.f, 0.f, 0.f};
            f32x4 acc1 = {0.f, 0.f, 0.f, 0.f};
            int rr = g16 * 16 + ln;
            int rsw = (rr & 7) << 4;
#pragma unroll
            for (int ks = 0; ks < 4; ++ks) {
                short8 ah = *(const short8*)(ldsH + rr * 256 + ((lg * 16 + ks * 64) ^ rsw));
                acc0 = __builtin_amdgcn_mfma_f32_16x16x32_bf16(ah, bh[0][ks], acc0, 0, 0, 0);
                acc1 = __builtin_amdgcn_mfma_f32_16x16x32_bf16(ah, bh[1][ks], acc1, 0, 0, 0);
            }
            f32x4 cv = *(const f32x4*)&cs_s[g16 * 16 + lg * 4];   // biased +1024
            int idx0 = (c0 - cbase) + g16 * 16 + lg * 4;          // quarter-local, 11 bits
#pragma unroll
            for (int rg = 0; rg < 4; ++rg) {
                float kf0 = fmaf(-2.f, acc0[rg], cv[rg]);
                float kf1 = fmaf(-2.f, acc1[rg], cv[rg]);
                unsigned ki = (unsigned)(idx0 + rg);
                unsigned k0 = (__float_as_uint(kf0) & 0xFFFFF800u) | ki;
                unsigned k1 = (__float_as_uint(kf1) & 0xFFFFF800u) | ki;
                if (k0 < d6a[5]) ins6(d6a, k0);   // guarded: exact (d sorted, d[5]=max)
                if (k1 < d6b[5]) ins6(d6b, k1);
            }
        }
    }

    // in-wave merge: partials for query (s, ln) live in lanes ln + 16*lg.
#pragma unroll
    for (int s = 0; s < 2; ++s) {
        unsigned m12[12];
#pragma unroll
        for (int t = 0; t < 6; ++t) m12[t] = s ? d6b[t] : d6a[t];
#pragma unroll
        for (int t = 6; t < 12; ++t) m12[t] = 0xFFFFFFFFu;
#pragma unroll
        for (int sg = 1; sg < 4; ++sg)
#pragma unroll
            for (int t = 0; t < 6; ++t) {
                unsigned v = __shfl(s ? d6b[t] : d6a[t], ln + sg * 16);
#pragma unroll
                for (int u = 0; u < 12; ++u) {
                    unsigned lo = m12[u] < v ? m12[u] : v;
                    unsigned hi = m12[u] < v ? v : m12[u];
                    m12[u] = lo; v = hi;
                }
            }
        int q = q0 + s * 16 + ln;
        if (lg == 0 && q < Sg) {
            int* cp = &cand[(size_t)(gbase + q) * NCAND + qtr * 12];
#pragma unroll
            for (int t = 0; t < 12; ++t) cp[t] = gbase + cbase + (int)(m12[t] & 2047u);
        }
    }
}

// ---------------------------------------------------------------- exact fp32 re-rank, wave per query
// 4 groups of 16 lanes; group g owns quarter g's 12 candidates (4-way ILP).
// lane holds 8 floats of the row; 4-step shfl_xor reduce within group.
// group-local top-6 -> group 0 merges all lists (others frozen) -> write set.
__global__ __launch_bounds__(256) void knn_rerank_k(const float* __restrict__ x,
                                                    const float* __restrict__ sqn,
                                                    const int* __restrict__ cand,
                                                    int* __restrict__ knn_idx)
{
    int w = threadIdx.x >> 6, lane = threadIdx.x & 63;
    int grp = lane >> 4, gl = lane & 15;
    int q = blockIdx.x * 4 + w;
    float4 qa = *(const float4*)&x[(size_t)q * 128 + gl * 8];
    float4 qb = *(const float4*)&x[(size_t)q * 128 + gl * 8 + 4];
    const int* cp = &cand[(size_t)q * NCAND + grp * 12];

    float d6[6]; int i6[6]; float mx = __builtin_inff(); int sl = 0;
#pragma unroll
    for (int t = 0; t < 6; ++t) { d6[t] = __builtin_inff(); i6[t] = -1; }

#pragma unroll 2
    for (int j = 0; j < 12; ++j) {
        int c = cp[j];                          // group-uniform
        bool ok = (unsigned)c < (unsigned)N && c != q;
        int ca = ok ? c : 0;
        float4 va = *(const float4*)&x[(size_t)ca * 128 + gl * 8];
        float4 vb = *(const float4*)&x[(size_t)ca * 128 + gl * 8 + 4];
        float p = qa.x * va.x;
        p = fmaf(qa.y, va.y, p); p = fmaf(qa.z, va.z, p); p = fmaf(qa.w, va.w, p);
        p = fmaf(qb.x, vb.x, p); p = fmaf(qb.y, vb.y, p);
        p = fmaf(qb.z, vb.z, p); p = fmaf(qb.w, vb.w, p);
#pragma unroll
        for (int off = 1; off < 16; off <<= 1) p += __shfl_xor(p, off);
        float dv = ok ? fmaf(-2.f, p, sqn[ca]) : __builtin_inff();  // group-uniform
        if (dv < mx) {
#pragma unroll
            for (int t = 0; t < 6; ++t)
                if (t == sl) { d6[t] = dv; i6[t] = c; }
            float m2 = d6[0]; int s2 = 0;
#pragma unroll
            for (int t = 1; t < 6; ++t)
                if (d6[t] > m2) { m2 = d6[t]; s2 = t; }
            mx = m2; sl = s2;
        }
    }

    // merge groups 1..3 into group 0 (their lists stay frozen -> no race)
#pragma unroll
    for (int sg = 1; sg < 4; ++sg) {
#pragma unroll
        for (int t = 0; t < 6; ++t) {
            float dv = __shfl(d6[t], gl + sg * 16);
            int ci = __shfl(i6[t], gl + sg * 16);
            if (grp == 0 && dv < mx) {
#pragma unroll
                for (int u = 0; u < 6; ++u)
                    if (u == sl) { d6[u] = dv; i6[u] = ci; }
                float m2 = d6[0]; int s2 = 0;
#pragma unroll
                for (int u = 1; u < 6; ++u)
                    if (d6[u] > m2) { m2 = d6[u]; s2 = u; }
                mx = m2; sl = s2;
            }
        }
    }
    if (lane < 6) {
        int v;
#pragma unroll
        for (int t = 0; t < 6; ++t) if (t == lane) v = i6[t];
        knn_idx[(size_t)q * 6 + lane] = v;
    }
}

// ---------------------------------------------------------------- CSR build
__global__ __launch_bounds__(256) void hist_k(const int* __restrict__ dstA, int* __restrict__ deg)
{
    int e = blockIdx.x * 256 + threadIdx.x;
    atomicAdd(&deg[dstA[e]], 1);
}

__global__ __launch_bounds__(1024) void scan_k(const int* __restrict__ deg, int* __restrict__ rowptr)
{
    __shared__ int ps[1024];
    int t = threadIdx.x;
    const int chunk = 40;
    int base = t * chunk;
    int s = 0;
    for (int k = 0; k < chunk; ++k) { int i = base + k; if (i < N) s += deg[i]; }
    ps[t] = s;
    __syncthreads();
    for (int off = 1; off < 1024; off <<= 1) {
        int v = (t >= off) ? ps[t - off] : 0;
        __syncthreads();
        ps[t] += v;
        __syncthreads();
    }
    int run = ps[t] - s;
    for (int k = 0; k < chunk; ++k) {
        int i = base + k;
        if (i < N) { rowptr[i] = run; run += deg[i]; }
    }
    if (t == 0) rowptr[N] = E;
}

__global__ __launch_bounds__(256) void scatter_k(const int* __restrict__ srcA, const int* __restrict__ dstA,
                                                 const float* __restrict__ ea,
                                                 const int* __restrict__ rowptr, int* __restrict__ cnt,
                                                 int* __restrict__ csr_src, float* __restrict__ csr_ea)
{
    int e = blockIdx.x * 256 + threadIdx.x;
    int d = dstA[e];
    int pos = rowptr[d] + atomicAdd(&cnt[d], 1);
    csr_src[pos] = srcA[e];
    csr_ea[pos] = ea[e];
}

// ---------------------------------------------------------------- spatial GATv2 (wave per dst node)
__global__ __launch_bounds__(256) void spatial_gat_k(
    const float* __restrict__ xl, const float* __restrict__ xr,
    const int* __restrict__ rowptr, const int* __restrict__ csr_src, const float* __restrict__ csr_ea,
    const float* __restrict__ att, const float* __restrict__ wse, const float* __restrict__ bias,
    float* __restrict__ ch2)
{
    __shared__ float lg[4][LGCAP];
    int w = threadIdx.x >> 6, lane = threadIdx.x & 63;
    int dst = blockIdx.x * 4 + w;
    int base = rowptr[dst];
    int deg = rowptr[dst + 1] - base;
    if (deg > LGCAP) deg = LGCAP;
    float xr0 = xr[(size_t)dst * 128 + lane], xr1 = xr[(size_t)dst * 128 + 64 + lane];
    float at0 = att[lane], at1 = att[64 + lane];
    float we0 = wse[lane], we1 = wse[64 + lane];
    float m = -1e30f;
    for (int i = 0; i < deg; ++i) {
        int s = csr_src[base + i];
        float ea = csr_ea[base + i];
        float h0 = xl[(size_t)s * 128 + lane] + xr0 + ea * we0;
        float h1 = xl[(size_t)s * 128 + 64 + lane] + xr1 + ea * we1;
        h0 = h0 > 0.f ? h0 : 0.2f * h0;
        h1 = h1 > 0.f ? h1 : 0.2f * h1;
        float p = h0 * at0 + h1 * at1;
#pragma unroll
        for (int off = 32; off; off >>= 1) p += __shfl_xor(p, off);
        if (lane == 0) lg[w][i] = p;
        m = fmaxf(m, p);
    }
    __syncthreads();
    float sum = 0.f;
    for (int i = lane; i < deg; i += 64) {
        float ev = __expf(lg[w][i] - m);
        lg[w][i] = ev;
        sum += ev;
    }
#pragma unroll
    for (int off = 32; off; off >>= 1) sum += __shfl_xor(sum, off);
    float inv = 1.f / sum;
    __syncthreads();
    float o0 = 0.f, o1 = 0.f;
    for (int i = 0; i < deg; ++i) {
        float a = lg[w][i] * inv;
        int s = csr_src[base + i];
        o0 = fmaf(a, xl[(size_t)s * 128 + lane], o0);
        o1 = fmaf(a, xl[(size_t)s * 128 + 64 + lane], o1);
    }
    ch2[(size_t)dst * 256 + lane] = o0 + bias[lane];
    ch2[(size_t)dst * 256 + 64 + lane] = o1 + bias[64 + lane];
}

// ---------------------------------------------------------------- latent GATv2 (wave per dst; 6 knn + self)
__global__ __launch_bounds__(256) void latent_gat_k(
    const float* __restrict__ xl, const float* __restrict__ xr,
    const int* __restrict__ knn, const float* __restrict__ att,
    const float* __restrict__ bias, float* __restrict__ ch2)
{
    int w = threadIdx.x >> 6, lane = threadIdx.x & 63;
    int dst = blockIdx.x * 4 + w;
    float xr0 = xr[(size_t)dst * 128 + lane], xr1 = xr[(size_t)dst * 128 + 64 + lane];
    float at0 = att[lane], at1 = att[64 + lane];
    int s[7];
#pragma unroll
    for (int j = 0; j < 6; ++j) s[j] = knn[(size_t)dst * 6 + j];
    s[6] = dst;
    float l[7];
#pragma unroll
    for (int j = 0; j < 7; ++j) {
        float h0 = xl[(size_t)s[j] * 128 + lane] + xr0;
        float h1 = xl[(size_t)s[j] * 128 + 64 + lane] + xr1;
        h0 = h0 > 0.f ? h0 : 0.2f * h0;
        h1 = h1 > 0.f ? h1 : 0.2f * h1;
        float p = h0 * at0 + h1 * at1;
#pragma unroll
        for (int off = 32; off; off >>= 1) p += __shfl_xor(p, off);
        l[j] = p;
    }
    float m = l[0];
#pragma unroll
    for (int j = 1; j < 7; ++j) m = fmaxf(m, l[j]);
    float sum = 0.f;
#pragma unroll
    for (int j = 0; j < 7; ++j) { l[j] = __expf(l[j] - m); sum += l[j]; }
    float inv = 1.f / sum;
    float o0 = 0.f, o1 = 0.f;
#pragma unroll
    for (int j = 0; j < 7; ++j) {
        float a = l[j] * inv;
        o0 = fmaf(a, xl[(size_t)s[j] * 128 + lane], o0);
        o1 = fmaf(a, xl[(size_t)s[j] * 128 + 64 + lane], o1);
    }
    ch2[(size_t)dst * 256 + 128 + lane] = o0 + bias[lane];
    ch2[(size_t)dst * 256 + 192 + lane] = o1 + bias[64 + lane];
}

// ---------------------------------------------------------------- launch
extern "C" void kernel_launch(void* const* d_in, const int* in_sizes, int n_in,
                              void* d_out, int out_size, void* d_ws, size_t ws_size,
                              hipStream_t stream)
{
    const float* x      = (const float*)d_in[0];
    const int*   ei     = (const int*)  d_in[1];
    const float* eattr  = (const float*)d_in[2];
    const float* W_sl   = (const float*)d_in[4];
    const float* b_sl   = (const float*)d_in[5];
    const float* W_sr   = (const float*)d_in[6];
    const float* b_sr   = (const float*)d_in[7];
    const float* att_s  = (const float*)d_in[8];
    const float* W_se   = (const float*)d_in[9];
    const float* bias_s = (const float*)d_in[10];
    const float* W_ll   = (const float*)d_in[11];
    const float* b_ll   = (const float*)d_in[12];
    const float* W_lr   = (const float*)d_in[13];
    const float* b_lr   = (const float*)d_in[14];
    const float* att_l  = (const float*)d_in[15];
    const float* bias_l = (const float*)d_in[16];
    const float* W_c    = (const float*)d_in[17];
    const float* b_c    = (const float*)d_in[18];
    const float* W_f1   = (const float*)d_in[19];
    const float* b_f1   = (const float*)d_in[20];
    const float* W_f2   = (const float*)d_in[21];
    const float* b_f2   = (const float*)d_in[22];
    float* out = (float*)d_out;

    char* wp = (char*)d_ws;
    auto take = [&](size_t bytes) { char* p = wp; wp += (bytes + 255) & ~(size_t)255; return p; };
    float* xl_s    = (float*)take((size_t)N * D * 4);
    float* xr_s    = (float*)take((size_t)N * D * 4);
    float* xl_l    = (float*)take((size_t)N * D * 4);
    float* xr_l    = (float*)take((size_t)N * D * 4);
    float* ch2     = (float*)take((size_t)N * 2 * D * 4);
    float* sqn     = (float*)take((size_t)N * 4);
    int*   knn_idx = (int*)  take((size_t)N * KN * 4);
    int*   deg     = (int*)  take((size_t)N * 4);
    int*   rowptr  = (int*)  take((size_t)(N + 1) * 4);
    int*   csr_src = (int*)  take((size_t)E * 4);
    float* csr_ea  = (float*)take((size_t)E * 4);
    unsigned short* x_hi = (unsigned short*)take((size_t)N * D * 2);
    int*   knn_cand = (int*)take((size_t)N * NCAND * 4);
    float* fused   = xl_s;
    float* hbuf    = ch2;
    if ((size_t)(wp - (char*)d_ws) > ws_size) return;

    dim3 blk(256);

    // fused node transforms: 4 outputs, one launch
    gemm4_k<<<dim3(N / 64, 4), blk, 0, stream>>>(x,
        W_sl, W_sr, W_ll, W_lr, b_sl, b_sr, b_ll, b_lr,
        xl_s, xr_s, xl_l, xr_l);

    // kNN graph: prep -> bf16 MFMA prefilter -> exact fp32 re-rank
    prep_k<<<dim3(N / 4), blk, 0, stream>>>(x, x_hi, sqn);
    knn_mfma_k<<<dim3(Bg * 40 * 4), blk, 0, stream>>>(x_hi, sqn, knn_cand);
    knn_rerank_k<<<dim3(N / 4), blk, 0, stream>>>(x, sqn, knn_cand, knn_idx);

    // CSR of spatial edges by dst
    hipMemsetAsync(deg, 0, (size_t)N * 4, stream);
    hist_k<<<dim3(E / 256), blk, 0, stream>>>(ei + E, deg);
    scan_k<<<dim3(1), dim3(1024), 0, stream>>>(deg, rowptr);
    hipMemsetAsync(deg, 0, (size_t)N * 4, stream);
    scatter_k<<<dim3(E / 256), blk, 0, stream>>>(ei, ei + E, eattr, rowptr, deg, csr_src, csr_ea);

    // two GAT channels -> ch2 = [ch_sp | ch_lat]
    spatial_gat_k<<<dim3(N / 4), blk, 0, stream>>>(xl_s, xr_s, rowptr, csr_src, csr_ea,
                                                   att_s, W_se, bias_s, ch2);
    latent_gat_k<<<dim3(N / 4), blk, 0, stream>>>(xl_l, xr_l, knn_idx, att_l, bias_l, ch2);

    // fusion + FFN
    gemm_k<<<dim3(N / 64, 1), blk, 0, stream>>>(ch2, 2 * D, W_c, D, b_c, x, fused, D, 2 * D, 0);
    gemm_k<<<dim3(N / 64, 2), blk, 0, stream>>>(fused, D, W_f1, FF, b_f1, nullptr, hbuf, FF, D, 1);
    gemm_k<<<dim3(N / 64, 1), blk, 0, stream>>>(hbuf, FF, W_f2, D, b_f2, fused, out, D, FF, 1);
}

// Round 8
// 609.632 us; speedup vs baseline: 2.1343x; 1.1713x over previous
//
#include <hip/hip_runtime.h>
#include <math.h>

// ---------------------------------------------------------------- constants
constexpr int N  = 40000;   // nodes
constexpr int D  = 128;     // latent dim
constexpr int E  = 640000;  // spatial edges
constexpr int Bg = 8;       // graphs
constexpr int Sg = 5000;    // nodes per graph
constexpr int KN = 6;       // knn
constexpr int FF = 256;     // ffn hidden
constexpr int LGCAP = 320;  // max in-degree supported in spatial GAT (actual ~45)
constexpr int QLEN = 1280;  // candidate quarter length (64-aligned); last 1160
constexpr int NCAND = 48;   // 4 quarters x top-12

typedef short short8 __attribute__((ext_vector_type(8)));
typedef float f32x4  __attribute__((ext_vector_type(4)));

// ---------------------------------------------------------------- bf16 helpers
__device__ __forceinline__ unsigned short f2bf(float f)
{
    unsigned int u = __float_as_uint(f);
    return (unsigned short)((u + 0x7fffu + ((u >> 16) & 1u)) >> 16);
}

// ---------------------------------------------------------------- W pre-transpose + bf16 cast (one-shot)
// outputs Wt[col][K] (bf16 hi) for: 4 node Ws (128x128), W_c (256x128),
// W_f1 (128x256), W_f2 (256x128). 163840 elems total.
__global__ __launch_bounds__(256) void w_prep_k(
    const float* __restrict__ W0, const float* __restrict__ W1,
    const float* __restrict__ W2, const float* __restrict__ W3,
    const float* __restrict__ Wc, const float* __restrict__ Wf1,
    const float* __restrict__ Wf2,
    unsigned short* __restrict__ wt4, unsigned short* __restrict__ wtc,
    unsigned short* __restrict__ wtf1, unsigned short* __restrict__ wtf2)
{
    int idx = blockIdx.x * 256 + threadIdx.x;
    if (idx < 65536) {                        // node transforms [128][128]
        int m = idx >> 14, rem = idx & 16383;
        int k = rem & 127, c = rem >> 7;
        const float* Wm = (m == 0) ? W0 : (m == 1) ? W1 : (m == 2) ? W2 : W3;
        wt4[m * 16384 + c * 128 + k] = f2bf(Wm[k * 128 + c]);
    } else if (idx < 98304) {                 // W_c [256][128] -> [128][256]
        int rem = idx - 65536; int k = rem & 255, c = rem >> 8;
        wtc[c * 256 + k] = f2bf(Wc[k * 128 + c]);
    } else if (idx < 131072) {                // W_f1 [128][256] -> [256][128]
        int rem = idx - 98304; int k = rem & 127, c = rem >> 7;
        wtf1[c * 128 + k] = f2bf(Wf1[k * 256 + c]);
    } else {                                  // W_f2 [256][128] -> [128][256]
        int rem = idx - 131072; int k = rem & 255, c = rem >> 8;
        wtf2[c * 256 + k] = f2bf(Wf2[k * 128 + c]);
    }
}

// ---------------------------------------------------------------- MFMA GEMM: out = A@W + bias (+res) (+relu6)
// A fp32 [rows x lda]; Wt bf16-hi pre-transposed [cols][Kdim].
// A-side hi/lo split in-register (A exact); W truncation err ~3e-3 per dot.
// block = 64 rows x 128 cols, 4 waves; wave w owns rows w*16..+15, all 8 col-tiles.
__global__ __launch_bounds__(256) void gemm_mfma_k(
    const float* __restrict__ A, int lda,
    const unsigned short* __restrict__ Wt, int Kdim,
    const float* __restrict__ bias,
    const float* __restrict__ res,
    float* __restrict__ out, int ldo, int act)
{
    __shared__ float xs[64][36];              // pad 36 -> 2-way max on frag reads
    __shared__ unsigned short ws[128][40];    // pad 40 -> 2-way max
    int tid = threadIdx.x;
    int w = tid >> 6, lane = tid & 63;
    int lg = lane >> 4, ln = lane & 15;
    int r0 = blockIdx.x * 64;
    int cb = blockIdx.y * 128;

    f32x4 acc[8];
#pragma unroll
    for (int ct = 0; ct < 8; ++ct) acc[ct] = {0.f, 0.f, 0.f, 0.f};

    int srow = tid >> 2, sk8 = (tid & 3) * 8;   // x staging: 8 floats/thread
    int wcol = tid >> 1, wk = (tid & 1) * 16;   // W staging: 16 shorts/thread

    for (int kt = 0; kt < Kdim; kt += 32) {
        __syncthreads();
        *(float4*)&xs[srow][sk8]     = *(const float4*)&A[(size_t)(r0 + srow) * lda + kt + sk8];
        *(float4*)&xs[srow][sk8 + 4] = *(const float4*)&A[(size_t)(r0 + srow) * lda + kt + sk8 + 4];
        *(short8*)&ws[wcol][wk]     = *(const short8*)&Wt[(size_t)(cb + wcol) * Kdim + kt + wk];
        *(short8*)&ws[wcol][wk + 8] = *(const short8*)&Wt[(size_t)(cb + wcol) * Kdim + kt + wk + 8];
        __syncthreads();

        // a-frag (row = w*16+ln, k = lg*8..+7) -> hi/lo bf16
        int arow = w * 16 + ln;
        f32x4 a0 = *(const f32x4*)&xs[arow][lg * 8];
        f32x4 a1 = *(const f32x4*)&xs[arow][lg * 8 + 4];
        float af[8] = {a0[0], a0[1], a0[2], a0[3], a1[0], a1[1], a1[2], a1[3]};
        short8 ah, al;
#pragma unroll
        for (int i = 0; i < 8; ++i) {
            unsigned short h = f2bf(af[i]);
            ah[i] = (short)h;
            float hf = __uint_as_float(((unsigned)h) << 16);
            al[i] = (short)f2bf(af[i] - hf);
        }
#pragma unroll
        for (int ct = 0; ct < 8; ++ct) {
            short8 bw = *(const short8*)&ws[ct * 16 + ln][lg * 8];
            acc[ct] = __builtin_amdgcn_mfma_f32_16x16x32_bf16(ah, bw, acc[ct], 0, 0, 0);
            acc[ct] = __builtin_amdgcn_mfma_f32_16x16x32_bf16(al, bw, acc[ct], 0, 0, 0);
        }
    }

#pragma unroll
    for (int ct = 0; ct < 8; ++ct) {
        int c = cb + ct * 16 + ln;
        float bv = bias[c];
#pragma unroll
        for (int rg = 0; rg < 4; ++rg) {
            int r = r0 + w * 16 + lg * 4 + rg;
            float v = acc[ct][rg] + bv;
            if (res) v += res[(size_t)r * 128 + c];   // only gridDim.y==1 users
            if (act) v = fminf(fmaxf(v, 0.f), 6.f);
            out[(size_t)r * ldo + c] = v;
        }
    }
}

// ---------------------------------------------------------------- fused 4x node-transform MFMA GEMM
__global__ __launch_bounds__(256) void gemm4_mfma_k(
    const float* __restrict__ A, const unsigned short* __restrict__ wt4,
    const float* __restrict__ b0, const float* __restrict__ b1,
    const float* __restrict__ b2, const float* __restrict__ b3,
    float* __restrict__ o0, float* __restrict__ o1,
    float* __restrict__ o2, float* __restrict__ o3)
{
    const unsigned short* Wt = wt4 + blockIdx.y * 16384;
    const float* bias; float* out;
    if (blockIdx.y == 0)      { bias = b0; out = o0; }
    else if (blockIdx.y == 1) { bias = b1; out = o1; }
    else if (blockIdx.y == 2) { bias = b2; out = o2; }
    else                      { bias = b3; out = o3; }

    __shared__ float xs[64][36];
    __shared__ unsigned short ws[128][40];
    int tid = threadIdx.x;
    int w = tid >> 6, lane = tid & 63;
    int lg = lane >> 4, ln = lane & 15;
    int r0 = blockIdx.x * 64;

    f32x4 acc[8];
#pragma unroll
    for (int ct = 0; ct < 8; ++ct) acc[ct] = {0.f, 0.f, 0.f, 0.f};

    int srow = tid >> 2, sk8 = (tid & 3) * 8;
    int wcol = tid >> 1, wk = (tid & 1) * 16;

    for (int kt = 0; kt < 128; kt += 32) {
        __syncthreads();
        *(float4*)&xs[srow][sk8]     = *(const float4*)&A[(size_t)(r0 + srow) * 128 + kt + sk8];
        *(float4*)&xs[srow][sk8 + 4] = *(const float4*)&A[(size_t)(r0 + srow) * 128 + kt + sk8 + 4];
        *(short8*)&ws[wcol][wk]     = *(const short8*)&Wt[(size_t)wcol * 128 + kt + wk];
        *(short8*)&ws[wcol][wk + 8] = *(const short8*)&Wt[(size_t)wcol * 128 + kt + wk + 8];
        __syncthreads();

        int arow = w * 16 + ln;
        f32x4 a0 = *(const f32x4*)&xs[arow][lg * 8];
        f32x4 a1 = *(const f32x4*)&xs[arow][lg * 8 + 4];
        float af[8] = {a0[0], a0[1], a0[2], a0[3], a1[0], a1[1], a1[2], a1[3]};
        short8 ah, al;
#pragma unroll
        for (int i = 0; i < 8; ++i) {
            unsigned short h = f2bf(af[i]);
            ah[i] = (short)h;
            float hf = __uint_as_float(((unsigned)h) << 16);
            al[i] = (short)f2bf(af[i] - hf);
        }
#pragma unroll
        for (int ct = 0; ct < 8; ++ct) {
            short8 bw = *(const short8*)&ws[ct * 16 + ln][lg * 8];
            acc[ct] = __builtin_amdgcn_mfma_f32_16x16x32_bf16(ah, bw, acc[ct], 0, 0, 0);
            acc[ct] = __builtin_amdgcn_mfma_f32_16x16x32_bf16(al, bw, acc[ct], 0, 0, 0);
        }
    }

#pragma unroll
    for (int ct = 0; ct < 8; ++ct) {
        int c = ct * 16 + ln;
        float bv = bias[c];
#pragma unroll
        for (int rg = 0; rg < 4; ++rg) {
            int r = r0 + w * 16 + lg * 4 + rg;
            out[(size_t)r * 128 + c] = acc[ct][rg] + bv;
        }
    }
}

// ---------------------------------------------------------------- prep: sqnorm + bf16-hi cast (one x pass)
__global__ __launch_bounds__(256) void prep_k(const float* __restrict__ x,
                                              unsigned short* __restrict__ xh,
                                              float* __restrict__ sqn)
{
    int w = threadIdx.x >> 6, lane = threadIdx.x & 63;
    int row = blockIdx.x * 4 + w;
    float2 v = *(const float2*)&x[(size_t)row * 128 + lane * 2];
    ushort2 h = make_ushort2(f2bf(v.x), f2bf(v.y));
    *(ushort2*)&xh[(size_t)row * 128 + lane * 2] = h;
    float s = fmaf(v.y, v.y, v.x * v.x);
#pragma unroll
    for (int off = 32; off; off >>= 1) s += __shfl_xor(s, off);
    if (lane == 0) sqn[row] = s;
}

// ---------------------------------------------------------------- branchless sorted insert (ascending u32)
__device__ __forceinline__ void ins6(unsigned (&d)[6], unsigned k)
{
#pragma unroll
    for (int t = 0; t < 6; ++t) {
        unsigned lo = d[t] < k ? d[t] : k;
        unsigned hi = d[t] < k ? k : d[t];
        d[t] = lo; k = hi;
    }
}

// ---------------------------------------------------------------- kNN prefilter via MFMA, branchless selection
__global__ __launch_bounds__(256) void knn_mfma_k(const unsigned short* __restrict__ xh,
                                                  const float* __restrict__ sqn,
                                                  int* __restrict__ cand)
{
    __shared__ char lds[16640];               // 16KB hi tile + 256B biased csq
    char* ldsH = lds;
    float* cs_s = (float*)(lds + 16384);

    int b = blockIdx.x;
    int g = b & 7, r = b >> 3;                // g == XCD id -> per-graph L2 locality
    int qtr = r & 3, qblk = r >> 2;
    int gbase = g * Sg;
    int cbase = qtr * QLEN;
    int qlen = (qtr < 3) ? QLEN : (Sg - 3 * QLEN);   // 1160 last
    int ntiles = (qlen + 63) >> 6;                    // 20/20/20/19
    int tid = threadIdx.x;
    int w = tid >> 6, lane = tid & 63;
    int lg = lane >> 4, ln = lane & 15;
    int q0 = qblk * 128 + w * 32;

    short8 bh[2][4];
#pragma unroll
    for (int s = 0; s < 2; ++s) {
        int q = q0 + s * 16 + ln;
        int qrow = gbase + (q < Sg ? q : Sg - 1);
#pragma unroll
        for (int ks = 0; ks < 4; ++ks)
            bh[s][ks] = *(const short8*)&xh[(size_t)qrow * 128 + ks * 32 + lg * 8];
    }

    unsigned d6a[6], d6b[6];
#pragma unroll
    for (int t = 0; t < 6; ++t) { d6a[t] = 0xFFFFFFFFu; d6b[t] = 0xFFFFFFFFu; }

    for (int t64 = 0; t64 < ntiles; ++t64) {
        int c0 = cbase + t64 * 64;
        __syncthreads();
#pragma unroll
        for (int i = 0; i < 4; ++i) {
            int c = i * 256 + tid;
            int row = c >> 4, slot = c & 15;
            int cr = c0 + row;
            if (cr >= Sg) cr = Sg - 1;
            short8 vh = *(const short8*)&xh[(size_t)(gbase + cr) * 128 + slot * 8];
            *(short8*)(ldsH + row * 256 + ((slot * 16) ^ ((row & 7) << 4))) = vh;
        }
        if (tid < 64) {
            int cl = c0 + tid;
            cs_s[tid] = (cl < cbase + qlen) ? (sqn[gbase + cl] + 1024.0f) : __builtin_inff();
        }
        __syncthreads();

#pragma unroll
        for (int g16 = 0; g16 < 4; ++g16) {
            f32x4 acc0 = {0.f, 0.f, 0.f, 0.f};
            f32x4 acc1 = {0.f, 0.f, 0.f, 0.f};
            int rr = g16 * 16 + ln;
            int rsw = (rr & 7) << 4;
#pragma unroll
            for (int ks = 0; ks < 4; ++ks) {
                short8 ah = *(const short8*)(ldsH + rr * 256 + ((lg * 16 + ks * 64) ^ rsw));
                acc0 = __builtin_amdgcn_mfma_f32_16x16x32_bf16(ah, bh[0][ks], acc0, 0, 0, 0);
                acc1 = __builtin_amdgcn_mfma_f32_16x16x32_bf16(ah, bh[1][ks], acc1, 0, 0, 0);
            }
            f32x4 cv = *(const f32x4*)&cs_s[g16 * 16 + lg * 4];   // biased +1024
            int idx0 = (c0 - cbase) + g16 * 16 + lg * 4;          // quarter-local, 11 bits
#pragma unroll
            for (int rg = 0; rg < 4; ++rg) {
                float kf0 = fmaf(-2.f, acc0[rg], cv[rg]);
                float kf1 = fmaf(-2.f, acc1[rg], cv[rg]);
                unsigned ki = (unsigned)(idx0 + rg);
                unsigned k0 = (__float_as_uint(kf0) & 0xFFFFF800u) | ki;
                unsigned k1 = (__float_as_uint(kf1) & 0xFFFFF800u) | ki;
                if (k0 < d6a[5]) ins6(d6a, k0);
                if (k1 < d6b[5]) ins6(d6b, k1);
            }
        }
    }

#pragma unroll
    for (int s = 0; s < 2; ++s) {
        unsigned m12[12];
#pragma unroll
        for (int t = 0; t < 6; ++t) m12[t] = s ? d6b[t] : d6a[t];
#pragma unroll
        for (int t = 6; t < 12; ++t) m12[t] = 0xFFFFFFFFu;
#pragma unroll
        for (int sg = 1; sg < 4; ++sg)
#pragma unroll
            for (int t = 0; t < 6; ++t) {
                unsigned v = __shfl(s ? d6b[t] : d6a[t], ln + sg * 16);
#pragma unroll
                for (int u = 0; u < 12; ++u) {
                    unsigned lo = m12[u] < v ? m12[u] : v;
                    unsigned hi = m12[u] < v ? v : m12[u];
                    m12[u] = lo; v = hi;
                }
            }
        int q = q0 + s * 16 + ln;
        if (lg == 0 && q < Sg) {
            int* cp = &cand[(size_t)(gbase + q) * NCAND + qtr * 12];
#pragma unroll
            for (int t = 0; t < 12; ++t) cp[t] = gbase + cbase + (int)(m12[t] & 2047u);
        }
    }
}

// ---------------------------------------------------------------- exact fp32 re-rank, wave per query
__global__ __launch_bounds__(256) void knn_rerank_k(const float* __restrict__ x,
                                                    const float* __restrict__ sqn,
                                                    const int* __restrict__ cand,
                                                    int* __restrict__ knn_idx)
{
    int w = threadIdx.x >> 6, lane = threadIdx.x & 63;
    int grp = lane >> 4, gl = lane & 15;
    int q = blockIdx.x * 4 + w;
    float4 qa = *(const float4*)&x[(size_t)q * 128 + gl * 8];
    float4 qb = *(const float4*)&x[(size_t)q * 128 + gl * 8 + 4];
    const int* cp = &cand[(size_t)q * NCAND + grp * 12];

    float d6[6]; int i6[6]; float mx = __builtin_inff(); int sl = 0;
#pragma unroll
    for (int t = 0; t < 6; ++t) { d6[t] = __builtin_inff(); i6[t] = -1; }

#pragma unroll 2
    for (int j = 0; j < 12; ++j) {
        int c = cp[j];
        bool ok = (unsigned)c < (unsigned)N && c != q;
        int ca = ok ? c : 0;
        float4 va = *(const float4*)&x[(size_t)ca * 128 + gl * 8];
        float4 vb = *(const float4*)&x[(size_t)ca * 128 + gl * 8 + 4];
        float p = qa.x * va.x;
        p = fmaf(qa.y, va.y, p); p = fmaf(qa.z, va.z, p); p = fmaf(qa.w, va.w, p);
        p = fmaf(qb.x, vb.x, p); p = fmaf(qb.y, vb.y, p);
        p = fmaf(qb.z, vb.z, p); p = fmaf(qb.w, vb.w, p);
#pragma unroll
        for (int off = 1; off < 16; off <<= 1) p += __shfl_xor(p, off);
        float dv = ok ? fmaf(-2.f, p, sqn[ca]) : __builtin_inff();
        if (dv < mx) {
#pragma unroll
            for (int t = 0; t < 6; ++t)
                if (t == sl) { d6[t] = dv; i6[t] = c; }
            float m2 = d6[0]; int s2 = 0;
#pragma unroll
            for (int t = 1; t < 6; ++t)
                if (d6[t] > m2) { m2 = d6[t]; s2 = t; }
            mx = m2; sl = s2;
        }
    }

#pragma unroll
    for (int sg = 1; sg < 4; ++sg) {
#pragma unroll
        for (int t = 0; t < 6; ++t) {
            float dv = __shfl(d6[t], gl + sg * 16);
            int ci = __shfl(i6[t], gl + sg * 16);
            if (grp == 0 && dv < mx) {
#pragma unroll
                for (int u = 0; u < 6; ++u)
                    if (u == sl) { d6[u] = dv; i6[u] = ci; }
                float m2 = d6[0]; int s2 = 0;
#pragma unroll
                for (int u = 1; u < 6; ++u)
                    if (d6[u] > m2) { m2 = d6[u]; s2 = u; }
                mx = m2; sl = s2;
            }
        }
    }
    if (lane < 6) {
        int v;
#pragma unroll
        for (int t = 0; t < 6; ++t) if (t == lane) v = i6[t];
        knn_idx[(size_t)q * 6 + lane] = v;
    }
}

// ---------------------------------------------------------------- CSR build
__global__ __launch_bounds__(256) void hist_k(const int* __restrict__ dstA, int* __restrict__ deg)
{
    int e = blockIdx.x * 256 + threadIdx.x;
    atomicAdd(&deg[dstA[e]], 1);
}

__global__ __launch_bounds__(1024) void scan_k(const int* __restrict__ deg, int* __restrict__ rowptr)
{
    __shared__ int ps[1024];
    int t = threadIdx.x;
    const int chunk = 40;
    int base = t * chunk;
    int s = 0;
    for (int k = 0; k < chunk; ++k) { int i = base + k; if (i < N) s += deg[i]; }
    ps[t] = s;
    __syncthreads();
    for (int off = 1; off < 1024; off <<= 1) {
        int v = (t >= off) ? ps[t - off] : 0;
        __syncthreads();
        ps[t] += v;
        __syncthreads();
    }
    int run = ps[t] - s;
    for (int k = 0; k < chunk; ++k) {
        int i = base + k;
        if (i < N) { rowptr[i] = run; run += deg[i]; }
    }
    if (t == 0) rowptr[N] = E;
}

__global__ __launch_bounds__(256) void scatter_k(const int* __restrict__ srcA, const int* __restrict__ dstA,
                                                 const float* __restrict__ ea,
                                                 const int* __restrict__ rowptr, int* __restrict__ cnt,
                                                 int* __restrict__ csr_src, float* __restrict__ csr_ea)
{
    int e = blockIdx.x * 256 + threadIdx.x;
    int d = dstA[e];
    int pos = rowptr[d] + atomicAdd(&cnt[d], 1);
    csr_src[pos] = srcA[e];
    csr_ea[pos] = ea[e];
}

// ---------------------------------------------------------------- spatial GATv2 (wave per dst node)
__global__ __launch_bounds__(256) void spatial_gat_k(
    const float* __restrict__ xl, const float* __restrict__ xr,
    const int* __restrict__ rowptr, const int* __restrict__ csr_src, const float* __restrict__ csr_ea,
    const float* __restrict__ att, const float* __restrict__ wse, const float* __restrict__ bias,
    float* __restrict__ ch2)
{
    __shared__ float lg[4][LGCAP];
    int w = threadIdx.x >> 6, lane = threadIdx.x & 63;
    int dst = blockIdx.x * 4 + w;
    int base = rowptr[dst];
    int deg = rowptr[dst + 1] - base;
    if (deg > LGCAP) deg = LGCAP;
    float xr0 = xr[(size_t)dst * 128 + lane], xr1 = xr[(size_t)dst * 128 + 64 + lane];
    float at0 = att[lane], at1 = att[64 + lane];
    float we0 = wse[lane], we1 = wse[64 + lane];
    float m = -1e30f;
    for (int i = 0; i < deg; ++i) {
        int s = csr_src[base + i];
        float ea = csr_ea[base + i];
        float h0 = xl[(size_t)s * 128 + lane] + xr0 + ea * we0;
        float h1 = xl[(size_t)s * 128 + 64 + lane] + xr1 + ea * we1;
        h0 = h0 > 0.f ? h0 : 0.2f * h0;
        h1 = h1 > 0.f ? h1 : 0.2f * h1;
        float p = h0 * at0 + h1 * at1;
#pragma unroll
        for (int off = 32; off; off >>= 1) p += __shfl_xor(p, off);
        if (lane == 0) lg[w][i] = p;
        m = fmaxf(m, p);
    }
    __syncthreads();
    float sum = 0.f;
    for (int i = lane; i < deg; i += 64) {
        float ev = __expf(lg[w][i] - m);
        lg[w][i] = ev;
        sum += ev;
    }
#pragma unroll
    for (int off = 32; off; off >>= 1) sum += __shfl_xor(sum, off);
    float inv = 1.f / sum;
    __syncthreads();
    float o0 = 0.f, o1 = 0.f;
    for (int i = 0; i < deg; ++i) {
        float a = lg[w][i] * inv;
        int s = csr_src[base + i];
        o0 = fmaf(a, xl[(size_t)s * 128 + lane], o0);
        o1 = fmaf(a, xl[(size_t)s * 128 + 64 + lane], o1);
    }
    ch2[(size_t)dst * 256 + lane] = o0 + bias[lane];
    ch2[(size_t)dst * 256 + 64 + lane] = o1 + bias[64 + lane];
}

// ---------------------------------------------------------------- latent GATv2 (wave per dst; 6 knn + self)
__global__ __launch_bounds__(256) void latent_gat_k(
    const float* __restrict__ xl, const float* __restrict__ xr,
    const int* __restrict__ knn, const float* __restrict__ att,
    const float* __restrict__ bias, float* __restrict__ ch2)
{
    int w = threadIdx.x >> 6, lane = threadIdx.x & 63;
    int dst = blockIdx.x * 4 + w;
    float xr0 = xr[(size_t)dst * 128 + lane], xr1 = xr[(size_t)dst * 128 + 64 + lane];
    float at0 = att[lane], at1 = att[64 + lane];
    int s[7];
#pragma unroll
    for (int j = 0; j < 6; ++j) s[j] = knn[(size_t)dst * 6 + j];
    s[6] = dst;
    float l[7];
#pragma unroll
    for (int j = 0; j < 7; ++j) {
        float h0 = xl[(size_t)s[j] * 128 + lane] + xr0;
        float h1 = xl[(size_t)s[j] * 128 + 64 + lane] + xr1;
        h0 = h0 > 0.f ? h0 : 0.2f * h0;
        h1 = h1 > 0.f ? h1 : 0.2f * h1;
        float p = h0 * at0 + h1 * at1;
#pragma unroll
        for (int off = 32; off; off >>= 1) p += __shfl_xor(p, off);
        l[j] = p;
    }
    float m = l[0];
#pragma unroll
    for (int j = 1; j < 7; ++j) m = fmaxf(m, l[j]);
    float sum = 0.f;
#pragma unroll
    for (int j = 0; j < 7; ++j) { l[j] = __expf(l[j] - m); sum += l[j]; }
    float inv = 1.f / sum;
    float o0 = 0.f, o1 = 0.f;
#pragma unroll
    for (int j = 0; j < 7; ++j) {
        float a = l[j] * inv;
        o0 = fmaf(a, xl[(size_t)s[j] * 128 + lane], o0);
        o1 = fmaf(a, xl[(size_t)s[j] * 128 + 64 + lane], o1);
    }
    ch2[(size_t)dst * 256 + 128 + lane] = o0 + bias[lane];
    ch2[(size_t)dst * 256 + 192 + lane] = o1 + bias[64 + lane];
}

// ---------------------------------------------------------------- launch
extern "C" void kernel_launch(void* const* d_in, const int* in_sizes, int n_in,
                              void* d_out, int out_size, void* d_ws, size_t ws_size,
                              hipStream_t stream)
{
    const float* x      = (const float*)d_in[0];
    const int*   ei     = (const int*)  d_in[1];
    const float* eattr  = (const float*)d_in[2];
    const float* W_sl   = (const float*)d_in[4];
    const float* b_sl   = (const float*)d_in[5];
    const float* W_sr   = (const float*)d_in[6];
    const float* b_sr   = (const float*)d_in[7];
    const float* att_s  = (const float*)d_in[8];
    const float* W_se   = (const float*)d_in[9];
    const float* bias_s = (const float*)d_in[10];
    const float* W_ll   = (const float*)d_in[11];
    const float* b_ll   = (const float*)d_in[12];
    const float* W_lr   = (const float*)d_in[13];
    const float* b_lr   = (const float*)d_in[14];
    const float* att_l  = (const float*)d_in[15];
    const float* bias_l = (const float*)d_in[16];
    const float* W_c    = (const float*)d_in[17];
    const float* b_c    = (const float*)d_in[18];
    const float* W_f1   = (const float*)d_in[19];
    const float* b_f1   = (const float*)d_in[20];
    const float* W_f2   = (const float*)d_in[21];
    const float* b_f2   = (const float*)d_in[22];
    float* out = (float*)d_out;

    char* wp = (char*)d_ws;
    auto take = [&](size_t bytes) { char* p = wp; wp += (bytes + 255) & ~(size_t)255; return p; };
    float* xl_s    = (float*)take((size_t)N * D * 4);
    float* xr_s    = (float*)take((size_t)N * D * 4);
    float* xl_l    = (float*)take((size_t)N * D * 4);
    float* xr_l    = (float*)take((size_t)N * D * 4);
    float* ch2     = (float*)take((size_t)N * 2 * D * 4);
    float* sqn     = (float*)take((size_t)N * 4);
    int*   knn_idx = (int*)  take((size_t)N * KN * 4);
    int*   deg     = (int*)  take((size_t)N * 4);
    int*   rowptr  = (int*)  take((size_t)(N + 1) * 4);
    int*   csr_src = (int*)  take((size_t)E * 4);
    float* csr_ea  = (float*)take((size_t)E * 4);
    unsigned short* x_hi = (unsigned short*)take((size_t)N * D * 2);
    int*   knn_cand = (int*)take((size_t)N * NCAND * 4);
    unsigned short* wt4  = (unsigned short*)take(65536 * 2);
    unsigned short* wtc  = (unsigned short*)take(32768 * 2);
    unsigned short* wtf1 = (unsigned short*)take(32768 * 2);
    unsigned short* wtf2 = (unsigned short*)take(32768 * 2);
    float* fused   = xl_s;
    float* hbuf    = ch2;
    if ((size_t)(wp - (char*)d_ws) > ws_size) return;

    dim3 blk(256);

    // weight transpose + bf16 cast (one-shot, all matrices)
    w_prep_k<<<dim3(640), blk, 0, stream>>>(W_sl, W_sr, W_ll, W_lr, W_c, W_f1, W_f2,
                                            wt4, wtc, wtf1, wtf2);

    // fused node transforms: 4 outputs, one launch, MFMA
    gemm4_mfma_k<<<dim3(N / 64, 4), blk, 0, stream>>>(x, wt4,
        b_sl, b_sr, b_ll, b_lr, xl_s, xr_s, xl_l, xr_l);

    // kNN graph: prep -> bf16 MFMA prefilter -> exact fp32 re-rank
    prep_k<<<dim3(N / 4), blk, 0, stream>>>(x, x_hi, sqn);
    knn_mfma_k<<<dim3(Bg * 40 * 4), blk, 0, stream>>>(x_hi, sqn, knn_cand);
    knn_rerank_k<<<dim3(N / 4), blk, 0, stream>>>(x, sqn, knn_cand, knn_idx);

    // CSR of spatial edges by dst
    hipMemsetAsync(deg, 0, (size_t)N * 4, stream);
    hist_k<<<dim3(E / 256), blk, 0, stream>>>(ei + E, deg);
    scan_k<<<dim3(1), dim3(1024), 0, stream>>>(deg, rowptr);
    hipMemsetAsync(deg, 0, (size_t)N * 4, stream);
    scatter_k<<<dim3(E / 256), blk, 0, stream>>>(ei, ei + E, eattr, rowptr, deg, csr_src, csr_ea);

    // two GAT channels -> ch2 = [ch_sp | ch_lat]
    spatial_gat_k<<<dim3(N / 4), blk, 0, stream>>>(xl_s, xr_s, rowptr, csr_src, csr_ea,
                                                   att_s, W_se, bias_s, ch2);
    latent_gat_k<<<dim3(N / 4), blk, 0, stream>>>(xl_l, xr_l, knn_idx, att_l, bias_l, ch2);

    // fusion + FFN (MFMA)
    gemm_mfma_k<<<dim3(N / 64, 1), blk, 0, stream>>>(ch2, 2 * D, wtc, 256, b_c, x, fused, 128, 0);
    gemm_mfma_k<<<dim3(N / 64, 2), blk, 0, stream>>>(fused, 128, wtf1, 128, b_f1, nullptr, hbuf, 256, 1);
    gemm_mfma_k<<<dim3(N / 64, 1), blk, 0, stream>>>(hbuf, 256, wtf2, 256, b_f2, fused, out, 128, 1);
}

// Round 9
// 584.192 us; speedup vs baseline: 2.2272x; 1.0435x over previous
//
#include <hip/hip_runtime.h>
#include <math.h>

// ---------------------------------------------------------------- constants
constexpr int N  = 40000;   // nodes
constexpr int D  = 128;     // latent dim
constexpr int E  = 640000;  // spatial edges
constexpr int Bg = 8;       // graphs
constexpr int Sg = 5000;    // nodes per graph
constexpr int KN = 6;       // knn
constexpr int FF = 256;     // ffn hidden
constexpr int QLEN = 1280;  // candidate quarter length (64-aligned); last 1160
constexpr int NCAND = 48;   // 4 quarters x top-12

typedef short short8 __attribute__((ext_vector_type(8)));
typedef float f32x4  __attribute__((ext_vector_type(4)));
typedef __attribute__((address_space(1))) const void* gvp;
typedef __attribute__((address_space(3))) void* lvp;

// ---------------------------------------------------------------- bf16 helpers
__device__ __forceinline__ unsigned short f2bf(float f)
{
    unsigned int u = __float_as_uint(f);
    return (unsigned short)((u + 0x7fffu + ((u >> 16) & 1u)) >> 16);
}

__device__ __forceinline__ unsigned umin2(unsigned a, unsigned b) { return a < b ? a : b; }

// ---------------------------------------------------------------- W pre-transpose + bf16 cast (one-shot)
__global__ __launch_bounds__(256) void w_prep_k(
    const float* __restrict__ W0, const float* __restrict__ W1,
    const float* __restrict__ W2, const float* __restrict__ W3,
    const float* __restrict__ Wc, const float* __restrict__ Wf1,
    const float* __restrict__ Wf2,
    unsigned short* __restrict__ wt4, unsigned short* __restrict__ wtc,
    unsigned short* __restrict__ wtf1, unsigned short* __restrict__ wtf2)
{
    int idx = blockIdx.x * 256 + threadIdx.x;
    if (idx < 65536) {                        // node transforms [128][128]
        int m = idx >> 14, rem = idx & 16383;
        int k = rem & 127, c = rem >> 7;
        const float* Wm = (m == 0) ? W0 : (m == 1) ? W1 : (m == 2) ? W2 : W3;
        wt4[m * 16384 + c * 128 + k] = f2bf(Wm[k * 128 + c]);
    } else if (idx < 98304) {                 // W_c [256][128] -> [128][256]
        int rem = idx - 65536; int k = rem & 255, c = rem >> 8;
        wtc[c * 256 + k] = f2bf(Wc[k * 128 + c]);
    } else if (idx < 131072) {                // W_f1 [128][256] -> [256][128]
        int rem = idx - 98304; int k = rem & 127, c = rem >> 7;
        wtf1[c * 128 + k] = f2bf(Wf1[k * 256 + c]);
    } else {                                  // W_f2 [256][128] -> [128][256]
        int rem = idx - 131072; int k = rem & 255, c = rem >> 8;
        wtf2[c * 256 + k] = f2bf(Wf2[k * 128 + c]);
    }
}

// ---------------------------------------------------------------- MFMA GEMM: out = A@W + bias (+res) (+relu6)
__global__ __launch_bounds__(256) void gemm_mfma_k(
    const float* __restrict__ A, int lda,
    const unsigned short* __restrict__ Wt, int Kdim,
    const float* __restrict__ bias,
    const float* __restrict__ res,
    float* __restrict__ out, int ldo, int act)
{
    __shared__ float xs[64][36];
    __shared__ unsigned short ws[128][40];
    int tid = threadIdx.x;
    int w = tid >> 6, lane = tid & 63;
    int lg = lane >> 4, ln = lane & 15;
    int r0 = blockIdx.x * 64;
    int cb = blockIdx.y * 128;

    f32x4 acc[8];
#pragma unroll
    for (int ct = 0; ct < 8; ++ct) acc[ct] = {0.f, 0.f, 0.f, 0.f};

    int srow = tid >> 2, sk8 = (tid & 3) * 8;
    int wcol = tid >> 1, wk = (tid & 1) * 16;

    for (int kt = 0; kt < Kdim; kt += 32) {
        __syncthreads();
        *(float4*)&xs[srow][sk8]     = *(const float4*)&A[(size_t)(r0 + srow) * lda + kt + sk8];
        *(float4*)&xs[srow][sk8 + 4] = *(const float4*)&A[(size_t)(r0 + srow) * lda + kt + sk8 + 4];
        *(short8*)&ws[wcol][wk]     = *(const short8*)&Wt[(size_t)(cb + wcol) * Kdim + kt + wk];
        *(short8*)&ws[wcol][wk + 8] = *(const short8*)&Wt[(size_t)(cb + wcol) * Kdim + kt + wk + 8];
        __syncthreads();

        int arow = w * 16 + ln;
        f32x4 a0 = *(const f32x4*)&xs[arow][lg * 8];
        f32x4 a1 = *(const f32x4*)&xs[arow][lg * 8 + 4];
        float af[8] = {a0[0], a0[1], a0[2], a0[3], a1[0], a1[1], a1[2], a1[3]};
        short8 ah, al;
#pragma unroll
        for (int i = 0; i < 8; ++i) {
            unsigned short h = f2bf(af[i]);
            ah[i] = (short)h;
            float hf = __uint_as_float(((unsigned)h) << 16);
            al[i] = (short)f2bf(af[i] - hf);
        }
#pragma unroll
        for (int ct = 0; ct < 8; ++ct) {
            short8 bw = *(const short8*)&ws[ct * 16 + ln][lg * 8];
            acc[ct] = __builtin_amdgcn_mfma_f32_16x16x32_bf16(ah, bw, acc[ct], 0, 0, 0);
            acc[ct] = __builtin_amdgcn_mfma_f32_16x16x32_bf16(al, bw, acc[ct], 0, 0, 0);
        }
    }

#pragma unroll
    for (int ct = 0; ct < 8; ++ct) {
        int c = cb + ct * 16 + ln;
        float bv = bias[c];
#pragma unroll
        for (int rg = 0; rg < 4; ++rg) {
            int r = r0 + w * 16 + lg * 4 + rg;
            float v = acc[ct][rg] + bv;
            if (res) v += res[(size_t)r * 128 + c];
            if (act) v = fminf(fmaxf(v, 0.f), 6.f);
            out[(size_t)r * ldo + c] = v;
        }
    }
}

// ---------------------------------------------------------------- fused 4x node-transform MFMA GEMM
__global__ __launch_bounds__(256) void gemm4_mfma_k(
    const float* __restrict__ A, const unsigned short* __restrict__ wt4,
    const float* __restrict__ b0, const float* __restrict__ b1,
    const float* __restrict__ b2, const float* __restrict__ b3,
    float* __restrict__ o0, float* __restrict__ o1,
    float* __restrict__ o2, float* __restrict__ o3)
{
    const unsigned short* Wt = wt4 + blockIdx.y * 16384;
    const float* bias; float* out;
    if (blockIdx.y == 0)      { bias = b0; out = o0; }
    else if (blockIdx.y == 1) { bias = b1; out = o1; }
    else if (blockIdx.y == 2) { bias = b2; out = o2; }
    else                      { bias = b3; out = o3; }

    __shared__ float xs[64][36];
    __shared__ unsigned short ws[128][40];
    int tid = threadIdx.x;
    int w = tid >> 6, lane = tid & 63;
    int lg = lane >> 4, ln = lane & 15;
    int r0 = blockIdx.x * 64;

    f32x4 acc[8];
#pragma unroll
    for (int ct = 0; ct < 8; ++ct) acc[ct] = {0.f, 0.f, 0.f, 0.f};

    int srow = tid >> 2, sk8 = (tid & 3) * 8;
    int wcol = tid >> 1, wk = (tid & 1) * 16;

    for (int kt = 0; kt < 128; kt += 32) {
        __syncthreads();
        *(float4*)&xs[srow][sk8]     = *(const float4*)&A[(size_t)(r0 + srow) * 128 + kt + sk8];
        *(float4*)&xs[srow][sk8 + 4] = *(const float4*)&A[(size_t)(r0 + srow) * 128 + kt + sk8 + 4];
        *(short8*)&ws[wcol][wk]     = *(const short8*)&Wt[(size_t)wcol * 128 + kt + wk];
        *(short8*)&ws[wcol][wk + 8] = *(const short8*)&Wt[(size_t)wcol * 128 + kt + wk + 8];
        __syncthreads();

        int arow = w * 16 + ln;
        f32x4 a0 = *(const f32x4*)&xs[arow][lg * 8];
        f32x4 a1 = *(const f32x4*)&xs[arow][lg * 8 + 4];
        float af[8] = {a0[0], a0[1], a0[2], a0[3], a1[0], a1[1], a1[2], a1[3]};
        short8 ah, al;
#pragma unroll
        for (int i = 0; i < 8; ++i) {
            unsigned short h = f2bf(af[i]);
            ah[i] = (short)h;
            float hf = __uint_as_float(((unsigned)h) << 16);
            al[i] = (short)f2bf(af[i] - hf);
        }
#pragma unroll
        for (int ct = 0; ct < 8; ++ct) {
            short8 bw = *(const short8*)&ws[ct * 16 + ln][lg * 8];
            acc[ct] = __builtin_amdgcn_mfma_f32_16x16x32_bf16(ah, bw, acc[ct], 0, 0, 0);
            acc[ct] = __builtin_amdgcn_mfma_f32_16x16x32_bf16(al, bw, acc[ct], 0, 0, 0);
        }
    }

#pragma unroll
    for (int ct = 0; ct < 8; ++ct) {
        int c = ct * 16 + ln;
        float bv = bias[c];
#pragma unroll
        for (int rg = 0; rg < 4; ++rg) {
            int r = r0 + w * 16 + lg * 4 + rg;
            out[(size_t)r * 128 + c] = acc[ct][rg] + bv;
        }
    }
}

// ---------------------------------------------------------------- prep: sqnorm + bf16-hi cast (one x pass)
__global__ __launch_bounds__(256) void prep_k(const float* __restrict__ x,
                                              unsigned short* __restrict__ xh,
                                              float* __restrict__ sqn)
{
    int w = threadIdx.x >> 6, lane = threadIdx.x & 63;
    int row = blockIdx.x * 4 + w;
    float2 v = *(const float2*)&x[(size_t)row * 128 + lane * 2];
    ushort2 h = make_ushort2(f2bf(v.x), f2bf(v.y));
    *(ushort2*)&xh[(size_t)row * 128 + lane * 2] = h;
    float s = fmaf(v.y, v.y, v.x * v.x);
#pragma unroll
    for (int off = 32; off; off >>= 1) s += __shfl_xor(s, off);
    if (lane == 0) sqn[row] = s;
}

// ---------------------------------------------------------------- branchless sorted insert (ascending u32)
__device__ __forceinline__ void ins6(unsigned (&d)[6], unsigned k)
{
#pragma unroll
    for (int t = 0; t < 6; ++t) {
        unsigned lo = d[t] < k ? d[t] : k;
        unsigned hi = d[t] < k ? k : d[t];
        d[t] = lo; k = hi;
    }
}

// ---------------------------------------------------------------- kNN prefilter via MFMA
// double-buffered global_load_lds staging (linear LDS dest, inverse-swizzled
// global source, swizzled read) + group-guarded branchless selection.
__global__ __launch_bounds__(256) void knn_mfma_k(const unsigned short* __restrict__ xh,
                                                  const float* __restrict__ sqn,
                                                  int* __restrict__ cand)
{
    __shared__ char lds[33280];               // 2x16KB tiles + 2x256B biased csq

    int b = blockIdx.x;
    int g = b & 7, r = b >> 3;                // g == XCD id -> per-graph L2 locality
    int qtr = r & 3, qblk = r >> 2;
    int gbase = g * Sg;
    int cbase = qtr * QLEN;
    int qlen = (qtr < 3) ? QLEN : (Sg - 3 * QLEN);   // 1160 last
    int ntiles = (qlen + 63) >> 6;                    // 20/20/20/19
    int tid = threadIdx.x;
    int w = tid >> 6, lane = tid & 63;
    int lg = lane >> 4, ln = lane & 15;
    int q0 = qblk * 128 + w * 32;

    // resident query B-frags (hi only): [qset][kstep]
    short8 bh[2][4];
#pragma unroll
    for (int s = 0; s < 2; ++s) {
        int q = q0 + s * 16 + ln;
        int qrow = gbase + (q < Sg ? q : Sg - 1);
#pragma unroll
        for (int ks = 0; ks < 4; ++ks)
            bh[s][ks] = *(const short8*)&xh[(size_t)qrow * 128 + ks * 32 + lg * 8];
    }

    // stage tile t64 into buffer buf: DMA 16KB + csq
    auto stage = [&](int t64, int buf) {
        int c0 = cbase + t64 * 64;
#pragma unroll
        for (int i = 0; i < 4; ++i) {
            int row = i * 16 + (tid >> 4);
            int cr = c0 + row;
            if (cr >= Sg) cr = Sg - 1;
            int sslot = (tid & 15) ^ (row & 7);          // inverse swizzle on source
            const unsigned short* src = &xh[(size_t)(gbase + cr) * 128 + sslot * 8];
            char* dst = lds + buf * 16384 + i * 4096 + (tid & 192) * 16;  // wave-uniform
            __builtin_amdgcn_global_load_lds((gvp)src, (lvp)dst, 16, 0, 0);
        }
        if (tid < 64) {
            int cl = c0 + tid;
            float* cs = (float*)(lds + 32768 + buf * 256);
            cs[tid] = (cl < cbase + qlen) ? (sqn[gbase + cl] + 1024.0f) : __builtin_inff();
        }
    };

    unsigned d6a[6], d6b[6];
#pragma unroll
    for (int t = 0; t < 6; ++t) { d6a[t] = 0xFFFFFFFFu; d6b[t] = 0xFFFFFFFFu; }

    stage(0, 0);
    __syncthreads();

    for (int t64 = 0; t64 < ntiles; ++t64) {
        int cur = t64 & 1;
        if (t64 + 1 < ntiles) stage(t64 + 1, cur ^ 1);   // async prefetch
        const char* ldsH = lds + cur * 16384;
        const float* cs_s = (const float*)(lds + 32768 + cur * 256);
        int c0 = cbase + t64 * 64;

#pragma unroll
        for (int g16 = 0; g16 < 4; ++g16) {
            f32x4 acc0 = {0.f, 0.f, 0.f, 0.f};
            f32x4 acc1 = {0.f, 0.f, 0.f, 0.f};
            int rr = g16 * 16 + ln;
            int rsw = (ln & 7) << 4;                     // == (rr&7)<<4
#pragma unroll
            for (int ks = 0; ks < 4; ++ks) {
                short8 ah = *(const short8*)(ldsH + rr * 256 + ((lg * 16 + ks * 64) ^ rsw));
                acc0 = __builtin_amdgcn_mfma_f32_16x16x32_bf16(ah, bh[0][ks], acc0, 0, 0, 0);
                acc1 = __builtin_amdgcn_mfma_f32_16x16x32_bf16(ah, bh[1][ks], acc1, 0, 0, 0);
            }
            f32x4 cv = *(const f32x4*)&cs_s[g16 * 16 + lg * 4];   // biased +1024
            int idx0 = (c0 - cbase) + g16 * 16 + lg * 4;          // quarter-local, 11 bits
            unsigned kb0[4], kb1[4];
#pragma unroll
            for (int rg = 0; rg < 4; ++rg) {
                kb0[rg] = __float_as_uint(fmaf(-2.f, acc0[rg], cv[rg]));
                kb1[rg] = __float_as_uint(fmaf(-2.f, acc1[rg], cv[rg]));
            }
            unsigned mn0 = umin2(umin2(kb0[0], kb0[1]), umin2(kb0[2], kb0[3]));
            unsigned mn1 = umin2(umin2(kb1[0], kb1[1]), umin2(kb1[2], kb1[3]));
            if ((mn0 & 0xFFFFF800u) < d6a[5]) {          // group guard (exact: inner cmp unchanged)
#pragma unroll
                for (int rg = 0; rg < 4; ++rg) {
                    unsigned k = (kb0[rg] & 0xFFFFF800u) | (unsigned)(idx0 + rg);
                    if (k < d6a[5]) ins6(d6a, k);
                }
            }
            if ((mn1 & 0xFFFFF800u) < d6b[5]) {
#pragma unroll
                for (int rg = 0; rg < 4; ++rg) {
                    unsigned k = (kb1[rg] & 0xFFFFF800u) | (unsigned)(idx0 + rg);
                    if (k < d6b[5]) ins6(d6b, k);
                }
            }
        }
        __syncthreads();   // waves done reading buf[cur]; prefetch loads drained
    }

    // in-wave merge: partials for query (s, ln) live in lanes ln + 16*lg.
#pragma unroll
    for (int s = 0; s < 2; ++s) {
        unsigned m12[12];
#pragma unroll
        for (int t = 0; t < 6; ++t) m12[t] = s ? d6b[t] : d6a[t];
#pragma unroll
        for (int t = 6; t < 12; ++t) m12[t] = 0xFFFFFFFFu;
#pragma unroll
        for (int sg = 1; sg < 4; ++sg)
#pragma unroll
            for (int t = 0; t < 6; ++t) {
                unsigned v = __shfl(s ? d6b[t] : d6a[t], ln + sg * 16);
#pragma unroll
                for (int u = 0; u < 12; ++u) {
                    unsigned lo = m12[u] < v ? m12[u] : v;
                    unsigned hi = m12[u] < v ? v : m12[u];
                    m12[u] = lo; v = hi;
                }
            }
        int q = q0 + s * 16 + ln;
        if (lg == 0 && q < Sg) {
            int* cp = &cand[(size_t)(gbase + q) * NCAND + qtr * 12];
#pragma unroll
            for (int t = 0; t < 12; ++t) cp[t] = gbase + cbase + (int)(m12[t] & 2047u);
        }
    }
}

// ---------------------------------------------------------------- exact fp32 re-rank, wave per query
__global__ __launch_bounds__(256) void knn_rerank_k(const float* __restrict__ x,
                                                    const float* __restrict__ sqn,
                                                    const int* __restrict__ cand,
                                                    int* __restrict__ knn_idx)
{
    int w = threadIdx.x >> 6, lane = threadIdx.x & 63;
    int grp = lane >> 4, gl = lane & 15;
    int q = blockIdx.x * 4 + w;
    float4 qa = *(const float4*)&x[(size_t)q * 128 + gl * 8];
    float4 qb = *(const float4*)&x[(size_t)q * 128 + gl * 8 + 4];
    const int* cp = &cand[(size_t)q * NCAND + grp * 12];

    float d6[6]; int i6[6]; float mx = __builtin_inff(); int sl = 0;
#pragma unroll
    for (int t = 0; t < 6; ++t) { d6[t] = __builtin_inff(); i6[t] = -1; }

#pragma unroll 2
    for (int j = 0; j < 12; ++j) {
        int c = cp[j];
        bool ok = (unsigned)c < (unsigned)N && c != q;
        int ca = ok ? c : 0;
        float4 va = *(const float4*)&x[(size_t)ca * 128 + gl * 8];
        float4 vb = *(const float4*)&x[(size_t)ca * 128 + gl * 8 + 4];
        float p = qa.x * va.x;
        p = fmaf(qa.y, va.y, p); p = fmaf(qa.z, va.z, p); p = fmaf(qa.w, va.w, p);
        p = fmaf(qb.x, vb.x, p); p = fmaf(qb.y, vb.y, p);
        p = fmaf(qb.z, vb.z, p); p = fmaf(qb.w, vb.w, p);
#pragma unroll
        for (int off = 1; off < 16; off <<= 1) p += __shfl_xor(p, off);
        float dv = ok ? fmaf(-2.f, p, sqn[ca]) : __builtin_inff();
        if (dv < mx) {
#pragma unroll
            for (int t = 0; t < 6; ++t)
                if (t == sl) { d6[t] = dv; i6[t] = c; }
            float m2 = d6[0]; int s2 = 0;
#pragma unroll
            for (int t = 1; t < 6; ++t)
                if (d6[t] > m2) { m2 = d6[t]; s2 = t; }
            mx = m2; sl = s2;
        }
    }

#pragma unroll
    for (int sg = 1; sg < 4; ++sg) {
#pragma unroll
        for (int t = 0; t < 6; ++t) {
            float dv = __shfl(d6[t], gl + sg * 16);
            int ci = __shfl(i6[t], gl + sg * 16);
            if (grp == 0 && dv < mx) {
#pragma unroll
                for (int u = 0; u < 6; ++u)
                    if (u == sl) { d6[u] = dv; i6[u] = ci; }
                float m2 = d6[0]; int s2 = 0;
#pragma unroll
                for (int u = 1; u < 6; ++u)
                    if (d6[u] > m2) { m2 = d6[u]; s2 = u; }
                mx = m2; sl = s2;
            }
        }
    }
    if (lane < 6) {
        int v;
#pragma unroll
        for (int t = 0; t < 6; ++t) if (t == lane) v = i6[t];
        knn_idx[(size_t)q * 6 + lane] = v;
    }
}

// ---------------------------------------------------------------- CSR build
__global__ __launch_bounds__(256) void hist_k(const int* __restrict__ dstA, int* __restrict__ deg)
{
    int e = blockIdx.x * 256 + threadIdx.x;
    atomicAdd(&deg[dstA[e]], 1);
}

__global__ __launch_bounds__(1024) void scan_k(const int* __restrict__ deg, int* __restrict__ rowptr)
{
    __shared__ int ps[1024];
    int t = threadIdx.x;
    const int chunk = 40;
    int base = t * chunk;
    int s = 0;
    for (int k = 0; k < chunk; ++k) { int i = base + k; if (i < N) s += deg[i]; }
    ps[t] = s;
    __syncthreads();
    for (int off = 1; off < 1024; off <<= 1) {
        int v = (t >= off) ? ps[t - off] : 0;
        __syncthreads();
        ps[t] += v;
        __syncthreads();
    }
    int run = ps[t] - s;
    for (int k = 0; k < chunk; ++k) {
        int i = base + k;
        if (i < N) { rowptr[i] = run; run += deg[i]; }
    }
    if (t == 0) rowptr[N] = E;
}

__global__ __launch_bounds__(256) void scatter_k(const int* __restrict__ srcA, const int* __restrict__ dstA,
                                                 const float* __restrict__ ea,
                                                 const int* __restrict__ rowptr, int* __restrict__ cnt,
                                                 int* __restrict__ csr_src, float* __restrict__ csr_ea)
{
    int e = blockIdx.x * 256 + threadIdx.x;
    int d = dstA[e];
    int pos = rowptr[d] + atomicAdd(&cnt[d], 1);
    csr_src[pos] = srcA[e];
    csr_ea[pos] = ea[e];
}

// ---------------------------------------------------------------- spatial GATv2, single-pass online softmax
// wave per dst: each gathered xl row feeds logit AND accumulation (1x gather).
__global__ __launch_bounds__(256) void spatial_gat_k(
    const float* __restrict__ xl, const float* __restrict__ xr,
    const int* __restrict__ rowptr, const int* __restrict__ csr_src, const float* __restrict__ csr_ea,
    const float* __restrict__ att, const float* __restrict__ wse, const float* __restrict__ bias,
    float* __restrict__ ch2)
{
    int w = threadIdx.x >> 6, lane = threadIdx.x & 63;
    int dst = blockIdx.x * 4 + w;
    int base = rowptr[dst];
    int deg = rowptr[dst + 1] - base;
    float xr0 = xr[(size_t)dst * 128 + lane], xr1 = xr[(size_t)dst * 128 + 64 + lane];
    float at0 = att[lane], at1 = att[64 + lane];
    float we0 = wse[lane], we1 = wse[64 + lane];

    float m = -1e30f, ssum = 0.f, o0 = 0.f, o1 = 0.f;
    for (int i = 0; i < deg; ++i) {
        int s = csr_src[base + i];
        float ea = csr_ea[base + i];
        float v0 = xl[(size_t)s * 128 + lane];
        float v1 = xl[(size_t)s * 128 + 64 + lane];
        float h0 = fmaf(ea, we0, v0 + xr0);
        float h1 = fmaf(ea, we1, v1 + xr1);
        h0 = h0 > 0.f ? h0 : 0.2f * h0;
        h1 = h1 > 0.f ? h1 : 0.2f * h1;
        float p = fmaf(h1, at1, h0 * at0);
#pragma unroll
        for (int off = 32; off; off >>= 1) p += __shfl_xor(p, off);
        if (p <= m) {                       // wave-uniform branch
            float wt = __expf(p - m);
            ssum += wt;
            o0 = fmaf(wt, v0, o0);
            o1 = fmaf(wt, v1, o1);
        } else {
            float sc = __expf(m - p);
            ssum = fmaf(ssum, sc, 1.f);
            o0 = fmaf(o0, sc, v0);
            o1 = fmaf(o1, sc, v1);
            m = p;
        }
    }
    float inv = deg > 0 ? 1.f / ssum : 0.f;
    ch2[(size_t)dst * 256 + lane]      = fmaf(o0, inv, bias[lane]);
    ch2[(size_t)dst * 256 + 64 + lane] = fmaf(o1, inv, bias[64 + lane]);
}

// ---------------------------------------------------------------- latent GATv2 (wave per dst; 6 knn + self)
__global__ __launch_bounds__(256) void latent_gat_k(
    const float* __restrict__ xl, const float* __restrict__ xr,
    const int* __restrict__ knn, const float* __restrict__ att,
    const float* __restrict__ bias, float* __restrict__ ch2)
{
    int w = threadIdx.x >> 6, lane = threadIdx.x & 63;
    int dst = blockIdx.x * 4 + w;
    float xr0 = xr[(size_t)dst * 128 + lane], xr1 = xr[(size_t)dst * 128 + 64 + lane];
    float at0 = att[lane], at1 = att[64 + lane];
    int s[7];
#pragma unroll
    for (int j = 0; j < 6; ++j) s[j] = knn[(size_t)dst * 6 + j];
    s[6] = dst;
    float l[7];
#pragma unroll
    for (int j = 0; j < 7; ++j) {
        float h0 = xl[(size_t)s[j] * 128 + lane] + xr0;
        float h1 = xl[(size_t)s[j] * 128 + 64 + lane] + xr1;
        h0 = h0 > 0.f ? h0 : 0.2f * h0;
        h1 = h1 > 0.f ? h1 : 0.2f * h1;
        float p = h0 * at0 + h1 * at1;
#pragma unroll
        for (int off = 32; off; off >>= 1) p += __shfl_xor(p, off);
        l[j] = p;
    }
    float m = l[0];
#pragma unroll
    for (int j = 1; j < 7; ++j) m = fmaxf(m, l[j]);
    float sum = 0.f;
#pragma unroll
    for (int j = 0; j < 7; ++j) { l[j] = __expf(l[j] - m); sum += l[j]; }
    float inv = 1.f / sum;
    float o0 = 0.f, o1 = 0.f;
#pragma unroll
    for (int j = 0; j < 7; ++j) {
        float a = l[j] * inv;
        o0 = fmaf(a, xl[(size_t)s[j] * 128 + lane], o0);
        o1 = fmaf(a, xl[(size_t)s[j] * 128 + 64 + lane], o1);
    }
    ch2[(size_t)dst * 256 + 128 + lane] = o0 + bias[lane];
    ch2[(size_t)dst * 256 + 192 + lane] = o1 + bias[64 + lane];
}

// ---------------------------------------------------------------- launch
extern "C" void kernel_launch(void* const* d_in, const int* in_sizes, int n_in,
                              void* d_out, int out_size, void* d_ws, size_t ws_size,
                              hipStream_t stream)
{
    const float* x      = (const float*)d_in[0];
    const int*   ei     = (const int*)  d_in[1];
    const float* eattr  = (const float*)d_in[2];
    const float* W_sl   = (const float*)d_in[4];
    const float* b_sl   = (const float*)d_in[5];
    const float* W_sr   = (const float*)d_in[6];
    const float* b_sr   = (const float*)d_in[7];
    const float* att_s  = (const float*)d_in[8];
    const float* W_se   = (const float*)d_in[9];
    const float* bias_s = (const float*)d_in[10];
    const float* W_ll   = (const float*)d_in[11];
    const float* b_ll   = (const float*)d_in[12];
    const float* W_lr   = (const float*)d_in[13];
    const float* b_lr   = (const float*)d_in[14];
    const float* att_l  = (const float*)d_in[15];
    const float* bias_l = (const float*)d_in[16];
    const float* W_c    = (const float*)d_in[17];
    const float* b_c    = (const float*)d_in[18];
    const float* W_f1   = (const float*)d_in[19];
    const float* b_f1   = (const float*)d_in[20];
    const float* W_f2   = (const float*)d_in[21];
    const float* b_f2   = (const float*)d_in[22];
    float* out = (float*)d_out;

    char* wp = (char*)d_ws;
    auto take = [&](size_t bytes) { char* p = wp; wp += (bytes + 255) & ~(size_t)255; return p; };
    float* xl_s    = (float*)take((size_t)N * D * 4);
    float* xr_s    = (float*)take((size_t)N * D * 4);
    float* xl_l    = (float*)take((size_t)N * D * 4);
    float* xr_l    = (float*)take((size_t)N * D * 4);
    float* ch2     = (float*)take((size_t)N * 2 * D * 4);
    float* sqn     = (float*)take((size_t)N * 4);
    int*   knn_idx = (int*)  take((size_t)N * KN * 4);
    int*   deg     = (int*)  take((size_t)N * 4);
    int*   rowptr  = (int*)  take((size_t)(N + 1) * 4);
    int*   csr_src = (int*)  take((size_t)E * 4);
    float* csr_ea  = (float*)take((size_t)E * 4);
    unsigned short* x_hi = (unsigned short*)take((size_t)N * D * 2);
    int*   knn_cand = (int*)take((size_t)N * NCAND * 4);
    unsigned short* wt4  = (unsigned short*)take(65536 * 2);
    unsigned short* wtc  = (unsigned short*)take(32768 * 2);
    unsigned short* wtf1 = (unsigned short*)take(32768 * 2);
    unsigned short* wtf2 = (unsigned short*)take(32768 * 2);
    float* fused   = xl_s;
    float* hbuf    = ch2;
    if ((size_t)(wp - (char*)d_ws) > ws_size) return;

    dim3 blk(256);

    // weight transpose + bf16 cast (one-shot, all matrices)
    w_prep_k<<<dim3(640), blk, 0, stream>>>(W_sl, W_sr, W_ll, W_lr, W_c, W_f1, W_f2,
                                            wt4, wtc, wtf1, wtf2);

    // fused node transforms: 4 outputs, one launch, MFMA
    gemm4_mfma_k<<<dim3(N / 64, 4), blk, 0, stream>>>(x, wt4,
        b_sl, b_sr, b_ll, b_lr, xl_s, xr_s, xl_l, xr_l);

    // kNN graph: prep -> bf16 MFMA prefilter -> exact fp32 re-rank
    prep_k<<<dim3(N / 4), blk, 0, stream>>>(x, x_hi, sqn);
    knn_mfma_k<<<dim3(Bg * 40 * 4), blk, 0, stream>>>(x_hi, sqn, knn_cand);
    knn_rerank_k<<<dim3(N / 4), blk, 0, stream>>>(x, sqn, knn_cand, knn_idx);

    // CSR of spatial edges by dst
    hipMemsetAsync(deg, 0, (size_t)N * 4, stream);
    hist_k<<<dim3(E / 256), blk, 0, stream>>>(ei + E, deg);
    scan_k<<<dim3(1), dim3(1024), 0, stream>>>(deg, rowptr);
    hipMemsetAsync(deg, 0, (size_t)N * 4, stream);
    scatter_k<<<dim3(E / 256), blk, 0, stream>>>(ei, ei + E, eattr, rowptr, deg, csr_src, csr_ea);

    // two GAT channels -> ch2 = [ch_sp | ch_lat]
    spatial_gat_k<<<dim3(N / 4), blk, 0, stream>>>(xl_s, xr_s, rowptr, csr_src, csr_ea,
                                                   att_s, W_se, bias_s, ch2);
    latent_gat_k<<<dim3(N / 4), blk, 0, stream>>>(xl_l, xr_l, knn_idx, att_l, bias_l, ch2);

    // fusion + FFN (MFMA)
    gemm_mfma_k<<<dim3(N / 64, 1), blk, 0, stream>>>(ch2, 2 * D, wtc, 256, b_c, x, fused, 128, 0);
    gemm_mfma_k<<<dim3(N / 64, 2), blk, 0, stream>>>(fused, 128, wtf1, 128, b_f1, nullptr, hbuf, 256, 1);
    gemm_mfma_k<<<dim3(N / 64, 1), blk, 0, stream>>>(hbuf, 256, wtf2, 256, b_f2, fused, out, 128, 1);
}

// Round 10
// 570.586 us; speedup vs baseline: 2.2804x; 1.0238x over previous
//
#include <hip/hip_runtime.h>
#include <math.h>

// ---------------------------------------------------------------- constants
constexpr int N  = 40000;   // nodes
constexpr int D  = 128;     // latent dim
constexpr int E  = 640000;  // spatial edges
constexpr int Bg = 8;       // graphs
constexpr int Sg = 5000;    // nodes per graph
constexpr int KN = 6;       // knn
constexpr int FF = 256;     // ffn hidden
constexpr int QLEN = 1280;  // candidate quarter length (64-aligned); last 1160
constexpr int NCAND = 48;   // 4 quarters x top-12

typedef short short8 __attribute__((ext_vector_type(8)));
typedef float f32x4  __attribute__((ext_vector_type(4)));

// ---------------------------------------------------------------- bf16 helpers
__device__ __forceinline__ unsigned short f2bf(float f)
{
    unsigned int u = __float_as_uint(f);
    return (unsigned short)((u + 0x7fffu + ((u >> 16) & 1u)) >> 16);
}

__device__ __forceinline__ unsigned umin2(unsigned a, unsigned b) { return a < b ? a : b; }

// ---------------------------------------------------------------- W pre-transpose + bf16 cast (one-shot)
__global__ __launch_bounds__(256) void w_prep_k(
    const float* __restrict__ W0, const float* __restrict__ W1,
    const float* __restrict__ W2, const float* __restrict__ W3,
    const float* __restrict__ Wc, const float* __restrict__ Wf1,
    const float* __restrict__ Wf2,
    unsigned short* __restrict__ wt4, unsigned short* __restrict__ wtc,
    unsigned short* __restrict__ wtf1, unsigned short* __restrict__ wtf2)
{
    int idx = blockIdx.x * 256 + threadIdx.x;
    if (idx < 65536) {                        // node transforms [128][128]
        int m = idx >> 14, rem = idx & 16383;
        int k = rem & 127, c = rem >> 7;
        const float* Wm = (m == 0) ? W0 : (m == 1) ? W1 : (m == 2) ? W2 : W3;
        wt4[m * 16384 + c * 128 + k] = f2bf(Wm[k * 128 + c]);
    } else if (idx < 98304) {                 // W_c [256][128] -> [128][256]
        int rem = idx - 65536; int k = rem & 255, c = rem >> 8;
        wtc[c * 256 + k] = f2bf(Wc[k * 128 + c]);
    } else if (idx < 131072) {                // W_f1 [128][256] -> [256][128]
        int rem = idx - 98304; int k = rem & 127, c = rem >> 7;
        wtf1[c * 128 + k] = f2bf(Wf1[k * 256 + c]);
    } else {                                  // W_f2 [256][128] -> [128][256]
        int rem = idx - 131072; int k = rem & 255, c = rem >> 8;
        wtf2[c * 256 + k] = f2bf(Wf2[k * 128 + c]);
    }
}

// ---------------------------------------------------------------- MFMA GEMM: out = A@W + bias (+res) (+relu6)
__global__ __launch_bounds__(256) void gemm_mfma_k(
    const float* __restrict__ A, int lda,
    const unsigned short* __restrict__ Wt, int Kdim,
    const float* __restrict__ bias,
    const float* __restrict__ res,
    float* __restrict__ out, int ldo, int act)
{
    __shared__ float xs[64][36];
    __shared__ unsigned short ws[128][40];
    int tid = threadIdx.x;
    int w = tid >> 6, lane = tid & 63;
    int lg = lane >> 4, ln = lane & 15;
    int r0 = blockIdx.x * 64;
    int cb = blockIdx.y * 128;

    f32x4 acc[8];
#pragma unroll
    for (int ct = 0; ct < 8; ++ct) acc[ct] = {0.f, 0.f, 0.f, 0.f};

    int srow = tid >> 2, sk8 = (tid & 3) * 8;
    int wcol = tid >> 1, wk = (tid & 1) * 16;

    for (int kt = 0; kt < Kdim; kt += 32) {
        __syncthreads();
        *(float4*)&xs[srow][sk8]     = *(const float4*)&A[(size_t)(r0 + srow) * lda + kt + sk8];
        *(float4*)&xs[srow][sk8 + 4] = *(const float4*)&A[(size_t)(r0 + srow) * lda + kt + sk8 + 4];
        *(short8*)&ws[wcol][wk]     = *(const short8*)&Wt[(size_t)(cb + wcol) * Kdim + kt + wk];
        *(short8*)&ws[wcol][wk + 8] = *(const short8*)&Wt[(size_t)(cb + wcol) * Kdim + kt + wk + 8];
        __syncthreads();

        int arow = w * 16 + ln;
        f32x4 a0 = *(const f32x4*)&xs[arow][lg * 8];
        f32x4 a1 = *(const f32x4*)&xs[arow][lg * 8 + 4];
        float af[8] = {a0[0], a0[1], a0[2], a0[3], a1[0], a1[1], a1[2], a1[3]};
        short8 ah, al;
#pragma unroll
        for (int i = 0; i < 8; ++i) {
            unsigned short h = f2bf(af[i]);
            ah[i] = (short)h;
            float hf = __uint_as_float(((unsigned)h) << 16);
            al[i] = (short)f2bf(af[i] - hf);
        }
#pragma unroll
        for (int ct = 0; ct < 8; ++ct) {
            short8 bw = *(const short8*)&ws[ct * 16 + ln][lg * 8];
            acc[ct] = __builtin_amdgcn_mfma_f32_16x16x32_bf16(ah, bw, acc[ct], 0, 0, 0);
            acc[ct] = __builtin_amdgcn_mfma_f32_16x16x32_bf16(al, bw, acc[ct], 0, 0, 0);
        }
    }

#pragma unroll
    for (int ct = 0; ct < 8; ++ct) {
        int c = cb + ct * 16 + ln;
        float bv = bias[c];
#pragma unroll
        for (int rg = 0; rg < 4; ++rg) {
            int r = r0 + w * 16 + lg * 4 + rg;
            float v = acc[ct][rg] + bv;
            if (res) v += res[(size_t)r * 128 + c];
            if (act) v = fminf(fmaxf(v, 0.f), 6.f);
            out[(size_t)r * ldo + c] = v;
        }
    }
}

// ---------------------------------------------------------------- fused 4x node-transform MFMA GEMM
__global__ __launch_bounds__(256) void gemm4_mfma_k(
    const float* __restrict__ A, const unsigned short* __restrict__ wt4,
    const float* __restrict__ b0, const float* __restrict__ b1,
    const float* __restrict__ b2, const float* __restrict__ b3,
    float* __restrict__ o0, float* __restrict__ o1,
    float* __restrict__ o2, float* __restrict__ o3)
{
    const unsigned short* Wt = wt4 + blockIdx.y * 16384;
    const float* bias; float* out;
    if (blockIdx.y == 0)      { bias = b0; out = o0; }
    else if (blockIdx.y == 1) { bias = b1; out = o1; }
    else if (blockIdx.y == 2) { bias = b2; out = o2; }
    else                      { bias = b3; out = o3; }

    __shared__ float xs[64][36];
    __shared__ unsigned short ws[128][40];
    int tid = threadIdx.x;
    int w = tid >> 6, lane = tid & 63;
    int lg = lane >> 4, ln = lane & 15;
    int r0 = blockIdx.x * 64;

    f32x4 acc[8];
#pragma unroll
    for (int ct = 0; ct < 8; ++ct) acc[ct] = {0.f, 0.f, 0.f, 0.f};

    int srow = tid >> 2, sk8 = (tid & 3) * 8;
    int wcol = tid >> 1, wk = (tid & 1) * 16;

    for (int kt = 0; kt < 128; kt += 32) {
        __syncthreads();
        *(float4*)&xs[srow][sk8]     = *(const float4*)&A[(size_t)(r0 + srow) * 128 + kt + sk8];
        *(float4*)&xs[srow][sk8 + 4] = *(const float4*)&A[(size_t)(r0 + srow) * 128 + kt + sk8 + 4];
        *(short8*)&ws[wcol][wk]     = *(const short8*)&Wt[(size_t)wcol * 128 + kt + wk];
        *(short8*)&ws[wcol][wk + 8] = *(const short8*)&Wt[(size_t)wcol * 128 + kt + wk + 8];
        __syncthreads();

        int arow = w * 16 + ln;
        f32x4 a0 = *(const f32x4*)&xs[arow][lg * 8];
        f32x4 a1 = *(const f32x4*)&xs[arow][lg * 8 + 4];
        float af[8] = {a0[0], a0[1], a0[2], a0[3], a1[0], a1[1], a1[2], a1[3]};
        short8 ah, al;
#pragma unroll
        for (int i = 0; i < 8; ++i) {
            unsigned short h = f2bf(af[i]);
            ah[i] = (short)h;
            float hf = __uint_as_float(((unsigned)h) << 16);
            al[i] = (short)f2bf(af[i] - hf);
        }
#pragma unroll
        for (int ct = 0; ct < 8; ++ct) {
            short8 bw = *(const short8*)&ws[ct * 16 + ln][lg * 8];
            acc[ct] = __builtin_amdgcn_mfma_f32_16x16x32_bf16(ah, bw, acc[ct], 0, 0, 0);
            acc[ct] = __builtin_amdgcn_mfma_f32_16x16x32_bf16(al, bw, acc[ct], 0, 0, 0);
        }
    }

#pragma unroll
    for (int ct = 0; ct < 8; ++ct) {
        int c = ct * 16 + ln;
        float bv = bias[c];
#pragma unroll
        for (int rg = 0; rg < 4; ++rg) {
            int r = r0 + w * 16 + lg * 4 + rg;
            out[(size_t)r * 128 + c] = acc[ct][rg] + bv;
        }
    }
}

// ---------------------------------------------------------------- prep: sqnorm + bf16-hi cast (one x pass)
__global__ __launch_bounds__(256) void prep_k(const float* __restrict__ x,
                                              unsigned short* __restrict__ xh,
                                              float* __restrict__ sqn)
{
    int w = threadIdx.x >> 6, lane = threadIdx.x & 63;
    int row = blockIdx.x * 4 + w;
    float2 v = *(const float2*)&x[(size_t)row * 128 + lane * 2];
    ushort2 h = make_ushort2(f2bf(v.x), f2bf(v.y));
    *(ushort2*)&xh[(size_t)row * 128 + lane * 2] = h;
    float s = fmaf(v.y, v.y, v.x * v.x);
#pragma unroll
    for (int off = 32; off; off >>= 1) s += __shfl_xor(s, off);
    if (lane == 0) sqn[row] = s;
}

// ---------------------------------------------------------------- branchless sorted insert (ascending u32)
__device__ __forceinline__ void ins6(unsigned (&d)[6], unsigned k)
{
#pragma unroll
    for (int t = 0; t < 6; ++t) {
        unsigned lo = d[t] < k ? d[t] : k;
        unsigned hi = d[t] < k ? k : d[t];
        d[t] = lo; k = hi;
    }
}

// ---------------------------------------------------------------- kNN prefilter via MFMA
// single 16KB LDS tile, reg staging with hoisted per-lane addresses,
// peeled clamp tile (only qtr 3's last tile), group-guarded selection.
__global__ __launch_bounds__(256) void knn_mfma_k(const unsigned short* __restrict__ xh,
                                                  const float* __restrict__ sqn,
                                                  int* __restrict__ cand)
{
    __shared__ char lds[16640];               // 16KB hi tile + 256B biased csq
    char* ldsH = lds;
    float* cs_s = (float*)(lds + 16384);

    int b = blockIdx.x;
    int g = b & 7, r = b >> 3;                // g == XCD id -> per-graph L2 locality
    int qtr = r & 3, qblk = r >> 2;
    int gbase = g * Sg;
    int cbase = qtr * QLEN;
    int qlen = (qtr < 3) ? QLEN : (Sg - 3 * QLEN);   // 1160 last
    int ntiles = (qlen + 63) >> 6;                    // 20/20/20/19
    int nfull = (qtr < 3) ? ntiles : ntiles - 1;      // tiles needing no clamp/guard
    int tid = threadIdx.x;
    int w = tid >> 6, lane = tid & 63;
    int lg = lane >> 4, ln = lane & 15;
    int q0 = qblk * 128 + w * 32;

    // resident query B-frags (hi only): [qset][kstep]
    short8 bh[2][4];
#pragma unroll
    for (int s = 0; s < 2; ++s) {
        int q = q0 + s * 16 + ln;
        int qrow = gbase + (q < Sg ? q : Sg - 1);
#pragma unroll
        for (int ks = 0; ks < 4; ++ks)
            bh[s][ks] = *(const short8*)&xh[(size_t)qrow * 128 + ks * 32 + lg * 8];
    }

    // hoisted staging addresses: lane stages rows {i*16 + tid>>4}, 16B chunk tid&15.
    // (row&7) == ((tid>>4)&7) since 16 = 0 mod 8 -> swizzle tile-invariant.
    int srow = tid >> 4, sslot = tid & 15;
    int sw_st = (srow & 7) << 4;
    int dstoff[4];
    const unsigned short* src[4];
#pragma unroll
    for (int i = 0; i < 4; ++i) {
        int row = i * 16 + srow;
        dstoff[i] = row * 256 + ((sslot * 16) ^ sw_st);
        src[i] = &xh[(size_t)(gbase + cbase + row) * 128 + sslot * 8];
    }
    const float* csrc = &sqn[gbase + cbase];

    unsigned d6a[6], d6b[6];
#pragma unroll
    for (int t = 0; t < 6; ++t) { d6a[t] = 0xFFFFFFFFu; d6b[t] = 0xFFFFFFFFu; }

    for (int t64 = 0; t64 < ntiles; ++t64) {
        __syncthreads();
        if (t64 < nfull) {                    // fast path: no clamp, no csq guard
#pragma unroll
            for (int i = 0; i < 4; ++i) {
                short8 vh = *(const short8*)src[i];
                src[i] += 64 * 128;           // next tile
                *(short8*)(ldsH + dstoff[i]) = vh;
            }
            if (tid < 64) cs_s[tid] = csrc[tid] + 1024.0f;
        } else {                              // peeled: qtr==3 last tile only
            int c0 = cbase + t64 * 64;
#pragma unroll
            for (int i = 0; i < 4; ++i) {
                int cr = c0 + i * 16 + srow;
                if (cr >= Sg) cr = Sg - 1;
                short8 vh = *(const short8*)&xh[(size_t)(gbase + cr) * 128 + sslot * 8];
                *(short8*)(ldsH + dstoff[i]) = vh;
            }
            if (tid < 64) {
                int cl = c0 + tid;
                cs_s[tid] = (cl < cbase + qlen) ? (sqn[gbase + cl] + 1024.0f) : __builtin_inff();
            }
        }
        csrc += 64;
        __syncthreads();

        int c0 = cbase + t64 * 64;
#pragma unroll
        for (int g16 = 0; g16 < 4; ++g16) {
            f32x4 acc0 = {0.f, 0.f, 0.f, 0.f};
            f32x4 acc1 = {0.f, 0.f, 0.f, 0.f};
            int rr = g16 * 16 + ln;
            int rsw = (ln & 7) << 4;          // == (rr&7)<<4
#pragma unroll
            for (int ks = 0; ks < 4; ++ks) {
                short8 ah = *(const short8*)(ldsH + rr * 256 + ((lg * 16 + ks * 64) ^ rsw));
                acc0 = __builtin_amdgcn_mfma_f32_16x16x32_bf16(ah, bh[0][ks], acc0, 0, 0, 0);
                acc1 = __builtin_amdgcn_mfma_f32_16x16x32_bf16(ah, bh[1][ks], acc1, 0, 0, 0);
            }
            f32x4 cv = *(const f32x4*)&cs_s[g16 * 16 + lg * 4];   // biased +1024
            int idx0 = (c0 - cbase) + g16 * 16 + lg * 4;          // quarter-local, 11 bits
            unsigned kb0[4], kb1[4];
#pragma unroll
            for (int rg = 0; rg < 4; ++rg) {
                kb0[rg] = __float_as_uint(fmaf(-2.f, acc0[rg], cv[rg]));
                kb1[rg] = __float_as_uint(fmaf(-2.f, acc1[rg], cv[rg]));
            }
            unsigned mn0 = umin2(umin2(kb0[0], kb0[1]), umin2(kb0[2], kb0[3]));
            unsigned mn1 = umin2(umin2(kb1[0], kb1[1]), umin2(kb1[2], kb1[3]));
            if ((mn0 & 0xFFFFF800u) < d6a[5]) {   // guard exact: inner cmp unchanged
#pragma unroll
                for (int rg = 0; rg < 4; ++rg) {
                    unsigned k = (kb0[rg] & 0xFFFFF800u) | (unsigned)(idx0 + rg);
                    if (k < d6a[5]) ins6(d6a, k);
                }
            }
            if ((mn1 & 0xFFFFF800u) < d6b[5]) {
#pragma unroll
                for (int rg = 0; rg < 4; ++rg) {
                    unsigned k = (kb1[rg] & 0xFFFFF800u) | (unsigned)(idx0 + rg);
                    if (k < d6b[5]) ins6(d6b, k);
                }
            }
        }
    }

    // in-wave merge: partials for query (s, ln) live in lanes ln + 16*lg.
#pragma unroll
    for (int s = 0; s < 2; ++s) {
        unsigned m12[12];
#pragma unroll
        for (int t = 0; t < 6; ++t) m12[t] = s ? d6b[t] : d6a[t];
#pragma unroll
        for (int t = 6; t < 12; ++t) m12[t] = 0xFFFFFFFFu;
#pragma unroll
        for (int sg = 1; sg < 4; ++sg)
#pragma unroll
            for (int t = 0; t < 6; ++t) {
                unsigned v = __shfl(s ? d6b[t] : d6a[t], ln + sg * 16);
#pragma unroll
                for (int u = 0; u < 12; ++u) {
                    unsigned lo = m12[u] < v ? m12[u] : v;
                    unsigned hi = m12[u] < v ? v : m12[u];
                    m12[u] = lo; v = hi;
                }
            }
        int q = q0 + s * 16 + ln;
        if (lg == 0 && q < Sg) {
            int* cp = &cand[(size_t)(gbase + q) * NCAND + qtr * 12];
#pragma unroll
            for (int t = 0; t < 12; ++t) cp[t] = gbase + cbase + (int)(m12[t] & 2047u);
        }
    }
}

// ---------------------------------------------------------------- exact fp32 re-rank, wave per query
__global__ __launch_bounds__(256) void knn_rerank_k(const float* __restrict__ x,
                                                    const float* __restrict__ sqn,
                                                    const int* __restrict__ cand,
                                                    int* __restrict__ knn_idx)
{
    int w = threadIdx.x >> 6, lane = threadIdx.x & 63;
    int grp = lane >> 4, gl = lane & 15;
    int q = blockIdx.x * 4 + w;
    float4 qa = *(const float4*)&x[(size_t)q * 128 + gl * 8];
    float4 qb = *(const float4*)&x[(size_t)q * 128 + gl * 8 + 4];
    const int* cp = &cand[(size_t)q * NCAND + grp * 12];

    float d6[6]; int i6[6]; float mx = __builtin_inff(); int sl = 0;
#pragma unroll
    for (int t = 0; t < 6; ++t) { d6[t] = __builtin_inff(); i6[t] = -1; }

#pragma unroll 2
    for (int j = 0; j < 12; ++j) {
        int c = cp[j];
        bool ok = (unsigned)c < (unsigned)N && c != q;
        int ca = ok ? c : 0;
        float4 va = *(const float4*)&x[(size_t)ca * 128 + gl * 8];
        float4 vb = *(const float4*)&x[(size_t)ca * 128 + gl * 8 + 4];
        float p = qa.x * va.x;
        p = fmaf(qa.y, va.y, p); p = fmaf(qa.z, va.z, p); p = fmaf(qa.w, va.w, p);
        p = fmaf(qb.x, vb.x, p); p = fmaf(qb.y, vb.y, p);
        p = fmaf(qb.z, vb.z, p); p = fmaf(qb.w, vb.w, p);
#pragma unroll
        for (int off = 1; off < 16; off <<= 1) p += __shfl_xor(p, off);
        float dv = ok ? fmaf(-2.f, p, sqn[ca]) : __builtin_inff();
        if (dv < mx) {
#pragma unroll
            for (int t = 0; t < 6; ++t)
                if (t == sl) { d6[t] = dv; i6[t] = c; }
            float m2 = d6[0]; int s2 = 0;
#pragma unroll
            for (int t = 1; t < 6; ++t)
                if (d6[t] > m2) { m2 = d6[t]; s2 = t; }
            mx = m2; sl = s2;
        }
    }

#pragma unroll
    for (int sg = 1; sg < 4; ++sg) {
#pragma unroll
        for (int t = 0; t < 6; ++t) {
            float dv = __shfl(d6[t], gl + sg * 16);
            int ci = __shfl(i6[t], gl + sg * 16);
            if (grp == 0 && dv < mx) {
#pragma unroll
                for (int u = 0; u < 6; ++u)
                    if (u == sl) { d6[u] = dv; i6[u] = ci; }
                float m2 = d6[0]; int s2 = 0;
#pragma unroll
                for (int u = 1; u < 6; ++u)
                    if (d6[u] > m2) { m2 = d6[u]; s2 = u; }
                mx = m2; sl = s2;
            }
        }
    }
    if (lane < 6) {
        int v;
#pragma unroll
        for (int t = 0; t < 6; ++t) if (t == lane) v = i6[t];
        knn_idx[(size_t)q * 6 + lane] = v;
    }
}

// ---------------------------------------------------------------- CSR build
__global__ __launch_bounds__(256) void hist_k(const int* __restrict__ dstA, int* __restrict__ deg)
{
    int e = blockIdx.x * 256 + threadIdx.x;
    atomicAdd(&deg[dstA[e]], 1);
}

__global__ __launch_bounds__(1024) void scan_k(const int* __restrict__ deg, int* __restrict__ rowptr)
{
    __shared__ int ps[1024];
    int t = threadIdx.x;
    const int chunk = 40;
    int base = t * chunk;
    int s = 0;
    for (int k = 0; k < chunk; ++k) { int i = base + k; if (i < N) s += deg[i]; }
    ps[t] = s;
    __syncthreads();
    for (int off = 1; off < 1024; off <<= 1) {
        int v = (t >= off) ? ps[t - off] : 0;
        __syncthreads();
        ps[t] += v;
        __syncthreads();
    }
    int run = ps[t] - s;
    for (int k = 0; k < chunk; ++k) {
        int i = base + k;
        if (i < N) { rowptr[i] = run; run += deg[i]; }
    }
    if (t == 0) rowptr[N] = E;
}

__global__ __launch_bounds__(256) void scatter_k(const int* __restrict__ srcA, const int* __restrict__ dstA,
                                                 const float* __restrict__ ea,
                                                 const int* __restrict__ rowptr, int* __restrict__ cnt,
                                                 int* __restrict__ csr_src, float* __restrict__ csr_ea)
{
    int e = blockIdx.x * 256 + threadIdx.x;
    int d = dstA[e];
    int pos = rowptr[d] + atomicAdd(&cnt[d], 1);
    csr_src[pos] = srcA[e];
    csr_ea[pos] = ea[e];
}

// ---------------------------------------------------------------- fused GAT (blockIdx.y: 0=spatial, 1=latent)
__global__ __launch_bounds__(256) void gat_fused_k(
    const float* __restrict__ xl_s, const float* __restrict__ xr_s,
    const int* __restrict__ rowptr, const int* __restrict__ csr_src, const float* __restrict__ csr_ea,
    const float* __restrict__ att_s, const float* __restrict__ wse, const float* __restrict__ bias_s,
    const float* __restrict__ xl_l, const float* __restrict__ xr_l,
    const int* __restrict__ knn, const float* __restrict__ att_l, const float* __restrict__ bias_l,
    float* __restrict__ ch2)
{
    int w = threadIdx.x >> 6, lane = threadIdx.x & 63;
    int dst = blockIdx.x * 4 + w;

    if (blockIdx.y == 0) {
        // spatial channel: single-pass online softmax over CSR neighborhood
        int base = rowptr[dst];
        int deg = rowptr[dst + 1] - base;
        float xr0 = xr_s[(size_t)dst * 128 + lane], xr1 = xr_s[(size_t)dst * 128 + 64 + lane];
        float at0 = att_s[lane], at1 = att_s[64 + lane];
        float we0 = wse[lane], we1 = wse[64 + lane];

        float m = -1e30f, ssum = 0.f, o0 = 0.f, o1 = 0.f;
        for (int i = 0; i < deg; ++i) {
            int s = csr_src[base + i];
            float ea = csr_ea[base + i];
            float v0 = xl_s[(size_t)s * 128 + lane];
            float v1 = xl_s[(size_t)s * 128 + 64 + lane];
            float h0 = fmaf(ea, we0, v0 + xr0);
            float h1 = fmaf(ea, we1, v1 + xr1);
            h0 = h0 > 0.f ? h0 : 0.2f * h0;
            h1 = h1 > 0.f ? h1 : 0.2f * h1;
            float p = fmaf(h1, at1, h0 * at0);
#pragma unroll
            for (int off = 32; off; off >>= 1) p += __shfl_xor(p, off);
            if (p <= m) {                       // wave-uniform branch
                float wt = __expf(p - m);
                ssum += wt;
                o0 = fmaf(wt, v0, o0);
                o1 = fmaf(wt, v1, o1);
            } else {
                float sc = __expf(m - p);
                ssum = fmaf(ssum, sc, 1.f);
                o0 = fmaf(o0, sc, v0);
                o1 = fmaf(o1, sc, v1);
                m = p;
            }
        }
        float inv = deg > 0 ? 1.f / ssum : 0.f;
        ch2[(size_t)dst * 256 + lane]      = fmaf(o0, inv, bias_s[lane]);
        ch2[(size_t)dst * 256 + 64 + lane] = fmaf(o1, inv, bias_s[64 + lane]);
    } else {
        // latent channel: 6 knn + self
        float xr0 = xr_l[(size_t)dst * 128 + lane], xr1 = xr_l[(size_t)dst * 128 + 64 + lane];
        float at0 = att_l[lane], at1 = att_l[64 + lane];
        int s[7];
#pragma unroll
        for (int j = 0; j < 6; ++j) s[j] = knn[(size_t)dst * 6 + j];
        s[6] = dst;
        float l[7];
#pragma unroll
        for (int j = 0; j < 7; ++j) {
            float h0 = xl_l[(size_t)s[j] * 128 + lane] + xr0;
            float h1 = xl_l[(size_t)s[j] * 128 + 64 + lane] + xr1;
            h0 = h0 > 0.f ? h0 : 0.2f * h0;
            h1 = h1 > 0.f ? h1 : 0.2f * h1;
            float p = h0 * at0 + h1 * at1;
#pragma unroll
            for (int off = 32; off; off >>= 1) p += __shfl_xor(p, off);
            l[j] = p;
        }
        float m = l[0];
#pragma unroll
        for (int j = 1; j < 7; ++j) m = fmaxf(m, l[j]);
        float sum = 0.f;
#pragma unroll
        for (int j = 0; j < 7; ++j) { l[j] = __expf(l[j] - m); sum += l[j]; }
        float inv = 1.f / sum;
        float o0 = 0.f, o1 = 0.f;
#pragma unroll
        for (int j = 0; j < 7; ++j) {
            float a = l[j] * inv;
            o0 = fmaf(a, xl_l[(size_t)s[j] * 128 + lane], o0);
            o1 = fmaf(a, xl_l[(size_t)s[j] * 128 + 64 + lane], o1);
        }
        ch2[(size_t)dst * 256 + 128 + lane] = o0 + bias_l[lane];
        ch2[(size_t)dst * 256 + 192 + lane] = o1 + bias_l[64 + lane];
    }
}

// ---------------------------------------------------------------- launch
extern "C" void kernel_launch(void* const* d_in, const int* in_sizes, int n_in,
                              void* d_out, int out_size, void* d_ws, size_t ws_size,
                              hipStream_t stream)
{
    const float* x      = (const float*)d_in[0];
    const int*   ei     = (const int*)  d_in[1];
    const float* eattr  = (const float*)d_in[2];
    const float* W_sl   = (const float*)d_in[4];
    const float* b_sl   = (const float*)d_in[5];
    const float* W_sr   = (const float*)d_in[6];
    const float* b_sr   = (const float*)d_in[7];
    const float* att_s  = (const float*)d_in[8];
    const float* W_se   = (const float*)d_in[9];
    const float* bias_s = (const float*)d_in[10];
    const float* W_ll   = (const float*)d_in[11];
    const float* b_ll   = (const float*)d_in[12];
    const float* W_lr   = (const float*)d_in[13];
    const float* b_lr   = (const float*)d_in[14];
    const float* att_l  = (const float*)d_in[15];
    const float* bias_l = (const float*)d_in[16];
    const float* W_c    = (const float*)d_in[17];
    const float* b_c    = (const float*)d_in[18];
    const float* W_f1   = (const float*)d_in[19];
    const float* b_f1   = (const float*)d_in[20];
    const float* W_f2   = (const float*)d_in[21];
    const float* b_f2   = (const float*)d_in[22];
    float* out = (float*)d_out;

    char* wp = (char*)d_ws;
    auto take = [&](size_t bytes) { char* p = wp; wp += (bytes + 255) & ~(size_t)255; return p; };
    float* xl_s    = (float*)take((size_t)N * D * 4);
    float* xr_s    = (float*)take((size_t)N * D * 4);
    float* xl_l    = (float*)take((size_t)N * D * 4);
    float* xr_l    = (float*)take((size_t)N * D * 4);
    float* ch2     = (float*)take((size_t)N * 2 * D * 4);
    float* sqn     = (float*)take((size_t)N * 4);
    int*   knn_idx = (int*)  take((size_t)N * KN * 4);
    int*   deg     = (int*)  take((size_t)N * 4);
    int*   rowptr  = (int*)  take((size_t)(N + 1) * 4);
    int*   csr_src = (int*)  take((size_t)E * 4);
    float* csr_ea  = (float*)take((size_t)E * 4);
    unsigned short* x_hi = (unsigned short*)take((size_t)N * D * 2);
    int*   knn_cand = (int*)take((size_t)N * NCAND * 4);
    unsigned short* wt4  = (unsigned short*)take(65536 * 2);
    unsigned short* wtc  = (unsigned short*)take(32768 * 2);
    unsigned short* wtf1 = (unsigned short*)take(32768 * 2);
    unsigned short* wtf2 = (unsigned short*)take(32768 * 2);
    float* fused   = xl_s;
    float* hbuf    = ch2;
    if ((size_t)(wp - (char*)d_ws) > ws_size) return;

    dim3 blk(256);

    // weight transpose + bf16 cast (one-shot, all matrices)
    w_prep_k<<<dim3(640), blk, 0, stream>>>(W_sl, W_sr, W_ll, W_lr, W_c, W_f1, W_f2,
                                            wt4, wtc, wtf1, wtf2);

    // fused node transforms: 4 outputs, one launch, MFMA
    gemm4_mfma_k<<<dim3(N / 64, 4), blk, 0, stream>>>(x, wt4,
        b_sl, b_sr, b_ll, b_lr, xl_s, xr_s, xl_l, xr_l);

    // kNN graph: prep -> bf16 MFMA prefilter -> exact fp32 re-rank
    prep_k<<<dim3(N / 4), blk, 0, stream>>>(x, x_hi, sqn);
    knn_mfma_k<<<dim3(Bg * 40 * 4), blk, 0, stream>>>(x_hi, sqn, knn_cand);
    knn_rerank_k<<<dim3(N / 4), blk, 0, stream>>>(x, sqn, knn_cand, knn_idx);

    // CSR of spatial edges by dst
    hipMemsetAsync(deg, 0, (size_t)N * 4, stream);
    hist_k<<<dim3(E / 256), blk, 0, stream>>>(ei + E, deg);
    scan_k<<<dim3(1), dim3(1024), 0, stream>>>(deg, rowptr);
    hipMemsetAsync(deg, 0, (size_t)N * 4, stream);
    scatter_k<<<dim3(E / 256), blk, 0, stream>>>(ei, ei + E, eattr, rowptr, deg, csr_src, csr_ea);

    // both GAT channels in one launch -> ch2 = [ch_sp | ch_lat]
    gat_fused_k<<<dim3(N / 4, 2), blk, 0, stream>>>(xl_s, xr_s, rowptr, csr_src, csr_ea,
                                                    att_s, W_se, bias_s,
                                                    xl_l, xr_l, knn_idx, att_l, bias_l, ch2);

    // fusion + FFN (MFMA)
    gemm_mfma_k<<<dim3(N / 64, 1), blk, 0, stream>>>(ch2, 2 * D, wtc, 256, b_c, x, fused, 128, 0);
    gemm_mfma_k<<<dim3(N / 64, 2), blk, 0, stream>>>(fused, 128, wtf1, 128, b_f1, nullptr, hbuf, 256, 1);
    gemm_mfma_k<<<dim3(N / 64, 1), blk, 0, stream>>>(hbuf, 256, wtf2, 256, b_f2, fused, out, 128, 1);
}

// Round 11
// 521.163 us; speedup vs baseline: 2.4966x; 1.0948x over previous
//
#include <hip/hip_runtime.h>
#include <math.h>

// ---------------------------------------------------------------- constants
constexpr int N  = 40000;   // nodes
constexpr int D  = 128;     // latent dim
constexpr int E  = 640000;  // spatial edges
constexpr int Bg = 8;       // graphs
constexpr int Sg = 5000;    // nodes per graph
constexpr int KN = 6;       // knn
constexpr int FF = 256;     // ffn hidden
constexpr int CLEN = 640;   // candidate chunk length (64-aligned); chunk 7 = 520
constexpr int NCAND = 48;   // 8 chunks x top-6

typedef short short8 __attribute__((ext_vector_type(8)));
typedef float f32x4  __attribute__((ext_vector_type(4)));

// ---------------------------------------------------------------- bf16 helpers
__device__ __forceinline__ unsigned short f2bf(float f)
{
    unsigned int u = __float_as_uint(f);
    return (unsigned short)((u + 0x7fffu + ((u >> 16) & 1u)) >> 16);
}

// ---------------------------------------------------------------- W pre-transpose + bf16 cast (one-shot)
__global__ __launch_bounds__(256) void w_prep_k(
    const float* __restrict__ W0, const float* __restrict__ W1,
    const float* __restrict__ W2, const float* __restrict__ W3,
    const float* __restrict__ Wc, const float* __restrict__ Wf1,
    const float* __restrict__ Wf2,
    unsigned short* __restrict__ wt4, unsigned short* __restrict__ wtc,
    unsigned short* __restrict__ wtf1, unsigned short* __restrict__ wtf2)
{
    int idx = blockIdx.x * 256 + threadIdx.x;
    if (idx < 65536) {                        // node transforms [128][128]
        int m = idx >> 14, rem = idx & 16383;
        int k = rem & 127, c = rem >> 7;
        const float* Wm = (m == 0) ? W0 : (m == 1) ? W1 : (m == 2) ? W2 : W3;
        wt4[m * 16384 + c * 128 + k] = f2bf(Wm[k * 128 + c]);
    } else if (idx < 98304) {                 // W_c [256][128] -> [128][256]
        int rem = idx - 65536; int k = rem & 255, c = rem >> 8;
        wtc[c * 256 + k] = f2bf(Wc[k * 128 + c]);
    } else if (idx < 131072) {                // W_f1 [128][256] -> [256][128]
        int rem = idx - 98304; int k = rem & 127, c = rem >> 7;
        wtf1[c * 128 + k] = f2bf(Wf1[k * 256 + c]);
    } else {                                  // W_f2 [256][128] -> [128][256]
        int rem = idx - 131072; int k = rem & 255, c = rem >> 8;
        wtf2[c * 256 + k] = f2bf(Wf2[k * 128 + c]);
    }
}

// ---------------------------------------------------------------- MFMA GEMM: out = A@W + bias (+res) (+relu6)
__global__ __launch_bounds__(256) void gemm_mfma_k(
    const float* __restrict__ A, int lda,
    const unsigned short* __restrict__ Wt, int Kdim,
    const float* __restrict__ bias,
    const float* __restrict__ res,
    float* __restrict__ out, int ldo, int act)
{
    __shared__ float xs[64][36];
    __shared__ unsigned short ws[128][40];
    int tid = threadIdx.x;
    int w = tid >> 6, lane = tid & 63;
    int lg = lane >> 4, ln = lane & 15;
    int r0 = blockIdx.x * 64;
    int cb = blockIdx.y * 128;

    f32x4 acc[8];
#pragma unroll
    for (int ct = 0; ct < 8; ++ct) acc[ct] = {0.f, 0.f, 0.f, 0.f};

    int srow = tid >> 2, sk8 = (tid & 3) * 8;
    int wcol = tid >> 1, wk = (tid & 1) * 16;

    for (int kt = 0; kt < Kdim; kt += 32) {
        __syncthreads();
        *(float4*)&xs[srow][sk8]     = *(const float4*)&A[(size_t)(r0 + srow) * lda + kt + sk8];
        *(float4*)&xs[srow][sk8 + 4] = *(const float4*)&A[(size_t)(r0 + srow) * lda + kt + sk8 + 4];
        *(short8*)&ws[wcol][wk]     = *(const short8*)&Wt[(size_t)(cb + wcol) * Kdim + kt + wk];
        *(short8*)&ws[wcol][wk + 8] = *(const short8*)&Wt[(size_t)(cb + wcol) * Kdim + kt + wk + 8];
        __syncthreads();

        int arow = w * 16 + ln;
        f32x4 a0 = *(const f32x4*)&xs[arow][lg * 8];
        f32x4 a1 = *(const f32x4*)&xs[arow][lg * 8 + 4];
        float af[8] = {a0[0], a0[1], a0[2], a0[3], a1[0], a1[1], a1[2], a1[3]};
        short8 ah, al;
#pragma unroll
        for (int i = 0; i < 8; ++i) {
            unsigned short h = f2bf(af[i]);
            ah[i] = (short)h;
            float hf = __uint_as_float(((unsigned)h) << 16);
            al[i] = (short)f2bf(af[i] - hf);
        }
#pragma unroll
        for (int ct = 0; ct < 8; ++ct) {
            short8 bw = *(const short8*)&ws[ct * 16 + ln][lg * 8];
            acc[ct] = __builtin_amdgcn_mfma_f32_16x16x32_bf16(ah, bw, acc[ct], 0, 0, 0);
            acc[ct] = __builtin_amdgcn_mfma_f32_16x16x32_bf16(al, bw, acc[ct], 0, 0, 0);
        }
    }

#pragma unroll
    for (int ct = 0; ct < 8; ++ct) {
        int c = cb + ct * 16 + ln;
        float bv = bias[c];
#pragma unroll
        for (int rg = 0; rg < 4; ++rg) {
            int r = r0 + w * 16 + lg * 4 + rg;
            float v = acc[ct][rg] + bv;
            if (res) v += res[(size_t)r * 128 + c];
            if (act) v = fminf(fmaxf(v, 0.f), 6.f);
            out[(size_t)r * ldo + c] = v;
        }
    }
}

// ---------------------------------------------------------------- fused 4x node-transform MFMA GEMM
__global__ __launch_bounds__(256) void gemm4_mfma_k(
    const float* __restrict__ A, const unsigned short* __restrict__ wt4,
    const float* __restrict__ b0, const float* __restrict__ b1,
    const float* __restrict__ b2, const float* __restrict__ b3,
    float* __restrict__ o0, float* __restrict__ o1,
    float* __restrict__ o2, float* __restrict__ o3)
{
    const unsigned short* Wt = wt4 + blockIdx.y * 16384;
    const float* bias; float* out;
    if (blockIdx.y == 0)      { bias = b0; out = o0; }
    else if (blockIdx.y == 1) { bias = b1; out = o1; }
    else if (blockIdx.y == 2) { bias = b2; out = o2; }
    else                      { bias = b3; out = o3; }

    __shared__ float xs[64][36];
    __shared__ unsigned short ws[128][40];
    int tid = threadIdx.x;
    int w = tid >> 6, lane = tid & 63;
    int lg = lane >> 4, ln = lane & 15;
    int r0 = blockIdx.x * 64;

    f32x4 acc[8];
#pragma unroll
    for (int ct = 0; ct < 8; ++ct) acc[ct] = {0.f, 0.f, 0.f, 0.f};

    int srow = tid >> 2, sk8 = (tid & 3) * 8;
    int wcol = tid >> 1, wk = (tid & 1) * 16;

    for (int kt = 0; kt < 128; kt += 32) {
        __syncthreads();
        *(float4*)&xs[srow][sk8]     = *(const float4*)&A[(size_t)(r0 + srow) * 128 + kt + sk8];
        *(float4*)&xs[srow][sk8 + 4] = *(const float4*)&A[(size_t)(r0 + srow) * 128 + kt + sk8 + 4];
        *(short8*)&ws[wcol][wk]     = *(const short8*)&Wt[(size_t)wcol * 128 + kt + wk];
        *(short8*)&ws[wcol][wk + 8] = *(const short8*)&Wt[(size_t)wcol * 128 + kt + wk + 8];
        __syncthreads();

        int arow = w * 16 + ln;
        f32x4 a0 = *(const f32x4*)&xs[arow][lg * 8];
        f32x4 a1 = *(const f32x4*)&xs[arow][lg * 8 + 4];
        float af[8] = {a0[0], a0[1], a0[2], a0[3], a1[0], a1[1], a1[2], a1[3]};
        short8 ah, al;
#pragma unroll
        for (int i = 0; i < 8; ++i) {
            unsigned short h = f2bf(af[i]);
            ah[i] = (short)h;
            float hf = __uint_as_float(((unsigned)h) << 16);
            al[i] = (short)f2bf(af[i] - hf);
        }
#pragma unroll
        for (int ct = 0; ct < 8; ++ct) {
            short8 bw = *(const short8*)&ws[ct * 16 + ln][lg * 8];
            acc[ct] = __builtin_amdgcn_mfma_f32_16x16x32_bf16(ah, bw, acc[ct], 0, 0, 0);
            acc[ct] = __builtin_amdgcn_mfma_f32_16x16x32_bf16(al, bw, acc[ct], 0, 0, 0);
        }
    }

#pragma unroll
    for (int ct = 0; ct < 8; ++ct) {
        int c = ct * 16 + ln;
        float bv = bias[c];
#pragma unroll
        for (int rg = 0; rg < 4; ++rg) {
            int r = r0 + w * 16 + lg * 4 + rg;
            out[(size_t)r * 128 + c] = acc[ct][rg] + bv;
        }
    }
}

// ---------------------------------------------------------------- prep: sqnorm + bf16-hi cast (one x pass)
__global__ __launch_bounds__(256) void prep_k(const float* __restrict__ x,
                                              unsigned short* __restrict__ xh,
                                              float* __restrict__ sqn)
{
    int w = threadIdx.x >> 6, lane = threadIdx.x & 63;
    int row = blockIdx.x * 4 + w;
    float2 v = *(const float2*)&x[(size_t)row * 128 + lane * 2];
    ushort2 h = make_ushort2(f2bf(v.x), f2bf(v.y));
    *(ushort2*)&xh[(size_t)row * 128 + lane * 2] = h;
    float s = fmaf(v.y, v.y, v.x * v.x);
#pragma unroll
    for (int off = 32; off; off >>= 1) s += __shfl_xor(s, off);
    if (lane == 0) sqn[row] = s;
}

// ---------------------------------------------------------------- branchless sorted insert (ascending u32)
__device__ __forceinline__ void ins6(unsigned (&d)[6], unsigned k)
{
#pragma unroll
    for (int t = 0; t < 6; ++t) {
        unsigned lo = d[t] < k ? d[t] : k;
        unsigned hi = d[t] < k ? k : d[t];
        d[t] = lo; k = hi;
    }
}

// ---------------------------------------------------------------- kNN prefilter via MFMA
// grid: 8 graphs x 40 query-blocks(128q) x 8 candidate-chunks (640 each; last 520).
// Unconditional branchless per-lane top-6 (no divergent guards: the per-lane
// guard is ~always taken at wave level, so guards were pure overhead).
__global__ __launch_bounds__(256) void knn_mfma_k(const unsigned short* __restrict__ xh,
                                                  const float* __restrict__ sqn,
                                                  int* __restrict__ cand)
{
    __shared__ char lds[16640];               // 16KB hi tile + 256B biased csq
    char* ldsH = lds;
    float* cs_s = (float*)(lds + 16384);

    int b = blockIdx.x;
    int g = b & 7, r = b >> 3;                // g == XCD id -> per-graph L2 locality
    int chunk = r & 7, qblk = r >> 3;
    int gbase = g * Sg;
    int cbase = chunk * CLEN;
    int qlen = (chunk < 7) ? CLEN : (Sg - 7 * CLEN);  // 520 last
    int ntiles = (qlen + 63) >> 6;                     // 10 or 9
    int nfull = (chunk < 7) ? ntiles : ntiles - 1;     // tiles needing no clamp/guard
    int tid = threadIdx.x;
    int w = tid >> 6, lane = tid & 63;
    int lg = lane >> 4, ln = lane & 15;
    int q0 = qblk * 128 + w * 32;

    // resident query B-frags (hi only): [qset][kstep]
    short8 bh[2][4];
#pragma unroll
    for (int s = 0; s < 2; ++s) {
        int q = q0 + s * 16 + ln;
        int qrow = gbase + (q < Sg ? q : Sg - 1);
#pragma unroll
        for (int ks = 0; ks < 4; ++ks)
            bh[s][ks] = *(const short8*)&xh[(size_t)qrow * 128 + ks * 32 + lg * 8];
    }

    // hoisted staging addresses (row&7 tile-invariant since rows advance by 16)
    int srow = tid >> 4, sslot = tid & 15;
    int sw_st = (srow & 7) << 4;
    int dstoff[4];
    const unsigned short* src[4];
#pragma unroll
    for (int i = 0; i < 4; ++i) {
        int row = i * 16 + srow;
        dstoff[i] = row * 256 + ((sslot * 16) ^ sw_st);
        src[i] = &xh[(size_t)(gbase + cbase + row) * 128 + sslot * 8];
    }
    const float* csrc = &sqn[gbase + cbase];

    unsigned d6a[6], d6b[6];
#pragma unroll
    for (int t = 0; t < 6; ++t) { d6a[t] = 0xFFFFFFFFu; d6b[t] = 0xFFFFFFFFu; }

    for (int t64 = 0; t64 < ntiles; ++t64) {
        __syncthreads();
        if (t64 < nfull) {                    // fast path: no clamp, no csq guard
#pragma unroll
            for (int i = 0; i < 4; ++i) {
                short8 vh = *(const short8*)src[i];
                src[i] += 64 * 128;           // next tile
                *(short8*)(ldsH + dstoff[i]) = vh;
            }
            if (tid < 64) cs_s[tid] = csrc[tid] + 1024.0f;
        } else {                              // peeled: chunk 7 last tile only
            int c0 = cbase + t64 * 64;
#pragma unroll
            for (int i = 0; i < 4; ++i) {
                int cr = c0 + i * 16 + srow;
                if (cr >= Sg) cr = Sg - 1;
                short8 vh = *(const short8*)&xh[(size_t)(gbase + cr) * 128 + sslot * 8];
                *(short8*)(ldsH + dstoff[i]) = vh;
            }
            if (tid < 64) {
                int cl = c0 + tid;
                cs_s[tid] = (cl < cbase + qlen) ? (sqn[gbase + cl] + 1024.0f) : __builtin_inff();
            }
        }
        csrc += 64;
        __syncthreads();

        int c0 = cbase + t64 * 64;
#pragma unroll
        for (int g16 = 0; g16 < 4; ++g16) {
            f32x4 acc0 = {0.f, 0.f, 0.f, 0.f};
            f32x4 acc1 = {0.f, 0.f, 0.f, 0.f};
            int rr = g16 * 16 + ln;
            int rsw = (ln & 7) << 4;          // == (rr&7)<<4
#pragma unroll
            for (int ks = 0; ks < 4; ++ks) {
                short8 ah = *(const short8*)(ldsH + rr * 256 + ((lg * 16 + ks * 64) ^ rsw));
                acc0 = __builtin_amdgcn_mfma_f32_16x16x32_bf16(ah, bh[0][ks], acc0, 0, 0, 0);
                acc1 = __builtin_amdgcn_mfma_f32_16x16x32_bf16(ah, bh[1][ks], acc1, 0, 0, 0);
            }
            f32x4 cv = *(const f32x4*)&cs_s[g16 * 16 + lg * 4];   // biased +1024
            int idx0 = (c0 - cbase) + g16 * 16 + lg * 4;          // chunk-local, <640
#pragma unroll
            for (int rg = 0; rg < 4; ++rg) {
                unsigned ki = (unsigned)(idx0 + rg);
                unsigned k0 = (__float_as_uint(fmaf(-2.f, acc0[rg], cv[rg])) & 0xFFFFF800u) | ki;
                unsigned k1 = (__float_as_uint(fmaf(-2.f, acc1[rg], cv[rg])) & 0xFFFFF800u) | ki;
                ins6(d6a, k0);                // unconditional branchless
                ins6(d6b, k1);
            }
        }
    }

    // in-wave merge: partials for query (s, ln) live in lanes ln + 16*lg -> top-6
#pragma unroll
    for (int s = 0; s < 2; ++s) {
        unsigned m6[6];
#pragma unroll
        for (int t = 0; t < 6; ++t) m6[t] = s ? d6b[t] : d6a[t];
#pragma unroll
        for (int sg = 1; sg < 4; ++sg)
#pragma unroll
            for (int t = 0; t < 6; ++t) {
                unsigned v = __shfl(s ? d6b[t] : d6a[t], ln + sg * 16);
#pragma unroll
                for (int u = 0; u < 6; ++u) {
                    unsigned lo = m6[u] < v ? m6[u] : v;
                    unsigned hi = m6[u] < v ? v : m6[u];
                    m6[u] = lo; v = hi;
                }
            }
        int q = q0 + s * 16 + ln;
        if (lg == 0 && q < Sg) {
            int* cp = &cand[(size_t)(gbase + q) * NCAND + chunk * 6];
#pragma unroll
            for (int t = 0; t < 6; ++t) cp[t] = gbase + cbase + (int)(m6[t] & 2047u);
        }
    }
}

// ---------------------------------------------------------------- exact fp32 re-rank, wave per query
// 4 groups x 12 candidates, 2-deep pipelined gathers.
__global__ __launch_bounds__(256) void knn_rerank_k(const float* __restrict__ x,
                                                    const float* __restrict__ sqn,
                                                    const int* __restrict__ cand,
                                                    int* __restrict__ knn_idx)
{
    int w = threadIdx.x >> 6, lane = threadIdx.x & 63;
    int grp = lane >> 4, gl = lane & 15;
    int q = blockIdx.x * 4 + w;
    float4 qa = *(const float4*)&x[(size_t)q * 128 + gl * 8];
    float4 qb = *(const float4*)&x[(size_t)q * 128 + gl * 8 + 4];
    const int* cp = &cand[(size_t)q * NCAND + grp * 12];

    int ca[12]; unsigned okm = 0;
#pragma unroll
    for (int j = 0; j < 12; ++j) {
        int c = cp[j];
        bool ok = (unsigned)c < (unsigned)N && c != q;
        okm |= (ok ? 1u : 0u) << j;
        ca[j] = ok ? c : 0;
    }

    float d6[6]; int i6[6]; float mx = __builtin_inff(); int sl = 0;
#pragma unroll
    for (int t = 0; t < 6; ++t) { d6[t] = __builtin_inff(); i6[t] = -1; }

    float4 vaA = *(const float4*)&x[(size_t)ca[0] * 128 + gl * 8];
    float4 vbA = *(const float4*)&x[(size_t)ca[0] * 128 + gl * 8 + 4];
#pragma unroll
    for (int j = 0; j < 12; ++j) {
        float4 vaB, vbB;
        if (j < 11) {                          // prefetch next row before reduce chain
            vaB = *(const float4*)&x[(size_t)ca[j + 1] * 128 + gl * 8];
            vbB = *(const float4*)&x[(size_t)ca[j + 1] * 128 + gl * 8 + 4];
        }
        float p = qa.x * vaA.x;
        p = fmaf(qa.y, vaA.y, p); p = fmaf(qa.z, vaA.z, p); p = fmaf(qa.w, vaA.w, p);
        p = fmaf(qb.x, vbA.x, p); p = fmaf(qb.y, vbA.y, p);
        p = fmaf(qb.z, vbA.z, p); p = fmaf(qb.w, vbA.w, p);
#pragma unroll
        for (int off = 1; off < 16; off <<= 1) p += __shfl_xor(p, off);
        float dv = ((okm >> j) & 1u) ? fmaf(-2.f, p, sqn[ca[j]]) : __builtin_inff();
        if (dv < mx) {
#pragma unroll
            for (int t = 0; t < 6; ++t)
                if (t == sl) { d6[t] = dv; i6[t] = ca[j]; }
            float m2 = d6[0]; int s2 = 0;
#pragma unroll
            for (int t = 1; t < 6; ++t)
                if (d6[t] > m2) { m2 = d6[t]; s2 = t; }
            mx = m2; sl = s2;
        }
        vaA = vaB; vbA = vbB;
    }

    // merge groups 1..3 into group 0 (their lists frozen -> no race)
#pragma unroll
    for (int sg = 1; sg < 4; ++sg) {
#pragma unroll
        for (int t = 0; t < 6; ++t) {
            float dv = __shfl(d6[t], gl + sg * 16);
            int ci = __shfl(i6[t], gl + sg * 16);
            if (grp == 0 && dv < mx) {
#pragma unroll
                for (int u = 0; u < 6; ++u)
                    if (u == sl) { d6[u] = dv; i6[u] = ci; }
                float m2 = d6[0]; int s2 = 0;
#pragma unroll
                for (int u = 1; u < 6; ++u)
                    if (d6[u] > m2) { m2 = d6[u]; s2 = u; }
                mx = m2; sl = s2;
            }
        }
    }
    if (lane < 6) {
        int v;
#pragma unroll
        for (int t = 0; t < 6; ++t) if (t == lane) v = i6[t];
        knn_idx[(size_t)q * 6 + lane] = v;
    }
}

// ---------------------------------------------------------------- CSR build
__global__ __launch_bounds__(256) void hist_k(const int* __restrict__ dstA, int* __restrict__ deg)
{
    int e = blockIdx.x * 256 + threadIdx.x;
    atomicAdd(&deg[dstA[e]], 1);
}

__global__ __launch_bounds__(1024) void scan_k(const int* __restrict__ deg, int* __restrict__ rowptr)
{
    __shared__ int ps[1024];
    int t = threadIdx.x;
    const int chunk = 40;
    int base = t * chunk;
    int s = 0;
    for (int k = 0; k < chunk; ++k) { int i = base + k; if (i < N) s += deg[i]; }
    ps[t] = s;
    __syncthreads();
    for (int off = 1; off < 1024; off <<= 1) {
        int v = (t >= off) ? ps[t - off] : 0;
        __syncthreads();
        ps[t] += v;
        __syncthreads();
    }
    int run = ps[t] - s;
    for (int k = 0; k < chunk; ++k) {
        int i = base + k;
        if (i < N) { rowptr[i] = run; run += deg[i]; }
    }
    if (t == 0) rowptr[N] = E;
}

__global__ __launch_bounds__(256) void scatter_k(const int* __restrict__ srcA, const int* __restrict__ dstA,
                                                 const float* __restrict__ ea,
                                                 const int* __restrict__ rowptr, int* __restrict__ cnt,
                                                 int* __restrict__ csr_src, float* __restrict__ csr_ea)
{
    int e = blockIdx.x * 256 + threadIdx.x;
    int d = dstA[e];
    int pos = rowptr[d] + atomicAdd(&cnt[d], 1);
    csr_src[pos] = srcA[e];
    csr_ea[pos] = ea[e];
}

// ---------------------------------------------------------------- fused GAT (blockIdx.y: 0=spatial, 1=latent)
__global__ __launch_bounds__(256) void gat_fused_k(
    const float* __restrict__ xl_s, const float* __restrict__ xr_s,
    const int* __restrict__ rowptr, const int* __restrict__ csr_src, const float* __restrict__ csr_ea,
    const float* __restrict__ att_s, const float* __restrict__ wse, const float* __restrict__ bias_s,
    const float* __restrict__ xl_l, const float* __restrict__ xr_l,
    const int* __restrict__ knn, const float* __restrict__ att_l, const float* __restrict__ bias_l,
    float* __restrict__ ch2)
{
    int w = threadIdx.x >> 6, lane = threadIdx.x & 63;
    int dst = blockIdx.x * 4 + w;

    if (blockIdx.y == 0) {
        // spatial: single-pass online softmax, 1-ahead prefetched gathers
        int base = rowptr[dst];
        int deg = rowptr[dst + 1] - base;
        float xr0 = xr_s[(size_t)dst * 128 + lane], xr1 = xr_s[(size_t)dst * 128 + 64 + lane];
        float at0 = att_s[lane], at1 = att_s[64 + lane];
        float we0 = wse[lane], we1 = wse[64 + lane];

        float eaN = 0.f, v0N = 0.f, v1N = 0.f;
        if (deg > 0) {
            int s0 = csr_src[base];
            eaN = csr_ea[base];
            v0N = xl_s[(size_t)s0 * 128 + lane];
            v1N = xl_s[(size_t)s0 * 128 + 64 + lane];
        }
        float m = -1e30f, ssum = 0.f, o0 = 0.f, o1 = 0.f;
        for (int i = 0; i < deg; ++i) {
            float ea = eaN, v0 = v0N, v1 = v1N;
            if (i + 1 < deg) {                // prefetch next edge before reduce chain
                int sn = csr_src[base + i + 1];
                eaN = csr_ea[base + i + 1];
                v0N = xl_s[(size_t)sn * 128 + lane];
                v1N = xl_s[(size_t)sn * 128 + 64 + lane];
            }
            float h0 = fmaf(ea, we0, v0 + xr0);
            float h1 = fmaf(ea, we1, v1 + xr1);
            h0 = h0 > 0.f ? h0 : 0.2f * h0;
            h1 = h1 > 0.f ? h1 : 0.2f * h1;
            float p = fmaf(h1, at1, h0 * at0);
#pragma unroll
            for (int off = 32; off; off >>= 1) p += __shfl_xor(p, off);
            if (p <= m) {                     // wave-uniform branch
                float wt = __expf(p - m);
                ssum += wt;
                o0 = fmaf(wt, v0, o0);
                o1 = fmaf(wt, v1, o1);
            } else {
                float sc = __expf(m - p);
                ssum = fmaf(ssum, sc, 1.f);
                o0 = fmaf(o0, sc, v0);
                o1 = fmaf(o1, sc, v1);
                m = p;
            }
        }
        float inv = deg > 0 ? 1.f / ssum : 0.f;
        ch2[(size_t)dst * 256 + lane]      = fmaf(o0, inv, bias_s[lane]);
        ch2[(size_t)dst * 256 + 64 + lane] = fmaf(o1, inv, bias_s[64 + lane]);
    } else {
        // latent channel: 6 knn + self
        float xr0 = xr_l[(size_t)dst * 128 + lane], xr1 = xr_l[(size_t)dst * 128 + 64 + lane];
        float at0 = att_l[lane], at1 = att_l[64 + lane];
        int s[7];
#pragma unroll
        for (int j = 0; j < 6; ++j) s[j] = knn[(size_t)dst * 6 + j];
        s[6] = dst;
        float l[7];
#pragma unroll
        for (int j = 0; j < 7; ++j) {
            float h0 = xl_l[(size_t)s[j] * 128 + lane] + xr0;
            float h1 = xl_l[(size_t)s[j] * 128 + 64 + lane] + xr1;
            h0 = h0 > 0.f ? h0 : 0.2f * h0;
            h1 = h1 > 0.f ? h1 : 0.2f * h1;
            float p = h0 * at0 + h1 * at1;
#pragma unroll
            for (int off = 32; off; off >>= 1) p += __shfl_xor(p, off);
            l[j] = p;
        }
        float m = l[0];
#pragma unroll
        for (int j = 1; j < 7; ++j) m = fmaxf(m, l[j]);
        float sum = 0.f;
#pragma unroll
        for (int j = 0; j < 7; ++j) { l[j] = __expf(l[j] - m); sum += l[j]; }
        float inv = 1.f / sum;
        float o0 = 0.f, o1 = 0.f;
#pragma unroll
        for (int j = 0; j < 7; ++j) {
            float a = l[j] * inv;
            o0 = fmaf(a, xl_l[(size_t)s[j] * 128 + lane], o0);
            o1 = fmaf(a, xl_l[(size_t)s[j] * 128 + 64 + lane], o1);
        }
        ch2[(size_t)dst * 256 + 128 + lane] = o0 + bias_l[lane];
        ch2[(size_t)dst * 256 + 192 + lane] = o1 + bias_l[64 + lane];
    }
}

// ---------------------------------------------------------------- launch
extern "C" void kernel_launch(void* const* d_in, const int* in_sizes, int n_in,
                              void* d_out, int out_size, void* d_ws, size_t ws_size,
                              hipStream_t stream)
{
    const float* x      = (const float*)d_in[0];
    const int*   ei     = (const int*)  d_in[1];
    const float* eattr  = (const float*)d_in[2];
    const float* W_sl   = (const float*)d_in[4];
    const float* b_sl   = (const float*)d_in[5];
    const float* W_sr   = (const float*)d_in[6];
    const float* b_sr   = (const float*)d_in[7];
    const float* att_s  = (const float*)d_in[8];
    const float* W_se   = (const float*)d_in[9];
    const float* bias_s = (const float*)d_in[10];
    const float* W_ll   = (const float*)d_in[11];
    const float* b_ll   = (const float*)d_in[12];
    const float* W_lr   = (const float*)d_in[13];
    const float* b_lr   = (const float*)d_in[14];
    const float* att_l  = (const float*)d_in[15];
    const float* bias_l = (const float*)d_in[16];
    const float* W_c    = (const float*)d_in[17];
    const float* b_c    = (const float*)d_in[18];
    const float* W_f1   = (const float*)d_in[19];
    const float* b_f1   = (const float*)d_in[20];
    const float* W_f2   = (const float*)d_in[21];
    const float* b_f2   = (const float*)d_in[22];
    float* out = (float*)d_out;

    char* wp = (char*)d_ws;
    auto take = [&](size_t bytes) { char* p = wp; wp += (bytes + 255) & ~(size_t)255; return p; };
    float* xl_s    = (float*)take((size_t)N * D * 4);
    float* xr_s    = (float*)take((size_t)N * D * 4);
    float* xl_l    = (float*)take((size_t)N * D * 4);
    float* xr_l    = (float*)take((size_t)N * D * 4);
    float* ch2     = (float*)take((size_t)N * 2 * D * 4);
    float* sqn     = (float*)take((size_t)N * 4);
    int*   knn_idx = (int*)  take((size_t)N * KN * 4);
    int*   deg     = (int*)  take((size_t)N * 4);
    int*   rowptr  = (int*)  take((size_t)(N + 1) * 4);
    int*   csr_src = (int*)  take((size_t)E * 4);
    float* csr_ea  = (float*)take((size_t)E * 4);
    unsigned short* x_hi = (unsigned short*)take((size_t)N * D * 2);
    int*   knn_cand = (int*)take((size_t)N * NCAND * 4);
    unsigned short* wt4  = (unsigned short*)take(65536 * 2);
    unsigned short* wtc  = (unsigned short*)take(32768 * 2);
    unsigned short* wtf1 = (unsigned short*)take(32768 * 2);
    unsigned short* wtf2 = (unsigned short*)take(32768 * 2);
    float* fused   = xl_s;
    float* hbuf    = ch2;
    if ((size_t)(wp - (char*)d_ws) > ws_size) return;

    dim3 blk(256);

    // weight transpose + bf16 cast (one-shot, all matrices)
    w_prep_k<<<dim3(640), blk, 0, stream>>>(W_sl, W_sr, W_ll, W_lr, W_c, W_f1, W_f2,
                                            wt4, wtc, wtf1, wtf2);

    // fused node transforms: 4 outputs, one launch, MFMA
    gemm4_mfma_k<<<dim3(N / 64, 4), blk, 0, stream>>>(x, wt4,
        b_sl, b_sr, b_ll, b_lr, xl_s, xr_s, xl_l, xr_l);

    // kNN graph: prep -> bf16 MFMA prefilter (8 chunks) -> exact fp32 re-rank
    prep_k<<<dim3(N / 4), blk, 0, stream>>>(x, x_hi, sqn);
    knn_mfma_k<<<dim3(Bg * 40 * 8), blk, 0, stream>>>(x_hi, sqn, knn_cand);
    knn_rerank_k<<<dim3(N / 4), blk, 0, stream>>>(x, sqn, knn_cand, knn_idx);

    // CSR of spatial edges by dst
    hipMemsetAsync(deg, 0, (size_t)N * 4, stream);
    hist_k<<<dim3(E / 256), blk, 0, stream>>>(ei + E, deg);
    scan_k<<<dim3(1), dim3(1024), 0, stream>>>(deg, rowptr);
    hipMemsetAsync(deg, 0, (size_t)N * 4, stream);
    scatter_k<<<dim3(E / 256), blk, 0, stream>>>(ei, ei + E, eattr, rowptr, deg, csr_src, csr_ea);

    // both GAT channels in one launch -> ch2 = [ch_sp | ch_lat]
    gat_fused_k<<<dim3(N / 4, 2), blk, 0, stream>>>(xl_s, xr_s, rowptr, csr_src, csr_ea,
                                                    att_s, W_se, bias_s,
                                                    xl_l, xr_l, knn_idx, att_l, bias_l, ch2);

    // fusion + FFN (MFMA)
    gemm_mfma_k<<<dim3(N / 64, 1), blk, 0, stream>>>(ch2, 2 * D, wtc, 256, b_c, x, fused, 128, 0);
    gemm_mfma_k<<<dim3(N / 64, 2), blk, 0, stream>>>(fused, 128, wtf1, 128, b_f1, nullptr, hbuf, 256, 1);
    gemm_mfma_k<<<dim3(N / 64, 1), blk, 0, stream>>>(hbuf, 256, wtf2, 256, b_f2, fused, out, 128, 1);
}